// Round 2
// baseline (493.223 us; speedup 1.0000x reference)
//
#include <hip/hip_runtime.h>
#include <hip/hip_bf16.h>

// Shapes (fixed by reference): B=8, N=1024, Din=256, H=4, Dh=128, Do=64
#define BSZ 8
#define NN 1024
#define DIN 256
#define NH 4
#define DH 128
#define DOUT 64
#define RTOT (BSZ*NN)          // 8192 rows total
#define FCAT (NH*DH)           // 512
#define ALPHA 0.2f
#define NEG_INF -9e15f

// ---------------- Kernel A: Wh1[r, h*128+f] = sum_k x[r,k] * W_heads[h,k,f] ----------------
__global__ __launch_bounds__(512) void k_wh1(const float* __restrict__ x,
                                             const float* __restrict__ W,
                                             float* __restrict__ Wh1) {
    __shared__ float xs[16][DIN];          // 16 KB
    const int tid = threadIdx.x;
    const int r0  = blockIdx.x * 16;
    // 16*256 = 4096 floats = 1024 float4; 512 threads x 2
    const float4* xsrc = (const float4*)(x + (size_t)r0 * DIN);
    float4* xdst = (float4*)&xs[0][0];
#pragma unroll
    for (int t = 0; t < 2; ++t) xdst[tid + t * 512] = xsrc[tid + t * 512];
    __syncthreads();
    const int c = tid;                     // 0..511
    const int h = c >> 7, f = c & 127;
    const float* wp = W + (size_t)h * DIN * DH + f;
    float acc[16];
#pragma unroll
    for (int t = 0; t < 16; ++t) acc[t] = 0.f;
    for (int k = 0; k < DIN; ++k) {
        const float w = wp[(size_t)k * DH];
#pragma unroll
        for (int t = 0; t < 16; ++t) acc[t] += xs[t][k] * w;
    }
#pragma unroll
    for (int t = 0; t < 16; ++t)
        Wh1[(size_t)(r0 + t) * FCAT + c] = acc[t];
}

// ---------------- Kernel B: src1/dst1[h, r] = dot(Wh1[r, h*128 : +128], a_heads halves) ----
__global__ __launch_bounds__(256) void k_srcdst1(const float* __restrict__ Wh1,
                                                 const float* __restrict__ a,
                                                 float* __restrict__ src1,
                                                 float* __restrict__ dst1) {
    const int tid = threadIdx.x;
    const int wid = tid >> 6, lane = tid & 63;
    const int w = blockIdx.x * 4 + wid;    // 0 .. 4*8192-1
    const int h = w >> 13, r = w & (RTOT - 1);
    const float* row = Wh1 + (size_t)r * FCAT + h * DH;
    const float a0 = a[h * 2 * DH + lane];
    const float a1 = a[h * 2 * DH + lane + 64];
    const float b0 = a[h * 2 * DH + DH + lane];
    const float b1 = a[h * 2 * DH + DH + lane + 64];
    const float v0 = row[lane], v1 = row[lane + 64];
    float sv = v0 * a0 + v1 * a1;
    float dv = v0 * b0 + v1 * b1;
#pragma unroll
    for (int o = 32; o > 0; o >>= 1) {
        sv += __shfl_down(sv, o, 64);
        dv += __shfl_down(dv, o, 64);
    }
    if (lane == 0) { src1[h * RTOT + r] = sv; dst1[h * RTOT + r] = dv; }
}

// ---------------- Kernel C: layer-1 attention+aggregation, 8 rows per block, one head -----
__global__ __launch_bounds__(256) void k_attn1(const int* __restrict__ adj,
                                               const float* __restrict__ Wh1,
                                               const float* __restrict__ src1,
                                               const float* __restrict__ dst1,
                                               float* __restrict__ xcat) {
    __shared__ __align__(16) float P[8][NN];   // 32 KB unnormalized softmax weights
    __shared__ float red[4];
    __shared__ float rowsum[8];
    const int tid  = threadIdx.x;
    const int lane = tid & 63, wid = tid >> 6;
    const int bx   = blockIdx.x;
    const int tile = bx & 1023, h = bx >> 10;
    const int r0   = tile * 8;
    const int b    = r0 >> 10;
    const int i0   = r0 & 1023;
    const float* dsth = dst1 + h * RTOT + b * NN;
    const int* adjb   = adj + (size_t)b * NN * NN;

    for (int ti = 0; ti < 8; ++ti) {
        const int i = i0 + ti;
        const float si = src1[h * RTOT + r0 + ti];
        float lmax = -INFINITY;
#pragma unroll
        for (int jj = 0; jj < 4; ++jj) {
            const int j = tid + jj * 256;
            float v = si + dsth[j];
            v = v >= 0.f ? v : ALPHA * v;
            const float s = adjb[(size_t)i * NN + j] > 0 ? v : NEG_INF;
            P[ti][j] = s;
            lmax = fmaxf(lmax, s);
        }
#pragma unroll
        for (int o = 32; o > 0; o >>= 1) lmax = fmaxf(lmax, __shfl_down(lmax, o, 64));
        if (lane == 0) red[wid] = lmax;
        __syncthreads();
        const float m = fmaxf(fmaxf(red[0], red[1]), fmaxf(red[2], red[3]));
        __syncthreads();
        float lsum = 0.f;
#pragma unroll
        for (int jj = 0; jj < 4; ++jj) {
            const int j = tid + jj * 256;
            const float p = __expf(P[ti][j] - m);
            P[ti][j] = p;
            lsum += p;
        }
#pragma unroll
        for (int o = 32; o > 0; o >>= 1) lsum += __shfl_down(lsum, o, 64);
        if (lane == 0) red[wid] = lsum;
        __syncthreads();
        if (tid == 0) rowsum[ti] = red[0] + red[1] + red[2] + red[3];
        __syncthreads();
    }

    // phase 2: out[ti, f] = sum_j P[ti][j] * Wh1[b*1024+j, h*128+f] / rowsum[ti]
    const int f = tid & 127, g = tid >> 7;   // 2 groups x 4 rows
    const float* whp = Wh1 + (size_t)b * NN * FCAT + h * DH + f;
    float acc[4] = {0.f, 0.f, 0.f, 0.f};
    for (int j = 0; j < NN; j += 4) {
        const float w0 = whp[(size_t)(j + 0) * FCAT];
        const float w1 = whp[(size_t)(j + 1) * FCAT];
        const float w2 = whp[(size_t)(j + 2) * FCAT];
        const float w3 = whp[(size_t)(j + 3) * FCAT];
#pragma unroll
        for (int rr = 0; rr < 4; ++rr) {
            const float4 p = *(const float4*)&P[g * 4 + rr][j];
            acc[rr] += p.x * w0 + p.y * w1 + p.z * w2 + p.w * w3;
        }
    }
#pragma unroll
    for (int rr = 0; rr < 4; ++rr) {
        const int r = r0 + g * 4 + rr;
        xcat[(size_t)r * FCAT + h * DH + f] = acc[rr] / rowsum[g * 4 + rr];
    }
}

// ---------------- Kernel D: Wh2 = xcat[8192,512] @ W_out[512,64] ---------------------------
__global__ __launch_bounds__(256) void k_wh2(const float* __restrict__ xcat,
                                             const float* __restrict__ Wout,
                                             float* __restrict__ Wh2) {
    __shared__ float xs[16][FCAT];         // 32 KB
    const int tid = threadIdx.x;
    const int r0  = blockIdx.x * 16;
    // 16*512 = 8192 floats = 2048 float4; 256 threads x 8
    const float4* xsrc = (const float4*)(xcat + (size_t)r0 * FCAT);
    float4* xdst = (float4*)&xs[0][0];
#pragma unroll
    for (int t = 0; t < 8; ++t) xdst[tid + t * 256] = xsrc[tid + t * 256];
    __syncthreads();
    const int c = tid & 63, g = tid >> 6;  // 4 groups x 4 rows
    float acc[4] = {0.f, 0.f, 0.f, 0.f};
    for (int k = 0; k < FCAT; ++k) {
        const float w = Wout[(size_t)k * DOUT + c];
#pragma unroll
        for (int rr = 0; rr < 4; ++rr) acc[rr] += xs[g * 4 + rr][k] * w;
    }
#pragma unroll
    for (int rr = 0; rr < 4; ++rr)
        Wh2[(size_t)(r0 + g * 4 + rr) * DOUT + c] = acc[rr];
}

// ---------------- Kernel E: src2/dst2[r] = dot(Wh2[r], a_out halves) -----------------------
__global__ __launch_bounds__(256) void k_srcdst2(const float* __restrict__ Wh2,
                                                 const float* __restrict__ aout,
                                                 float* __restrict__ src2,
                                                 float* __restrict__ dst2) {
    const int tid = threadIdx.x;
    const int wid = tid >> 6, lane = tid & 63;
    const int r = blockIdx.x * 4 + wid;
    const float v = Wh2[(size_t)r * DOUT + lane];
    float sv = v * aout[lane];
    float dv = v * aout[64 + lane];
#pragma unroll
    for (int o = 32; o > 0; o >>= 1) {
        sv += __shfl_down(sv, o, 64);
        dv += __shfl_down(dv, o, 64);
    }
    if (lane == 0) { src2[r] = sv; dst2[r] = dv; }
}

// ---------------- Kernel F: layer-2 attention + aggregation + ELU --------------------------
__global__ __launch_bounds__(256) void k_attn2(const int* __restrict__ adj,
                                               const float* __restrict__ Wh2,
                                               const float* __restrict__ src2,
                                               const float* __restrict__ dst2,
                                               float* __restrict__ t2) {
    __shared__ __align__(16) float P[8][NN];
    __shared__ float red[4];
    __shared__ float rowsum[8];
    const int tid  = threadIdx.x;
    const int lane = tid & 63, wid = tid >> 6;
    const int r0   = blockIdx.x * 8;
    const int b    = r0 >> 10;
    const int i0   = r0 & 1023;
    const float* dstb = dst2 + b * NN;
    const int* adjb   = adj + (size_t)b * NN * NN;

    for (int ti = 0; ti < 8; ++ti) {
        const int i = i0 + ti;
        const float si = src2[r0 + ti];
        float lmax = -INFINITY;
#pragma unroll
        for (int jj = 0; jj < 4; ++jj) {
            const int j = tid + jj * 256;
            float v = si + dstb[j];
            v = v >= 0.f ? v : ALPHA * v;
            const float s = adjb[(size_t)i * NN + j] > 0 ? v : NEG_INF;
            P[ti][j] = s;
            lmax = fmaxf(lmax, s);
        }
#pragma unroll
        for (int o = 32; o > 0; o >>= 1) lmax = fmaxf(lmax, __shfl_down(lmax, o, 64));
        if (lane == 0) red[wid] = lmax;
        __syncthreads();
        const float m = fmaxf(fmaxf(red[0], red[1]), fmaxf(red[2], red[3]));
        __syncthreads();
        float lsum = 0.f;
#pragma unroll
        for (int jj = 0; jj < 4; ++jj) {
            const int j = tid + jj * 256;
            const float p = __expf(P[ti][j] - m);
            P[ti][j] = p;
            lsum += p;
        }
#pragma unroll
        for (int o = 32; o > 0; o >>= 1) lsum += __shfl_down(lsum, o, 64);
        if (lane == 0) red[wid] = lsum;
        __syncthreads();
        if (tid == 0) rowsum[ti] = red[0] + red[1] + red[2] + red[3];
        __syncthreads();
    }

    const int f = tid & 63, g = tid >> 6;  // 4 groups x 2 rows
    const float* whp = Wh2 + (size_t)b * NN * DOUT + f;
    float acc[2] = {0.f, 0.f};
    for (int j = 0; j < NN; j += 4) {
        const float w0 = whp[(size_t)(j + 0) * DOUT];
        const float w1 = whp[(size_t)(j + 1) * DOUT];
        const float w2 = whp[(size_t)(j + 2) * DOUT];
        const float w3 = whp[(size_t)(j + 3) * DOUT];
#pragma unroll
        for (int rr = 0; rr < 2; ++rr) {
            const float4 p = *(const float4*)&P[g * 2 + rr][j];
            acc[rr] += p.x * w0 + p.y * w1 + p.z * w2 + p.w * w3;
        }
    }
#pragma unroll
    for (int rr = 0; rr < 2; ++rr) {
        const int r = r0 + g * 2 + rr;
        const float v = acc[rr] / rowsum[g * 2 + rr];
        t2[(size_t)r * DOUT + f] = v > 0.f ? v : (__expf(v) - 1.f);   // ELU
    }
}

// ---------------- Kernel G: out = relu(t2 @ Wf + bf) --------------------------------------
__global__ __launch_bounds__(256) void k_fc(const float* __restrict__ t2,
                                            const float* __restrict__ Wf,
                                            const float* __restrict__ bfv,
                                            float* __restrict__ out) {
    const int gid = blockIdx.x * 256 + threadIdx.x;
    const int r = gid >> 6, c = gid & 63;
    float acc = bfv[c];
    const float* row = t2 + (size_t)r * DOUT;
    for (int k = 0; k < DOUT; ++k)
        acc += row[k] * Wf[(size_t)k * DOUT + c];
    out[gid] = fmaxf(acc, 0.f);
}

extern "C" void kernel_launch(void* const* d_in, const int* in_sizes, int n_in,
                              void* d_out, int out_size, void* d_ws, size_t ws_size,
                              hipStream_t stream) {
    const float* x   = (const float*)d_in[0];
    const int*   adj = (const int*)d_in[1];
    const float* Wh  = (const float*)d_in[2];
    const float* ah  = (const float*)d_in[3];
    const float* Wo  = (const float*)d_in[4];
    const float* ao  = (const float*)d_in[5];
    const float* Wf  = (const float*)d_in[6];
    const float* bf  = (const float*)d_in[7];
    float* out = (float*)d_out;

    float* ws   = (float*)d_ws;
    float* Wh1  = ws;                          // 8192*512
    float* src1 = Wh1 + (size_t)RTOT * FCAT;   // 4*8192
    float* dst1 = src1 + NH * RTOT;            // 4*8192
    float* xcat = dst1 + NH * RTOT;            // 8192*512
    float* Wh2  = xcat + (size_t)RTOT * FCAT;  // 8192*64
    float* src2 = Wh2 + (size_t)RTOT * DOUT;   // 8192
    float* dst2 = src2 + RTOT;                 // 8192
    float* t2   = dst2 + RTOT;                 // 8192*64

    hipLaunchKernelGGL(k_wh1,     dim3(RTOT / 16), dim3(512), 0, stream, x, Wh, Wh1);
    hipLaunchKernelGGL(k_srcdst1, dim3(NH * RTOT / 4), dim3(256), 0, stream, Wh1, ah, src1, dst1);
    hipLaunchKernelGGL(k_attn1,   dim3(NH * RTOT / 8), dim3(256), 0, stream, adj, Wh1, src1, dst1, xcat);
    hipLaunchKernelGGL(k_wh2,     dim3(RTOT / 16), dim3(256), 0, stream, xcat, Wo, Wh2);
    hipLaunchKernelGGL(k_srcdst2, dim3(RTOT / 4), dim3(256), 0, stream, Wh2, ao, src2, dst2);
    hipLaunchKernelGGL(k_attn2,   dim3(RTOT / 8), dim3(256), 0, stream, adj, Wh2, src2, dst2, t2);
    hipLaunchKernelGGL(k_fc,      dim3(RTOT * DOUT / 256), dim3(256), 0, stream, t2, Wf, bf, out);
}

// Round 3
// 257.394 us; speedup vs baseline: 1.9162x; 1.9162x over previous
//
#include <hip/hip_runtime.h>
#include <hip/hip_bf16.h>

// Shapes (fixed by reference): B=8, N=1024, Din=256, H=4, Dh=128, Do=64
#define BSZ 8
#define NN 1024
#define DIN 256
#define NH 4
#define DH 128
#define DOUT 64
#define RTOT (BSZ*NN)          // 8192 rows total
#define FCAT (NH*DH)           // 512
#define ALPHA 0.2f
#define NEG_INF -9e15f
#define PSTRIDE 1032           // bf16 elems per P row: 1024 + 8 pad (2064 B, 16B-aligned)

typedef unsigned short ushortT;
typedef __attribute__((ext_vector_type(8))) short bf16x8;
typedef __attribute__((ext_vector_type(4))) float f32x4;

static __device__ __forceinline__ ushortT f2bf(float f) {
    __hip_bfloat16 h = __float2bfloat16(f);
    return *reinterpret_cast<ushortT*>(&h);
}

// ---------------- Kernel A: Wh1 = x @ W_heads (f32 out + bf16-transposed out) --------------
__global__ __launch_bounds__(512) void k_wh1(const float* __restrict__ x,
                                             const float* __restrict__ W,
                                             float* __restrict__ Wh1,
                                             ushortT* __restrict__ WhT) {
    __shared__ float xs[16][DIN];          // 16 KB
    const int tid = threadIdx.x;
    const int r0  = blockIdx.x * 16;
    const float4* xsrc = (const float4*)(x + (size_t)r0 * DIN);
    float4* xdst = (float4*)&xs[0][0];
#pragma unroll
    for (int t = 0; t < 2; ++t) xdst[tid + t * 512] = xsrc[tid + t * 512];
    __syncthreads();
    const int c = tid;                     // 0..511
    const int h = c >> 7, f = c & 127;
    const float* wp = W + (size_t)h * DIN * DH + f;
    float acc[16];
#pragma unroll
    for (int t = 0; t < 16; ++t) acc[t] = 0.f;
    for (int k = 0; k < DIN; ++k) {
        const float w = wp[(size_t)k * DH];
#pragma unroll
        for (int t = 0; t < 16; ++t) acc[t] += xs[t][k] * w;
    }
#pragma unroll
    for (int t = 0; t < 16; ++t)
        Wh1[(size_t)(r0 + t) * FCAT + c] = acc[t];
    // bf16 transposed copy: WhT[((b*NH+h)*DH+f)*NN + j]
    const int b = r0 >> 10, jr = r0 & 1023;
    union { ushortT u[16]; uint4 q[2]; } tw;
#pragma unroll
    for (int t = 0; t < 16; ++t) tw.u[t] = f2bf(acc[t]);
    ushortT* wt = WhT + ((size_t)(b * NH + h) * DH + f) * NN + jr;
    *(uint4*)wt = tw.q[0];
    *(uint4*)(wt + 8) = tw.q[1];
}

// ---------------- Kernel B: src1/dst1[h, r] = dot(Wh1 row slice, a halves) -----------------
__global__ __launch_bounds__(256) void k_srcdst1(const float* __restrict__ Wh1,
                                                 const float* __restrict__ a,
                                                 float* __restrict__ src1,
                                                 float* __restrict__ dst1) {
    const int tid = threadIdx.x;
    const int wid = tid >> 6, lane = tid & 63;
    const int w = blockIdx.x * 4 + wid;
    const int h = w >> 13, r = w & (RTOT - 1);
    const float* row = Wh1 + (size_t)r * FCAT + h * DH;
    const float a0 = a[h * 2 * DH + lane];
    const float a1 = a[h * 2 * DH + lane + 64];
    const float b0 = a[h * 2 * DH + DH + lane];
    const float b1 = a[h * 2 * DH + DH + lane + 64];
    const float v0 = row[lane], v1 = row[lane + 64];
    float sv = v0 * a0 + v1 * a1;
    float dv = v0 * b0 + v1 * b1;
#pragma unroll
    for (int o = 32; o > 0; o >>= 1) {
        sv += __shfl_down(sv, o, 64);
        dv += __shfl_down(dv, o, 64);
    }
    if (lane == 0) { src1[h * RTOT + r] = sv; dst1[h * RTOT + r] = dv; }
}

// ---------------- Kernel C: layer-1 attention, 16 rows/block, MFMA aggregation -------------
__global__ __launch_bounds__(512) void k_attn1(const int* __restrict__ adj,
                                               const ushortT* __restrict__ WhT,
                                               const float* __restrict__ src1,
                                               const float* __restrict__ dst1,
                                               float* __restrict__ xcat) {
    __shared__ ushortT P[16 * PSTRIDE];    // 33 KB bf16 softmax weights (padded rows)
    __shared__ float dstv[NN];             // 4 KB
    __shared__ float rowinv[16];
    const int tid  = threadIdx.x;
    const int lane = tid & 63, wave = tid >> 6;
    const int bx   = blockIdx.x;
    const int tile = bx & 63;
    const int b    = (bx >> 6) & 7;
    const int h    = bx >> 9;
    const int i0   = tile * 16;

    // stage dst vector
    dstv[tid]       = dst1[h * RTOT + b * NN + tid];
    dstv[tid + 512] = dst1[h * RTOT + b * NN + tid + 512];
    __syncthreads();

    // phase 1: softmax rows (2 per wave), f32 two-pass, store bf16 P
#pragma unroll
    for (int rr = 0; rr < 2; ++rr) {
        const int il = wave * 2 + rr;
        const int i  = i0 + il;
        const float si = src1[h * RTOT + b * NN + i];
        const int* adjrow = adj + (size_t)b * NN * NN + (size_t)i * NN;
        float m = -INFINITY;
#pragma unroll
        for (int c = 0; c < 16; ++c) {
            const int j = lane + c * 64;
            float s = si + dstv[j];
            s = s >= 0.f ? s : ALPHA * s;
            s = adjrow[j] > 0 ? s : NEG_INF;
            m = fmaxf(m, s);
        }
#pragma unroll
        for (int o = 32; o > 0; o >>= 1) m = fmaxf(m, __shfl_xor(m, o, 64));
        float sum = 0.f;
#pragma unroll
        for (int c = 0; c < 16; ++c) {
            const int j = lane + c * 64;
            float s = si + dstv[j];
            s = s >= 0.f ? s : ALPHA * s;
            s = adjrow[j] > 0 ? s : NEG_INF;
            const float p = __expf(s - m);
            sum += p;
            P[il * PSTRIDE + j] = f2bf(p);
        }
#pragma unroll
        for (int o = 32; o > 0; o >>= 1) sum += __shfl_xor(sum, o, 64);
        if (lane == 0) rowinv[il] = 1.f / sum;
    }
    __syncthreads();

    // phase 2: C[16 x 16] = P[16 x 1024] @ WhT^T, one 16-col f-chunk per wave
    const int quad = lane >> 4, n = lane & 15;
    const int f0 = wave * 16;
    const ushortT* asrc = P + (lane & 15) * PSTRIDE + quad * 8;
    const ushortT* bsrc = WhT + ((size_t)(b * NH + h) * DH + f0 + n) * NN + quad * 8;
    f32x4 acc = {0.f, 0.f, 0.f, 0.f};
#pragma unroll 4
    for (int j0 = 0; j0 < NN; j0 += 32) {
        const bf16x8 av = *reinterpret_cast<const bf16x8*>(asrc + j0);
        const bf16x8 bv = *reinterpret_cast<const bf16x8*>(bsrc + j0);
        acc = __builtin_amdgcn_mfma_f32_16x16x32_bf16(av, bv, acc, 0, 0, 0);
    }
#pragma unroll
    for (int reg = 0; reg < 4; ++reg) {
        const int row = quad * 4 + reg;
        xcat[(size_t)(b * NN + i0 + row) * FCAT + h * DH + f0 + n] = acc[reg] * rowinv[row];
    }
}

// ---------------- Kernel D: Wh2 = xcat @ W_out (f32 out + bf16-transposed out) -------------
__global__ __launch_bounds__(256) void k_wh2(const float* __restrict__ xcat,
                                             const float* __restrict__ Wout,
                                             float* __restrict__ Wh2,
                                             ushortT* __restrict__ Wh2T) {
    __shared__ float xs[16][FCAT];         // 32 KB
    const int tid = threadIdx.x;
    const int r0  = blockIdx.x * 16;
    const float4* xsrc = (const float4*)(xcat + (size_t)r0 * FCAT);
    float4* xdst = (float4*)&xs[0][0];
#pragma unroll
    for (int t = 0; t < 8; ++t) xdst[tid + t * 256] = xsrc[tid + t * 256];
    __syncthreads();
    const int c = tid & 63, g = tid >> 6;  // 4 groups x 4 rows
    float acc[4] = {0.f, 0.f, 0.f, 0.f};
    for (int k = 0; k < FCAT; ++k) {
        const float w = Wout[(size_t)k * DOUT + c];
#pragma unroll
        for (int rr = 0; rr < 4; ++rr) acc[rr] += xs[g * 4 + rr][k] * w;
    }
#pragma unroll
    for (int rr = 0; rr < 4; ++rr)
        Wh2[(size_t)(r0 + g * 4 + rr) * DOUT + c] = acc[rr];
    const int b = r0 >> 10, jr = (r0 & 1023) + g * 4;
    union { ushortT u[4]; uint2 q; } tw;
#pragma unroll
    for (int rr = 0; rr < 4; ++rr) tw.u[rr] = f2bf(acc[rr]);
    *(uint2*)(Wh2T + ((size_t)(b * DOUT + c)) * NN + jr) = tw.q;
}

// ---------------- Kernel E: src2/dst2[r] = dot(Wh2[r], a_out halves) -----------------------
__global__ __launch_bounds__(256) void k_srcdst2(const float* __restrict__ Wh2,
                                                 const float* __restrict__ aout,
                                                 float* __restrict__ src2,
                                                 float* __restrict__ dst2) {
    const int tid = threadIdx.x;
    const int wid = tid >> 6, lane = tid & 63;
    const int r = blockIdx.x * 4 + wid;
    const float v = Wh2[(size_t)r * DOUT + lane];
    float sv = v * aout[lane];
    float dv = v * aout[64 + lane];
#pragma unroll
    for (int o = 32; o > 0; o >>= 1) {
        sv += __shfl_down(sv, o, 64);
        dv += __shfl_down(dv, o, 64);
    }
    if (lane == 0) { src2[r] = sv; dst2[r] = dv; }
}

// ---------------- Kernel F: layer-2 attention + MFMA aggregation + ELU ---------------------
__global__ __launch_bounds__(256) void k_attn2(const int* __restrict__ adj,
                                               const ushortT* __restrict__ Wh2T,
                                               const float* __restrict__ src2,
                                               const float* __restrict__ dst2,
                                               float* __restrict__ t2) {
    __shared__ ushortT P[16 * PSTRIDE];
    __shared__ float dstv[NN];
    __shared__ float rowinv[16];
    const int tid  = threadIdx.x;
    const int lane = tid & 63, wave = tid >> 6;
    const int bx   = blockIdx.x;
    const int tile = bx & 63;
    const int b    = bx >> 6;
    const int i0   = tile * 16;

#pragma unroll
    for (int t = 0; t < 4; ++t) dstv[tid + t * 256] = dst2[b * NN + tid + t * 256];
    __syncthreads();

#pragma unroll
    for (int rr = 0; rr < 4; ++rr) {
        const int il = wave * 4 + rr;
        const int i  = i0 + il;
        const float si = src2[b * NN + i];
        const int* adjrow = adj + (size_t)b * NN * NN + (size_t)i * NN;
        float m = -INFINITY;
#pragma unroll
        for (int c = 0; c < 16; ++c) {
            const int j = lane + c * 64;
            float s = si + dstv[j];
            s = s >= 0.f ? s : ALPHA * s;
            s = adjrow[j] > 0 ? s : NEG_INF;
            m = fmaxf(m, s);
        }
#pragma unroll
        for (int o = 32; o > 0; o >>= 1) m = fmaxf(m, __shfl_xor(m, o, 64));
        float sum = 0.f;
#pragma unroll
        for (int c = 0; c < 16; ++c) {
            const int j = lane + c * 64;
            float s = si + dstv[j];
            s = s >= 0.f ? s : ALPHA * s;
            s = adjrow[j] > 0 ? s : NEG_INF;
            const float p = __expf(s - m);
            sum += p;
            P[il * PSTRIDE + j] = f2bf(p);
        }
#pragma unroll
        for (int o = 32; o > 0; o >>= 1) sum += __shfl_xor(sum, o, 64);
        if (lane == 0) rowinv[il] = 1.f / sum;
    }
    __syncthreads();

    const int quad = lane >> 4, n = lane & 15;
    const int f0 = wave * 16;
    const ushortT* asrc = P + (lane & 15) * PSTRIDE + quad * 8;
    const ushortT* bsrc = Wh2T + ((size_t)(b * DOUT) + f0 + n) * NN + quad * 8;
    f32x4 acc = {0.f, 0.f, 0.f, 0.f};
#pragma unroll 4
    for (int j0 = 0; j0 < NN; j0 += 32) {
        const bf16x8 av = *reinterpret_cast<const bf16x8*>(asrc + j0);
        const bf16x8 bv = *reinterpret_cast<const bf16x8*>(bsrc + j0);
        acc = __builtin_amdgcn_mfma_f32_16x16x32_bf16(av, bv, acc, 0, 0, 0);
    }
#pragma unroll
    for (int reg = 0; reg < 4; ++reg) {
        const int row = quad * 4 + reg;
        const float v = acc[reg] * rowinv[row];
        t2[(size_t)(b * NN + i0 + row) * DOUT + f0 + n] = v > 0.f ? v : (__expf(v) - 1.f);
    }
}

// ---------------- Kernel G: out = relu(t2 @ Wf + bf) --------------------------------------
__global__ __launch_bounds__(256) void k_fc(const float* __restrict__ t2,
                                            const float* __restrict__ Wf,
                                            const float* __restrict__ bfv,
                                            float* __restrict__ out) {
    const int gid = blockIdx.x * 256 + threadIdx.x;
    const int r = gid >> 6, c = gid & 63;
    float acc = bfv[c];
    const float* row = t2 + (size_t)r * DOUT;
    for (int k = 0; k < DOUT; ++k)
        acc += row[k] * Wf[(size_t)k * DOUT + c];
    out[gid] = fmaxf(acc, 0.f);
}

extern "C" void kernel_launch(void* const* d_in, const int* in_sizes, int n_in,
                              void* d_out, int out_size, void* d_ws, size_t ws_size,
                              hipStream_t stream) {
    const float* x   = (const float*)d_in[0];
    const int*   adj = (const int*)d_in[1];
    const float* Wh  = (const float*)d_in[2];
    const float* ah  = (const float*)d_in[3];
    const float* Wo  = (const float*)d_in[4];
    const float* ao  = (const float*)d_in[5];
    const float* Wf  = (const float*)d_in[6];
    const float* bf  = (const float*)d_in[7];
    float* out = (float*)d_out;

    float* ws    = (float*)d_ws;
    float* Wh1   = ws;                          // 8192*512 f32
    float* src1  = Wh1 + (size_t)RTOT * FCAT;   // 4*8192
    float* dst1  = src1 + NH * RTOT;            // 4*8192
    float* xcat  = dst1 + NH * RTOT;            // 8192*512
    float* Wh2   = xcat + (size_t)RTOT * FCAT;  // 8192*64
    float* src2  = Wh2 + (size_t)RTOT * DOUT;   // 8192
    float* dst2  = src2 + RTOT;                 // 8192
    float* t2    = dst2 + RTOT;                 // 8192*64
    ushortT* WhT  = (ushortT*)(t2 + (size_t)RTOT * DOUT);  // 8192*512 bf16 (transposed)
    ushortT* Wh2T = WhT + (size_t)RTOT * FCAT;             // 8192*64 bf16 (transposed)

    hipLaunchKernelGGL(k_wh1,     dim3(RTOT / 16), dim3(512), 0, stream, x, Wh, Wh1, WhT);
    hipLaunchKernelGGL(k_srcdst1, dim3(NH * RTOT / 4), dim3(256), 0, stream, Wh1, ah, src1, dst1);
    hipLaunchKernelGGL(k_attn1,   dim3(NH * BSZ * (NN / 16)), dim3(512), 0, stream, adj, WhT, src1, dst1, xcat);
    hipLaunchKernelGGL(k_wh2,     dim3(RTOT / 16), dim3(256), 0, stream, xcat, Wo, Wh2, Wh2T);
    hipLaunchKernelGGL(k_srcdst2, dim3(RTOT / 4), dim3(256), 0, stream, Wh2, ao, src2, dst2);
    hipLaunchKernelGGL(k_attn2,   dim3(BSZ * (NN / 16)), dim3(256), 0, stream, adj, Wh2T, src2, dst2, t2);
    hipLaunchKernelGGL(k_fc,      dim3(RTOT * DOUT / 256), dim3(256), 0, stream, t2, Wf, bf, out);
}

// Round 4
// 244.987 us; speedup vs baseline: 2.0133x; 1.0506x over previous
//
#include <hip/hip_runtime.h>
#include <hip/hip_bf16.h>

// Shapes (fixed by reference): B=8, N=1024, Din=256, H=4, Dh=128, Do=64
#define BSZ 8
#define NN 1024
#define DIN 256
#define NH 4
#define DH 128
#define DOUT 64
#define RTOT (BSZ*NN)          // 8192 rows total
#define FCAT (NH*DH)           // 512
#define ALPHA 0.2f
#define PSTRIDE 1032           // bf16 elems per P row: 1024 + 8 pad (16B-aligned rows)

typedef unsigned short ushortT;
typedef __attribute__((ext_vector_type(8))) short bf16x8;
typedef __attribute__((ext_vector_type(4))) float f32x4;

static __device__ __forceinline__ ushortT f2bf(float f) {
    __hip_bfloat16 h = __float2bfloat16(f);
    return *reinterpret_cast<ushortT*>(&h);
}
static __device__ __forceinline__ float bfu2f(ushortT u) {
    return __uint_as_float(((unsigned)u) << 16);
}
static __device__ __forceinline__ void split2(float v, ushortT& hi, ushortT& lo) {
    hi = f2bf(v);
    lo = f2bf(v - bfu2f(hi));
}

// ---------------- prep 1: pack adj (0/1 int32) into bitmask, 1 bit per edge ---------------
__global__ __launch_bounds__(256) void k_pack(const int* __restrict__ adj,
                                              unsigned* __restrict__ adjbit) {
    const int g = blockIdx.x * 256 + threadIdx.x;     // word index, 8192*32 words
    const int row = g >> 5, w = g & 31;
    const int4* p = (const int4*)(adj + (size_t)row * NN + w * 32);
    unsigned m = 0;
#pragma unroll
    for (int q = 0; q < 8; ++q) {
        const int4 v = p[q];
        m |= (v.x > 0 ? 1u : 0u) << (q * 4 + 0);
        m |= (v.y > 0 ? 1u : 0u) << (q * 4 + 1);
        m |= (v.z > 0 ? 1u : 0u) << (q * 4 + 2);
        m |= (v.w > 0 ? 1u : 0u) << (q * 4 + 3);
    }
    adjbit[g] = m;
}

// ---------------- prep 2: transpose weights to bf16 hi/lo, k-contiguous -------------------
// WbT[h][f][k] (k=0..255) from W_heads[h][k][f];  WoT[f][k] (k=0..511) from W_out[k][f]
__global__ __launch_bounds__(256) void k_tw(const float* __restrict__ W,
                                            const float* __restrict__ Wout,
                                            ushortT* __restrict__ WbTh, ushortT* __restrict__ WbTl,
                                            ushortT* __restrict__ WoTh, ushortT* __restrict__ WoTl) {
    const int g = blockIdx.x * 256 + threadIdx.x;
    if (g < NH * DH * DIN) {
        const int h = g >> 15, rem = g & 32767, f = rem >> 8, k = rem & 255;
        const float v = W[(size_t)h * DIN * DH + (size_t)k * DH + f];
        ushortT hi, lo; split2(v, hi, lo);
        WbTh[g] = hi; WbTl[g] = lo;
    } else {
        const int g2 = g - NH * DH * DIN;
        if (g2 < DOUT * FCAT) {
            const int f = g2 >> 9, k = g2 & 511;
            const float v = Wout[(size_t)k * DOUT + f];
            ushortT hi, lo; split2(v, hi, lo);
            WoTh[g2] = hi; WoTl[g2] = lo;
        }
    }
}

// ---------------- Kernel A: Wh1 = x @ W_heads via MFMA (hi/lo), fused src1/dst1 -----------
// block: 256 thr (4 waves), 16 rows; wave w handles head h=w (128 f = 8 chunks of 16)
__global__ __launch_bounds__(256) void k_wh1(const float* __restrict__ x,
                                             const float* __restrict__ ah_,
                                             const ushortT* __restrict__ WbTh,
                                             const ushortT* __restrict__ WbTl,
                                             ushortT* __restrict__ WhT,
                                             float* __restrict__ src1,
                                             float* __restrict__ dst1) {
    __shared__ ushortT xh[16][264];
    __shared__ ushortT xl[16][264];
    const int tid = threadIdx.x;
    const int r0  = blockIdx.x * 16;
    const int b   = r0 >> 10, jr = r0 & 1023;
    // stage x tile as bf16 hi/lo
    {
        const int row = tid >> 4, c0 = (tid & 15) * 16;
        const float4* src = (const float4*)(x + (size_t)(r0 + row) * DIN + c0);
        union { ushortT u[16]; uint4 q[2]; } th, tl;
#pragma unroll
        for (int e = 0; e < 4; ++e) {
            const float4 v = src[e];
            split2(v.x, th.u[e * 4 + 0], tl.u[e * 4 + 0]);
            split2(v.y, th.u[e * 4 + 1], tl.u[e * 4 + 1]);
            split2(v.z, th.u[e * 4 + 2], tl.u[e * 4 + 2]);
            split2(v.w, th.u[e * 4 + 3], tl.u[e * 4 + 3]);
        }
        *(uint4*)&xh[row][c0] = th.q[0];
        *(uint4*)&xh[row][c0 + 8] = th.q[1];
        *(uint4*)&xl[row][c0] = tl.q[0];
        *(uint4*)&xl[row][c0 + 8] = tl.q[1];
    }
    __syncthreads();
    const int lane = tid & 63, wave = tid >> 6;
    const int quad = lane >> 4, n = lane & 15;
    const int h = wave;
    // cache A fragments (16 rows x 256 k, hi+lo)
    bf16x8 af[8], al[8];
#pragma unroll
    for (int s = 0; s < 8; ++s) {
        af[s] = *(const bf16x8*)&xh[n][quad * 8 + 32 * s];
        al[s] = *(const bf16x8*)&xl[n][quad * 8 + 32 * s];
    }
    float sacc[4] = {0, 0, 0, 0}, dacc[4] = {0, 0, 0, 0};
#pragma unroll
    for (int ch = 0; ch < 8; ++ch) {
        const int fl = ch * 16 + n;          // col within head
        const ushortT* bhp = WbTh + ((size_t)(h * DH + fl)) * DIN + quad * 8;
        const ushortT* blp = WbTl + ((size_t)(h * DH + fl)) * DIN + quad * 8;
        f32x4 acc = {0.f, 0.f, 0.f, 0.f};
#pragma unroll
        for (int s = 0; s < 8; ++s) {
            const bf16x8 bh = *(const bf16x8*)(bhp + 32 * s);
            const bf16x8 bl = *(const bf16x8*)(blp + 32 * s);
            acc = __builtin_amdgcn_mfma_f32_16x16x32_bf16(af[s], bh, acc, 0, 0, 0);
            acc = __builtin_amdgcn_mfma_f32_16x16x32_bf16(af[s], bl, acc, 0, 0, 0);
            acc = __builtin_amdgcn_mfma_f32_16x16x32_bf16(al[s], bh, acc, 0, 0, 0);
        }
        const float a_s = ah_[h * 2 * DH + fl];
        const float a_d = ah_[h * 2 * DH + DH + fl];
        union { ushortT u[4]; uint2 q; } tw;
#pragma unroll
        for (int reg = 0; reg < 4; ++reg) {
            const float v = acc[reg];
            sacc[reg] += v * a_s;
            dacc[reg] += v * a_d;
            tw.u[reg] = f2bf(v);
        }
        // WhT[(b*NH+h)*DH + fl][j]: 4 consecutive j = rows quad*4..+3
        *(uint2*)(WhT + ((size_t)((b * NH + h) * DH + fl)) * NN + jr + quad * 4) = tw.q;
    }
    // reduce src/dst over the 16 lanes of each quad
#pragma unroll
    for (int reg = 0; reg < 4; ++reg) {
        float s = sacc[reg], d = dacc[reg];
#pragma unroll
        for (int o = 8; o > 0; o >>= 1) {
            s += __shfl_xor(s, o, 64);
            d += __shfl_xor(d, o, 64);
        }
        if (n == 0) {
            src1[h * RTOT + r0 + quad * 4 + reg] = s;
            dst1[h * RTOT + r0 + quad * 4 + reg] = d;
        }
    }
}

// ---------------- Kernel C: layer-1 attention, one-pass softmax + MFMA aggregation --------
__global__ __launch_bounds__(512) void k_attn1(const unsigned* __restrict__ adjbit,
                                               const ushortT* __restrict__ WhT,
                                               const float* __restrict__ src1,
                                               const float* __restrict__ dst1,
                                               ushortT* __restrict__ xcatH,
                                               ushortT* __restrict__ xcatL) {
    __shared__ ushortT P[16 * PSTRIDE];    // 33 KB
    __shared__ float dstv[NN];             // 4 KB
    __shared__ unsigned mask[16][32];      // 2 KB
    __shared__ float rowinv[16];
    const int tid  = threadIdx.x;
    const int lane = tid & 63, wave = tid >> 6;
    const int bx   = blockIdx.x;
    const int tile = bx & 63;
    const int b    = (bx >> 6) & 7;
    const int h    = bx >> 9;
    const int i0   = tile * 16;

    dstv[tid]       = dst1[h * RTOT + b * NN + tid];
    dstv[tid + 512] = dst1[h * RTOT + b * NN + tid + 512];
    mask[tid >> 5][tid & 31] = adjbit[((size_t)(b * NN + i0 + (tid >> 5))) * 32 + (tid & 31)];
    __syncthreads();

    // one-pass softmax: m over UNMASKED scores (no adj needed); mask only gates exp
#pragma unroll
    for (int rr = 0; rr < 2; ++rr) {
        const int il = wave * 2 + rr;
        const float si = src1[h * RTOT + b * NN + i0 + il];
        float m = -INFINITY;
#pragma unroll
        for (int c = 0; c < 16; ++c) {
            float s = si + dstv[lane + c * 64];
            s = s >= 0.f ? s : ALPHA * s;
            m = fmaxf(m, s);
        }
#pragma unroll
        for (int o = 32; o > 0; o >>= 1) m = fmaxf(m, __shfl_xor(m, o, 64));
        float sum = 0.f;
#pragma unroll
        for (int c = 0; c < 16; ++c) {
            const int j = lane + c * 64;
            float s = si + dstv[j];
            s = s >= 0.f ? s : ALPHA * s;
            const unsigned bit = (mask[il][j >> 5] >> (j & 31)) & 1u;
            const float p = bit ? __expf(s - m) : 0.f;
            sum += p;
            P[il * PSTRIDE + j] = f2bf(p);
        }
#pragma unroll
        for (int o = 32; o > 0; o >>= 1) sum += __shfl_xor(sum, o, 64);
        if (lane == 0) rowinv[il] = 1.f / sum;
    }
    __syncthreads();

    // phase 2: C[16x16] per wave (f-chunk), K=1024
    const int quad = lane >> 4, n = lane & 15;
    const int f0 = wave * 16;
    const ushortT* asrc = P + n * PSTRIDE + quad * 8;
    const ushortT* bsrc = WhT + ((size_t)((b * NH + h) * DH + f0 + n)) * NN + quad * 8;
    f32x4 acc = {0.f, 0.f, 0.f, 0.f};
#pragma unroll 4
    for (int j0 = 0; j0 < NN; j0 += 32) {
        const bf16x8 av = *(const bf16x8*)(asrc + j0);
        const bf16x8 bv = *(const bf16x8*)(bsrc + j0);
        acc = __builtin_amdgcn_mfma_f32_16x16x32_bf16(av, bv, acc, 0, 0, 0);
    }
#pragma unroll
    for (int reg = 0; reg < 4; ++reg) {
        const int row = quad * 4 + reg;
        const float v = acc[reg] * rowinv[row];
        const size_t idx = (size_t)(b * NN + i0 + row) * FCAT + h * DH + f0 + n;
        ushortT hi, lo; split2(v, hi, lo);
        xcatH[idx] = hi;
        xcatL[idx] = lo;
    }
}

// ---------------- Kernel D: Wh2 = xcat @ W_out via MFMA (hi/lo) ---------------------------
__global__ __launch_bounds__(256) void k_wh2(const ushortT* __restrict__ xcatH,
                                             const ushortT* __restrict__ xcatL,
                                             const ushortT* __restrict__ WoTh,
                                             const ushortT* __restrict__ WoTl,
                                             float* __restrict__ Wh2,
                                             ushortT* __restrict__ Wh2T) {
    const int tid = threadIdx.x;
    const int r0  = blockIdx.x * 16;
    const int b   = r0 >> 10, jr = r0 & 1023;
    const int lane = tid & 63, wave = tid >> 6;
    const int quad = lane >> 4, n = lane & 15;
    const int f0 = wave * 16;
    const ushortT* ahp = xcatH + (size_t)(r0 + n) * FCAT + quad * 8;
    const ushortT* alp = xcatL + (size_t)(r0 + n) * FCAT + quad * 8;
    const ushortT* bhp = WoTh + (size_t)(f0 + n) * FCAT + quad * 8;
    const ushortT* blp = WoTl + (size_t)(f0 + n) * FCAT + quad * 8;
    f32x4 acc = {0.f, 0.f, 0.f, 0.f};
#pragma unroll
    for (int s = 0; s < 16; ++s) {
        const int off = 32 * s;
        const bf16x8 ah = *(const bf16x8*)(ahp + off);
        const bf16x8 al = *(const bf16x8*)(alp + off);
        const bf16x8 bh = *(const bf16x8*)(bhp + off);
        const bf16x8 bl = *(const bf16x8*)(blp + off);
        acc = __builtin_amdgcn_mfma_f32_16x16x32_bf16(ah, bh, acc, 0, 0, 0);
        acc = __builtin_amdgcn_mfma_f32_16x16x32_bf16(ah, bl, acc, 0, 0, 0);
        acc = __builtin_amdgcn_mfma_f32_16x16x32_bf16(al, bh, acc, 0, 0, 0);
    }
    union { ushortT u[4]; uint2 q; } tw;
#pragma unroll
    for (int reg = 0; reg < 4; ++reg) {
        const int row = quad * 4 + reg;
        Wh2[(size_t)(r0 + row) * DOUT + f0 + n] = acc[reg];
        tw.u[reg] = f2bf(acc[reg]);
    }
    *(uint2*)(Wh2T + ((size_t)(b * DOUT + f0 + n)) * NN + jr + quad * 4) = tw.q;
}

// ---------------- Kernel E: src2/dst2[r] = dot(Wh2[r], a_out halves) -----------------------
__global__ __launch_bounds__(256) void k_srcdst2(const float* __restrict__ Wh2,
                                                 const float* __restrict__ aout,
                                                 float* __restrict__ src2,
                                                 float* __restrict__ dst2) {
    const int tid = threadIdx.x;
    const int wid = tid >> 6, lane = tid & 63;
    const int r = blockIdx.x * 4 + wid;
    const float v = Wh2[(size_t)r * DOUT + lane];
    float sv = v * aout[lane];
    float dv = v * aout[64 + lane];
#pragma unroll
    for (int o = 32; o > 0; o >>= 1) {
        sv += __shfl_down(sv, o, 64);
        dv += __shfl_down(dv, o, 64);
    }
    if (lane == 0) { src2[r] = sv; dst2[r] = dv; }
}

// ---------------- Kernel F: layer-2 attention (one-pass) + MFMA + ELU ----------------------
__global__ __launch_bounds__(256) void k_attn2(const unsigned* __restrict__ adjbit,
                                               const ushortT* __restrict__ Wh2T,
                                               const float* __restrict__ src2,
                                               const float* __restrict__ dst2,
                                               float* __restrict__ t2) {
    __shared__ ushortT P[16 * PSTRIDE];
    __shared__ float dstv[NN];
    __shared__ unsigned mask[16][32];
    __shared__ float rowinv[16];
    const int tid  = threadIdx.x;
    const int lane = tid & 63, wave = tid >> 6;
    const int tile = blockIdx.x & 63;
    const int b    = blockIdx.x >> 6;
    const int i0   = tile * 16;

#pragma unroll
    for (int t = 0; t < 4; ++t) dstv[tid + t * 256] = dst2[b * NN + tid + t * 256];
#pragma unroll
    for (int t = 0; t < 2; ++t) {
        const int g = tid + t * 256;
        mask[g >> 5][g & 31] = adjbit[((size_t)(b * NN + i0 + (g >> 5))) * 32 + (g & 31)];
    }
    __syncthreads();

#pragma unroll
    for (int rr = 0; rr < 4; ++rr) {
        const int il = wave * 4 + rr;
        const float si = src2[b * NN + i0 + il];
        float m = -INFINITY;
#pragma unroll
        for (int c = 0; c < 16; ++c) {
            float s = si + dstv[lane + c * 64];
            s = s >= 0.f ? s : ALPHA * s;
            m = fmaxf(m, s);
        }
#pragma unroll
        for (int o = 32; o > 0; o >>= 1) m = fmaxf(m, __shfl_xor(m, o, 64));
        float sum = 0.f;
#pragma unroll
        for (int c = 0; c < 16; ++c) {
            const int j = lane + c * 64;
            float s = si + dstv[j];
            s = s >= 0.f ? s : ALPHA * s;
            const unsigned bit = (mask[il][j >> 5] >> (j & 31)) & 1u;
            const float p = bit ? __expf(s - m) : 0.f;
            sum += p;
            P[il * PSTRIDE + j] = f2bf(p);
        }
#pragma unroll
        for (int o = 32; o > 0; o >>= 1) sum += __shfl_xor(sum, o, 64);
        if (lane == 0) rowinv[il] = 1.f / sum;
    }
    __syncthreads();

    const int quad = lane >> 4, n = lane & 15;
    const int f0 = wave * 16;
    const ushortT* asrc = P + n * PSTRIDE + quad * 8;
    const ushortT* bsrc = Wh2T + ((size_t)(b * DOUT + f0 + n)) * NN + quad * 8;
    f32x4 acc = {0.f, 0.f, 0.f, 0.f};
#pragma unroll 4
    for (int j0 = 0; j0 < NN; j0 += 32) {
        const bf16x8 av = *(const bf16x8*)(asrc + j0);
        const bf16x8 bv = *(const bf16x8*)(bsrc + j0);
        acc = __builtin_amdgcn_mfma_f32_16x16x32_bf16(av, bv, acc, 0, 0, 0);
    }
#pragma unroll
    for (int reg = 0; reg < 4; ++reg) {
        const int row = quad * 4 + reg;
        const float v = acc[reg] * rowinv[row];
        t2[(size_t)(b * NN + i0 + row) * DOUT + f0 + n] = v > 0.f ? v : (__expf(v) - 1.f);
    }
}

// ---------------- Kernel G: out = relu(t2 @ Wf + bf) --------------------------------------
__global__ __launch_bounds__(256) void k_fc(const float* __restrict__ t2,
                                            const float* __restrict__ Wf,
                                            const float* __restrict__ bfv,
                                            float* __restrict__ out) {
    const int gid = blockIdx.x * 256 + threadIdx.x;
    const int r = gid >> 6, c = gid & 63;
    float acc = bfv[c];
    const float* row = t2 + (size_t)r * DOUT;
    for (int k = 0; k < DOUT; ++k)
        acc += row[k] * Wf[(size_t)k * DOUT + c];
    out[gid] = fmaxf(acc, 0.f);
}

extern "C" void kernel_launch(void* const* d_in, const int* in_sizes, int n_in,
                              void* d_out, int out_size, void* d_ws, size_t ws_size,
                              hipStream_t stream) {
    const float* x   = (const float*)d_in[0];
    const int*   adj = (const int*)d_in[1];
    const float* Wh  = (const float*)d_in[2];
    const float* ah  = (const float*)d_in[3];
    const float* Wo  = (const float*)d_in[4];
    const float* ao  = (const float*)d_in[5];
    const float* Wf  = (const float*)d_in[6];
    const float* bf  = (const float*)d_in[7];
    float* out = (float*)d_out;

    float* ws   = (float*)d_ws;
    float* src1 = ws;                                  // 4*8192
    float* dst1 = src1 + NH * RTOT;                    // 4*8192
    float* Wh2  = dst1 + NH * RTOT;                    // 8192*64
    float* src2 = Wh2 + (size_t)RTOT * DOUT;           // 8192
    float* dst2 = src2 + RTOT;                         // 8192
    float* t2   = dst2 + RTOT;                         // 8192*64
    ushortT* xcatH = (ushortT*)(t2 + (size_t)RTOT * DOUT);   // 8192*512
    ushortT* xcatL = xcatH + (size_t)RTOT * FCAT;            // 8192*512
    ushortT* WhT   = xcatL + (size_t)RTOT * FCAT;            // 8192*512
    ushortT* Wh2T  = WhT + (size_t)RTOT * FCAT;              // 8192*64
    ushortT* WbTh  = Wh2T + (size_t)RTOT * DOUT;             // 4*128*256
    ushortT* WbTl  = WbTh + NH * DH * DIN;
    ushortT* WoTh  = WbTl + NH * DH * DIN;                   // 64*512
    ushortT* WoTl  = WoTh + DOUT * FCAT;
    unsigned* adjbit = (unsigned*)(WoTl + DOUT * FCAT);      // 8192*32 words

    hipLaunchKernelGGL(k_pack,    dim3(RTOT * 32 / 256), dim3(256), 0, stream, adj, adjbit);
    hipLaunchKernelGGL(k_tw,      dim3((NH * DH * DIN + DOUT * FCAT + 255) / 256), dim3(256), 0, stream,
                       Wh, Wo, WbTh, WbTl, WoTh, WoTl);
    hipLaunchKernelGGL(k_wh1,     dim3(RTOT / 16), dim3(256), 0, stream,
                       x, ah, WbTh, WbTl, WhT, src1, dst1);
    hipLaunchKernelGGL(k_attn1,   dim3(NH * BSZ * (NN / 16)), dim3(512), 0, stream,
                       adjbit, WhT, src1, dst1, xcatH, xcatL);
    hipLaunchKernelGGL(k_wh2,     dim3(RTOT / 16), dim3(256), 0, stream,
                       xcatH, xcatL, WoTh, WoTl, Wh2, Wh2T);
    hipLaunchKernelGGL(k_srcdst2, dim3(RTOT / 4), dim3(256), 0, stream, Wh2, ao, src2, dst2);
    hipLaunchKernelGGL(k_attn2,   dim3(BSZ * (NN / 16)), dim3(256), 0, stream,
                       adjbit, Wh2T, src2, dst2, t2);
    hipLaunchKernelGGL(k_fc,      dim3(RTOT * DOUT / 256), dim3(256), 0, stream, t2, Wf, bf, out);
}

// Round 5
// 221.535 us; speedup vs baseline: 2.2264x; 1.1059x over previous
//
#include <hip/hip_runtime.h>
#include <hip/hip_bf16.h>

// Shapes (fixed by reference): B=8, N=1024, Din=256, H=4, Dh=128, Do=64
#define BSZ 8
#define NN 1024
#define DIN 256
#define NH 4
#define DH 128
#define DOUT 64
#define RTOT (BSZ*NN)          // 8192 rows total
#define FCAT (NH*DH)           // 512
#define ALPHA 0.2f

typedef unsigned short ushortT;
typedef __attribute__((ext_vector_type(8))) short bf16x8;
typedef __attribute__((ext_vector_type(4))) float f32x4;

static __device__ __forceinline__ ushortT f2bf(float f) {
    __hip_bfloat16 h = __float2bfloat16(f);
    return *reinterpret_cast<ushortT*>(&h);
}
static __device__ __forceinline__ float bfu2f(ushortT u) {
    return __uint_as_float(((unsigned)u) << 16);
}
static __device__ __forceinline__ void split2(float v, ushortT& hi, ushortT& lo) {
    hi = f2bf(v);
    lo = f2bf(v - bfu2f(hi));
}
// async global->LDS, 16B per lane; LDS dest = l + lane*16 (wave-uniform l)
static __device__ __forceinline__ void gload16(const ushortT* g, ushortT* l) {
    __builtin_amdgcn_global_load_lds(
        (const __attribute__((address_space(1))) unsigned int*)(const void*)g,
        (__attribute__((address_space(3))) unsigned int*)(void*)l, 16, 0, 0);
}

// ---------------- prep 1: pack adj (0/1 int32) into bitmask, 1 bit per edge ---------------
__global__ __launch_bounds__(256) void k_pack(const int* __restrict__ adj,
                                              unsigned* __restrict__ adjbit) {
    const int g = blockIdx.x * 256 + threadIdx.x;     // word index, 8192*32 words
    const int row = g >> 5, w = g & 31;
    const int4* p = (const int4*)(adj + (size_t)row * NN + w * 32);
    unsigned m = 0;
#pragma unroll
    for (int q = 0; q < 8; ++q) {
        const int4 v = p[q];
        m |= (v.x > 0 ? 1u : 0u) << (q * 4 + 0);
        m |= (v.y > 0 ? 1u : 0u) << (q * 4 + 1);
        m |= (v.z > 0 ? 1u : 0u) << (q * 4 + 2);
        m |= (v.w > 0 ? 1u : 0u) << (q * 4 + 3);
    }
    adjbit[g] = m;
}

// ---------------- prep 2: transpose weights to bf16 hi/lo, k-contiguous -------------------
__global__ __launch_bounds__(256) void k_tw(const float* __restrict__ W,
                                            const float* __restrict__ Wout,
                                            ushortT* __restrict__ WbTh, ushortT* __restrict__ WbTl,
                                            ushortT* __restrict__ WoTh, ushortT* __restrict__ WoTl) {
    const int g = blockIdx.x * 256 + threadIdx.x;
    if (g < NH * DH * DIN) {
        const int h = g >> 15, rem = g & 32767, f = rem >> 8, k = rem & 255;
        const float v = W[(size_t)h * DIN * DH + (size_t)k * DH + f];
        ushortT hi, lo; split2(v, hi, lo);
        WbTh[g] = hi; WbTl[g] = lo;
    } else {
        const int g2 = g - NH * DH * DIN;
        if (g2 < DOUT * FCAT) {
            const int f = g2 >> 9, k = g2 & 511;
            const float v = Wout[(size_t)k * DOUT + f];
            ushortT hi, lo; split2(v, hi, lo);
            WoTh[g2] = hi; WoTl[g2] = lo;
        }
    }
}

// ---------------- Kernel A: Wh1 = x @ W_heads via MFMA (hi/lo), fused src1/dst1 -----------
__global__ __launch_bounds__(256) void k_wh1(const float* __restrict__ x,
                                             const float* __restrict__ ah_,
                                             const ushortT* __restrict__ WbTh,
                                             const ushortT* __restrict__ WbTl,
                                             ushortT* __restrict__ WhT,
                                             float* __restrict__ src1,
                                             float* __restrict__ dst1) {
    __shared__ ushortT xh[16][264];
    __shared__ ushortT xl[16][264];
    const int tid = threadIdx.x;
    const int r0  = blockIdx.x * 16;
    const int b   = r0 >> 10, jr = r0 & 1023;
    {
        const int row = tid >> 4, c0 = (tid & 15) * 16;
        const float4* src = (const float4*)(x + (size_t)(r0 + row) * DIN + c0);
        union { ushortT u[16]; uint4 q[2]; } th, tl;
#pragma unroll
        for (int e = 0; e < 4; ++e) {
            const float4 v = src[e];
            split2(v.x, th.u[e * 4 + 0], tl.u[e * 4 + 0]);
            split2(v.y, th.u[e * 4 + 1], tl.u[e * 4 + 1]);
            split2(v.z, th.u[e * 4 + 2], tl.u[e * 4 + 2]);
            split2(v.w, th.u[e * 4 + 3], tl.u[e * 4 + 3]);
        }
        *(uint4*)&xh[row][c0] = th.q[0];
        *(uint4*)&xh[row][c0 + 8] = th.q[1];
        *(uint4*)&xl[row][c0] = tl.q[0];
        *(uint4*)&xl[row][c0 + 8] = tl.q[1];
    }
    __syncthreads();
    const int lane = tid & 63, wave = tid >> 6;
    const int quad = lane >> 4, n = lane & 15;
    const int h = wave;
    bf16x8 af[8], al[8];
#pragma unroll
    for (int s = 0; s < 8; ++s) {
        af[s] = *(const bf16x8*)&xh[n][quad * 8 + 32 * s];
        al[s] = *(const bf16x8*)&xl[n][quad * 8 + 32 * s];
    }
    float sacc[4] = {0, 0, 0, 0}, dacc[4] = {0, 0, 0, 0};
#pragma unroll
    for (int ch = 0; ch < 8; ++ch) {
        const int fl = ch * 16 + n;
        const ushortT* bhp = WbTh + ((size_t)(h * DH + fl)) * DIN + quad * 8;
        const ushortT* blp = WbTl + ((size_t)(h * DH + fl)) * DIN + quad * 8;
        f32x4 acc = {0.f, 0.f, 0.f, 0.f};
#pragma unroll
        for (int s = 0; s < 8; ++s) {
            const bf16x8 bh = *(const bf16x8*)(bhp + 32 * s);
            const bf16x8 bl = *(const bf16x8*)(blp + 32 * s);
            acc = __builtin_amdgcn_mfma_f32_16x16x32_bf16(af[s], bh, acc, 0, 0, 0);
            acc = __builtin_amdgcn_mfma_f32_16x16x32_bf16(af[s], bl, acc, 0, 0, 0);
            acc = __builtin_amdgcn_mfma_f32_16x16x32_bf16(al[s], bh, acc, 0, 0, 0);
        }
        const float a_s = ah_[h * 2 * DH + fl];
        const float a_d = ah_[h * 2 * DH + DH + fl];
        union { ushortT u[4]; uint2 q; } tw;
#pragma unroll
        for (int reg = 0; reg < 4; ++reg) {
            const float v = acc[reg];
            sacc[reg] += v * a_s;
            dacc[reg] += v * a_d;
            tw.u[reg] = f2bf(v);
        }
        *(uint2*)(WhT + ((size_t)((b * NH + h) * DH + fl)) * NN + jr + quad * 4) = tw.q;
    }
#pragma unroll
    for (int reg = 0; reg < 4; ++reg) {
        float s = sacc[reg], d = dacc[reg];
#pragma unroll
        for (int o = 8; o > 0; o >>= 1) {
            s += __shfl_xor(s, o, 64);
            d += __shfl_xor(d, o, 64);
        }
        if (n == 0) {
            src1[h * RTOT + r0 + quad * 4 + reg] = s;
            dst1[h * RTOT + r0 + quad * 4 + reg] = d;
        }
    }
}

// ---------------- softmax layer 1: one wave = 4 rows, dst in regs, write bf16 P -----------
__global__ __launch_bounds__(256) void k_soft1(const unsigned* __restrict__ adjbit,
                                               const float* __restrict__ src1,
                                               const float* __restrict__ dst1,
                                               ushortT* __restrict__ P1,
                                               float* __restrict__ rinv1) {
    const int tid = threadIdx.x, lane = tid & 63, wave = tid >> 6;
    const int tile = blockIdx.x & 63;
    const int hb = blockIdx.x >> 6;        // h*8 + b
    const int h = hb >> 3, b = hb & 7;
    const int i0 = tile * 16 + wave * 4;
    const float* dp = dst1 + h * RTOT + b * NN;
    float d[16];
    {
        const float4 v0 = *(const float4*)(dp + lane * 8);
        const float4 v1 = *(const float4*)(dp + lane * 8 + 4);
        const float4 v2 = *(const float4*)(dp + 512 + lane * 8);
        const float4 v3 = *(const float4*)(dp + 512 + lane * 8 + 4);
        d[0]=v0.x; d[1]=v0.y; d[2]=v0.z; d[3]=v0.w;
        d[4]=v1.x; d[5]=v1.y; d[6]=v1.z; d[7]=v1.w;
        d[8]=v2.x; d[9]=v2.y; d[10]=v2.z; d[11]=v2.w;
        d[12]=v3.x; d[13]=v3.y; d[14]=v3.z; d[15]=v3.w;
    }
    const float* sp = src1 + h * RTOT + b * NN;
#pragma unroll
    for (int rr = 0; rr < 4; ++rr) {
        const int i = i0 + rr;
        const float si = sp[i];
        float s[16]; float m = -INFINITY;
#pragma unroll
        for (int e = 0; e < 16; ++e) {
            float v = si + d[e];
            v = v >= 0.f ? v : ALPHA * v;
            s[e] = v;
            m = fmaxf(m, v);
        }
#pragma unroll
        for (int o = 32; o > 0; o >>= 1) m = fmaxf(m, __shfl_xor(m, o, 64));
        const unsigned w0 = adjbit[(size_t)(b * NN + i) * 32 + (lane >> 2)] >> ((lane & 3) * 8);
        const unsigned w1 = adjbit[(size_t)(b * NN + i) * 32 + 16 + (lane >> 2)] >> ((lane & 3) * 8);
        float sum = 0.f;
        union { ushortT u[16]; uint4 q[2]; } t;
#pragma unroll
        for (int e = 0; e < 8; ++e) {
            const float p = ((w0 >> e) & 1u) ? __expf(s[e] - m) : 0.f;
            sum += p; t.u[e] = f2bf(p);
        }
#pragma unroll
        for (int e = 0; e < 8; ++e) {
            const float p = ((w1 >> e) & 1u) ? __expf(s[8 + e] - m) : 0.f;
            sum += p; t.u[8 + e] = f2bf(p);
        }
#pragma unroll
        for (int o = 32; o > 0; o >>= 1) sum += __shfl_xor(sum, o, 64);
        ushortT* prow = P1 + (size_t)((b * NH + h) * NN + i) * NN;
        *(uint4*)(prow + lane * 8) = t.q[0];
        *(uint4*)(prow + 512 + lane * 8) = t.q[1];
        if (lane == 0) rinv1[(size_t)(b * NH + h) * NN + i] = 1.f / sum;
    }
}

// ---------------- GEMM layer 1: xcat[i, h*128+f] = (P1 @ WhT^T) * rinv1 -------------------
// grid 256: bhp = bx>>3 (b*4+h), itile = bx&7. block 512 = 8 waves, tile M=128 F=128, BK=64.
__global__ __launch_bounds__(512) void k_pv1(const ushortT* __restrict__ P1,
                                             const ushortT* __restrict__ WhT,
                                             const float* __restrict__ rinv1,
                                             ushortT* __restrict__ xcatH,
                                             ushortT* __restrict__ xcatL) {
    __shared__ ushortT As[128 * 64];
    __shared__ ushortT Bs[128 * 64];
    const int tid = threadIdx.x, lane = tid & 63, wave = tid >> 6;
    const int itile = blockIdx.x & 7, bhp = blockIdx.x >> 3;
    const int b = bhp >> 2, h = bhp & 3;
    const int i0 = itile * 128;
    const int m16 = lane & 15, quad = lane >> 4;
    const int mg = wave >> 1, fg = wave & 1;
    const ushortT* Pbase = P1 + (size_t)(bhp * NN + i0) * NN;
    const ushortT* Bbase = WhT + (size_t)(bhp * DH) * NN;
    const int srow = lane >> 3;               // staging row within 8
    const int scol = (lane & 7) ^ srow;       // swizzled global chunk
    f32x4 acc[2][4];
#pragma unroll
    for (int a = 0; a < 2; ++a)
#pragma unroll
        for (int c = 0; c < 4; ++c) acc[a][c] = (f32x4){0.f, 0.f, 0.f, 0.f};

    for (int kt = 0; kt < 16; ++kt) {
        __syncthreads();
        const int kbase = kt * 64 + scol * 8;
        gload16(Pbase + (size_t)(wave * 16 + srow) * NN + kbase,     As + (wave * 16) * 64);
        gload16(Pbase + (size_t)(wave * 16 + 8 + srow) * NN + kbase, As + (wave * 16 + 8) * 64);
        gload16(Bbase + (size_t)(wave * 16 + srow) * NN + kbase,     Bs + (wave * 16) * 64);
        gload16(Bbase + (size_t)(wave * 16 + 8 + srow) * NN + kbase, Bs + (wave * 16 + 8) * 64);
        __syncthreads();
#pragma unroll
        for (int ks = 0; ks < 2; ++ks) {
            bf16x8 afr[2], bfr[4];
#pragma unroll
            for (int ms = 0; ms < 2; ++ms) {
                const int row = (mg * 2 + ms) * 16 + m16;
                const int cl = (ks * 4 + quad) ^ (row & 7);
                afr[ms] = *(const bf16x8*)&As[row * 64 + cl * 8];
            }
#pragma unroll
            for (int fs = 0; fs < 4; ++fs) {
                const int row = (fg * 4 + fs) * 16 + m16;
                const int cl = (ks * 4 + quad) ^ (row & 7);
                bfr[fs] = *(const bf16x8*)&Bs[row * 64 + cl * 8];
            }
#pragma unroll
            for (int ms = 0; ms < 2; ++ms)
#pragma unroll
                for (int fs = 0; fs < 4; ++fs)
                    acc[ms][fs] = __builtin_amdgcn_mfma_f32_16x16x32_bf16(afr[ms], bfr[fs], acc[ms][fs], 0, 0, 0);
        }
    }
    // epilogue: normalize and write hi/lo bf16 xcat
#pragma unroll
    for (int ms = 0; ms < 2; ++ms) {
        float rv[4];
#pragma unroll
        for (int reg = 0; reg < 4; ++reg)
            rv[reg] = rinv1[(size_t)bhp * NN + i0 + (mg * 2 + ms) * 16 + quad * 4 + reg];
#pragma unroll
        for (int fs = 0; fs < 4; ++fs) {
            const int f = h * DH + (fg * 4 + fs) * 16 + m16;
#pragma unroll
            for (int reg = 0; reg < 4; ++reg) {
                const int i = i0 + (mg * 2 + ms) * 16 + quad * 4 + reg;
                const float v = acc[ms][fs][reg] * rv[reg];
                const size_t idx = (size_t)(b * NN + i) * FCAT + f;
                ushortT hi, lo; split2(v, hi, lo);
                xcatH[idx] = hi;
                xcatL[idx] = lo;
            }
        }
    }
}

// ---------------- Kernel D: Wh2 = xcat @ W_out via MFMA (hi/lo) ---------------------------
__global__ __launch_bounds__(256) void k_wh2(const ushortT* __restrict__ xcatH,
                                             const ushortT* __restrict__ xcatL,
                                             const ushortT* __restrict__ WoTh,
                                             const ushortT* __restrict__ WoTl,
                                             float* __restrict__ Wh2,
                                             ushortT* __restrict__ Wh2T) {
    const int tid = threadIdx.x;
    const int r0  = blockIdx.x * 16;
    const int b   = r0 >> 10, jr = r0 & 1023;
    const int lane = tid & 63, wave = tid >> 6;
    const int quad = lane >> 4, n = lane & 15;
    const int f0 = wave * 16;
    const ushortT* ahp = xcatH + (size_t)(r0 + n) * FCAT + quad * 8;
    const ushortT* alp = xcatL + (size_t)(r0 + n) * FCAT + quad * 8;
    const ushortT* bhp = WoTh + (size_t)(f0 + n) * FCAT + quad * 8;
    const ushortT* blp = WoTl + (size_t)(f0 + n) * FCAT + quad * 8;
    f32x4 acc = {0.f, 0.f, 0.f, 0.f};
#pragma unroll
    for (int s = 0; s < 16; ++s) {
        const int off = 32 * s;
        const bf16x8 ah = *(const bf16x8*)(ahp + off);
        const bf16x8 al = *(const bf16x8*)(alp + off);
        const bf16x8 bh = *(const bf16x8*)(bhp + off);
        const bf16x8 bl = *(const bf16x8*)(blp + off);
        acc = __builtin_amdgcn_mfma_f32_16x16x32_bf16(ah, bh, acc, 0, 0, 0);
        acc = __builtin_amdgcn_mfma_f32_16x16x32_bf16(ah, bl, acc, 0, 0, 0);
        acc = __builtin_amdgcn_mfma_f32_16x16x32_bf16(al, bh, acc, 0, 0, 0);
    }
    union { ushortT u[4]; uint2 q; } tw;
#pragma unroll
    for (int reg = 0; reg < 4; ++reg) {
        const int row = quad * 4 + reg;
        Wh2[(size_t)(r0 + row) * DOUT + f0 + n] = acc[reg];
        tw.u[reg] = f2bf(acc[reg]);
    }
    *(uint2*)(Wh2T + ((size_t)(b * DOUT + f0 + n)) * NN + jr + quad * 4) = tw.q;
}

// ---------------- Kernel E: src2/dst2[r] = dot(Wh2[r], a_out halves) -----------------------
__global__ __launch_bounds__(256) void k_srcdst2(const float* __restrict__ Wh2,
                                                 const float* __restrict__ aout,
                                                 float* __restrict__ src2,
                                                 float* __restrict__ dst2) {
    const int tid = threadIdx.x;
    const int wid = tid >> 6, lane = tid & 63;
    const int r = blockIdx.x * 4 + wid;
    const float v = Wh2[(size_t)r * DOUT + lane];
    float sv = v * aout[lane];
    float dv = v * aout[64 + lane];
#pragma unroll
    for (int o = 32; o > 0; o >>= 1) {
        sv += __shfl_down(sv, o, 64);
        dv += __shfl_down(dv, o, 64);
    }
    if (lane == 0) { src2[r] = sv; dst2[r] = dv; }
}

// ---------------- softmax layer 2 ----------------------------------------------------------
__global__ __launch_bounds__(256) void k_soft2(const unsigned* __restrict__ adjbit,
                                               const float* __restrict__ src2,
                                               const float* __restrict__ dst2,
                                               ushortT* __restrict__ P2,
                                               float* __restrict__ rinv2) {
    const int tid = threadIdx.x, lane = tid & 63, wave = tid >> 6;
    const int tile = blockIdx.x & 63;
    const int b = blockIdx.x >> 6;
    const int i0 = tile * 16 + wave * 4;
    const float* dp = dst2 + b * NN;
    float d[16];
    {
        const float4 v0 = *(const float4*)(dp + lane * 8);
        const float4 v1 = *(const float4*)(dp + lane * 8 + 4);
        const float4 v2 = *(const float4*)(dp + 512 + lane * 8);
        const float4 v3 = *(const float4*)(dp + 512 + lane * 8 + 4);
        d[0]=v0.x; d[1]=v0.y; d[2]=v0.z; d[3]=v0.w;
        d[4]=v1.x; d[5]=v1.y; d[6]=v1.z; d[7]=v1.w;
        d[8]=v2.x; d[9]=v2.y; d[10]=v2.z; d[11]=v2.w;
        d[12]=v3.x; d[13]=v3.y; d[14]=v3.z; d[15]=v3.w;
    }
#pragma unroll
    for (int rr = 0; rr < 4; ++rr) {
        const int i = i0 + rr;
        const float si = src2[b * NN + i];
        float s[16]; float m = -INFINITY;
#pragma unroll
        for (int e = 0; e < 16; ++e) {
            float v = si + d[e];
            v = v >= 0.f ? v : ALPHA * v;
            s[e] = v;
            m = fmaxf(m, v);
        }
#pragma unroll
        for (int o = 32; o > 0; o >>= 1) m = fmaxf(m, __shfl_xor(m, o, 64));
        const unsigned w0 = adjbit[(size_t)(b * NN + i) * 32 + (lane >> 2)] >> ((lane & 3) * 8);
        const unsigned w1 = adjbit[(size_t)(b * NN + i) * 32 + 16 + (lane >> 2)] >> ((lane & 3) * 8);
        float sum = 0.f;
        union { ushortT u[16]; uint4 q[2]; } t;
#pragma unroll
        for (int e = 0; e < 8; ++e) {
            const float p = ((w0 >> e) & 1u) ? __expf(s[e] - m) : 0.f;
            sum += p; t.u[e] = f2bf(p);
        }
#pragma unroll
        for (int e = 0; e < 8; ++e) {
            const float p = ((w1 >> e) & 1u) ? __expf(s[8 + e] - m) : 0.f;
            sum += p; t.u[8 + e] = f2bf(p);
        }
#pragma unroll
        for (int o = 32; o > 0; o >>= 1) sum += __shfl_xor(sum, o, 64);
        ushortT* prow = P2 + (size_t)(b * NN + i) * NN;
        *(uint4*)(prow + lane * 8) = t.q[0];
        *(uint4*)(prow + 512 + lane * 8) = t.q[1];
        if (lane == 0) rinv2[(size_t)b * NN + i] = 1.f / sum;
    }
}

// ---------------- GEMM layer 2: t2 = elu((P2 @ Wh2T^T) * rinv2) ---------------------------
// grid 128: b = bx>>4, itile = bx&15. block 256 = 4 waves, tile M=64 F=64, BK=64.
__global__ __launch_bounds__(256) void k_pv2(const ushortT* __restrict__ P2,
                                             const ushortT* __restrict__ Wh2T,
                                             const float* __restrict__ rinv2,
                                             float* __restrict__ t2) {
    __shared__ ushortT As[64 * 64];
    __shared__ ushortT Bs[64 * 64];
    const int tid = threadIdx.x, lane = tid & 63, wave = tid >> 6;
    const int itile = blockIdx.x & 15, b = blockIdx.x >> 4;
    const int i0 = itile * 64;
    const int m16 = lane & 15, quad = lane >> 4;
    const ushortT* Pbase = P2 + (size_t)(b * NN + i0) * NN;
    const ushortT* Bbase = Wh2T + (size_t)(b * DOUT) * NN;
    const int srow = lane >> 3;
    const int scol = (lane & 7) ^ srow;
    f32x4 acc[4];
#pragma unroll
    for (int c = 0; c < 4; ++c) acc[c] = (f32x4){0.f, 0.f, 0.f, 0.f};

    for (int kt = 0; kt < 16; ++kt) {
        __syncthreads();
        const int kbase = kt * 64 + scol * 8;
        gload16(Pbase + (size_t)(wave * 16 + srow) * NN + kbase,     As + (wave * 16) * 64);
        gload16(Pbase + (size_t)(wave * 16 + 8 + srow) * NN + kbase, As + (wave * 16 + 8) * 64);
        gload16(Bbase + (size_t)(wave * 16 + srow) * NN + kbase,     Bs + (wave * 16) * 64);
        gload16(Bbase + (size_t)(wave * 16 + 8 + srow) * NN + kbase, Bs + (wave * 16 + 8) * 64);
        __syncthreads();
#pragma unroll
        for (int ks = 0; ks < 2; ++ks) {
            const int arow = wave * 16 + m16;
            const int acl = (ks * 4 + quad) ^ (arow & 7);
            const bf16x8 afr = *(const bf16x8*)&As[arow * 64 + acl * 8];
#pragma unroll
            for (int fs = 0; fs < 4; ++fs) {
                const int row = fs * 16 + m16;
                const int cl = (ks * 4 + quad) ^ (row & 7);
                const bf16x8 bfr = *(const bf16x8*)&Bs[row * 64 + cl * 8];
                acc[fs] = __builtin_amdgcn_mfma_f32_16x16x32_bf16(afr, bfr, acc[fs], 0, 0, 0);
            }
        }
    }
    float rv[4];
#pragma unroll
    for (int reg = 0; reg < 4; ++reg)
        rv[reg] = rinv2[(size_t)b * NN + i0 + wave * 16 + quad * 4 + reg];
#pragma unroll
    for (int fs = 0; fs < 4; ++fs) {
        const int f = fs * 16 + m16;
#pragma unroll
        for (int reg = 0; reg < 4; ++reg) {
            const int i = i0 + wave * 16 + quad * 4 + reg;
            const float v = acc[fs][reg] * rv[reg];
            t2[(size_t)(b * NN + i) * DOUT + f] = v > 0.f ? v : (__expf(v) - 1.f);
        }
    }
}

// ---------------- Kernel G: out = relu(t2 @ Wf + bf) --------------------------------------
__global__ __launch_bounds__(256) void k_fc(const float* __restrict__ t2,
                                            const float* __restrict__ Wf,
                                            const float* __restrict__ bfv,
                                            float* __restrict__ out) {
    const int gid = blockIdx.x * 256 + threadIdx.x;
    const int r = gid >> 6, c = gid & 63;
    float acc = bfv[c];
    const float* row = t2 + (size_t)r * DOUT;
    for (int k = 0; k < DOUT; ++k)
        acc += row[k] * Wf[(size_t)k * DOUT + c];
    out[gid] = fmaxf(acc, 0.f);
}

extern "C" void kernel_launch(void* const* d_in, const int* in_sizes, int n_in,
                              void* d_out, int out_size, void* d_ws, size_t ws_size,
                              hipStream_t stream) {
    const float* x   = (const float*)d_in[0];
    const int*   adj = (const int*)d_in[1];
    const float* Wh  = (const float*)d_in[2];
    const float* ah  = (const float*)d_in[3];
    const float* Wo  = (const float*)d_in[4];
    const float* ao  = (const float*)d_in[5];
    const float* Wf  = (const float*)d_in[6];
    const float* bf  = (const float*)d_in[7];
    float* out = (float*)d_out;

    float* ws    = (float*)d_ws;
    float* src1  = ws;                                 // 4*8192
    float* dst1  = src1 + NH * RTOT;                   // 4*8192
    float* Wh2   = dst1 + NH * RTOT;                   // 8192*64
    float* src2  = Wh2 + (size_t)RTOT * DOUT;          // 8192
    float* dst2  = src2 + RTOT;                        // 8192
    float* t2    = dst2 + RTOT;                        // 8192*64
    float* rinv1 = t2 + (size_t)RTOT * DOUT;           // 4*8192
    float* rinv2 = rinv1 + NH * RTOT;                  // 8192
    ushortT* xcatH = (ushortT*)(rinv2 + RTOT);               // 8192*512
    ushortT* xcatL = xcatH + (size_t)RTOT * FCAT;            // 8192*512
    ushortT* WhT   = xcatL + (size_t)RTOT * FCAT;            // 8192*512
    ushortT* Wh2T  = WhT + (size_t)RTOT * FCAT;              // 8192*64
    ushortT* WbTh  = Wh2T + (size_t)RTOT * DOUT;             // 4*128*256
    ushortT* WbTl  = WbTh + NH * DH * DIN;
    ushortT* WoTh  = WbTl + NH * DH * DIN;                   // 64*512
    ushortT* WoTl  = WoTh + DOUT * FCAT;
    unsigned* adjbit = (unsigned*)(WoTl + DOUT * FCAT);      // 8192*32 words
    ushortT* P1    = (ushortT*)(adjbit + (size_t)RTOT * 32); // 32768*1024 bf16 (64 MB)
    ushortT* P2    = xcatH;   // alias: xcat dead after k_wh2; P2 = 8192*1024 bf16 (16 MB)

    hipLaunchKernelGGL(k_pack,    dim3(RTOT * 32 / 256), dim3(256), 0, stream, adj, adjbit);
    hipLaunchKernelGGL(k_tw,      dim3((NH * DH * DIN + DOUT * FCAT + 255) / 256), dim3(256), 0, stream,
                       Wh, Wo, WbTh, WbTl, WoTh, WoTl);
    hipLaunchKernelGGL(k_wh1,     dim3(RTOT / 16), dim3(256), 0, stream,
                       x, ah, WbTh, WbTl, WhT, src1, dst1);
    hipLaunchKernelGGL(k_soft1,   dim3(NH * BSZ * 64), dim3(256), 0, stream,
                       adjbit, src1, dst1, P1, rinv1);
    hipLaunchKernelGGL(k_pv1,     dim3(NH * BSZ * 8), dim3(512), 0, stream,
                       P1, WhT, rinv1, xcatH, xcatL);
    hipLaunchKernelGGL(k_wh2,     dim3(RTOT / 16), dim3(256), 0, stream,
                       xcatH, xcatL, WoTh, WoTl, Wh2, Wh2T);
    hipLaunchKernelGGL(k_srcdst2, dim3(RTOT / 4), dim3(256), 0, stream, Wh2, ao, src2, dst2);
    hipLaunchKernelGGL(k_soft2,   dim3(BSZ * 64), dim3(256), 0, stream,
                       adjbit, src2, dst2, P2, rinv2);
    hipLaunchKernelGGL(k_pv2,     dim3(BSZ * 16), dim3(256), 0, stream,
                       P2, Wh2T, rinv2, t2);
    hipLaunchKernelGGL(k_fc,      dim3(RTOT * DOUT / 256), dim3(256), 0, stream, t2, Wf, bf, out);
}

// Round 6
// 191.441 us; speedup vs baseline: 2.5764x; 1.1572x over previous
//
#include <hip/hip_runtime.h>
#include <hip/hip_bf16.h>

// Shapes (fixed by reference): B=8, N=1024, Din=256, H=4, Dh=128, Do=64
#define BSZ 8
#define NN 1024
#define DIN 256
#define NH 4
#define DH 128
#define DOUT 64
#define RTOT (BSZ*NN)          // 8192 rows total
#define FCAT (NH*DH)           // 512
#define ALPHA 0.2f

typedef unsigned short ushortT;
typedef __attribute__((ext_vector_type(8))) short bf16x8;
typedef __attribute__((ext_vector_type(4))) float f32x4;

static __device__ __forceinline__ ushortT f2bf(float f) {
    __hip_bfloat16 h = __float2bfloat16(f);
    return *reinterpret_cast<ushortT*>(&h);
}
static __device__ __forceinline__ float bfu2f(ushortT u) {
    return __uint_as_float(((unsigned)u) << 16);
}
static __device__ __forceinline__ void split2(float v, ushortT& hi, ushortT& lo) {
    hi = f2bf(v);
    lo = f2bf(v - bfu2f(hi));
}
// async global->LDS, 16B per lane; LDS dest = base(wave-uniform) + lane*16
static __device__ __forceinline__ void gload16(const ushortT* g, ushortT* l) {
    __builtin_amdgcn_global_load_lds(
        (const __attribute__((address_space(1))) unsigned int*)(const void*)g,
        (__attribute__((address_space(3))) unsigned int*)(void*)l, 16, 0, 0);
}

// ============ prep: adj bitmask + weight transforms (bf16 hi/lo, k-contig) ============
// WbT tiled layout: [h][kt=k/64][f][k%64]  (contiguous 16KB planes per (h,kt))
// WoT layout: [f][k] (k=0..511)
__global__ __launch_bounds__(256) void k_prep(const int* __restrict__ adj,
                                              const float* __restrict__ W,
                                              const float* __restrict__ Wout,
                                              unsigned* __restrict__ adjbit,
                                              ushortT* __restrict__ WbTh, ushortT* __restrict__ WbTl,
                                              ushortT* __restrict__ WoTh, ushortT* __restrict__ WoTl) {
    const int bx = blockIdx.x, t = threadIdx.x;
    if (bx < 1024) {                    // pack: 262144 words
        const int g = bx * 256 + t;
        const int row = g >> 5, w = g & 31;
        const int4* p = (const int4*)(adj + (size_t)row * NN + w * 32);
        unsigned m = 0;
#pragma unroll
        for (int q = 0; q < 8; ++q) {
            const int4 v = p[q];
            m |= (v.x > 0 ? 1u : 0u) << (q * 4 + 0);
            m |= (v.y > 0 ? 1u : 0u) << (q * 4 + 1);
            m |= (v.z > 0 ? 1u : 0u) << (q * 4 + 2);
            m |= (v.w > 0 ? 1u : 0u) << (q * 4 + 3);
        }
        adjbit[g] = m;
        return;
    }
    const int g2 = (bx - 1024) * 256 + t;
    if (g2 < NH * DH * DIN) {           // 131072
        const int h = g2 >> 15, f = (g2 >> 8) & 127, k = g2 & 255;
        const int kt = k >> 6, k64 = k & 63;
        const float v = W[(size_t)h * DIN * DH + (size_t)k * DH + f];
        ushortT hi, lo; split2(v, hi, lo);
        const int idx = ((h * 4 + kt) * 128 + f) * 64 + k64;
        WbTh[idx] = hi; WbTl[idx] = lo;
    } else {
        const int g3 = g2 - NH * DH * DIN;   // < 32768
        const int f = g3 >> 9, k = g3 & 511;
        const float v = Wout[(size_t)k * DOUT + f];
        ushortT hi, lo; split2(v, hi, lo);
        WoTh[g3] = hi; WoTl[g3] = lo;
    }
}

// ============ k_wh1: Wh1 = x @ W_heads, tiled MFMA GEMM (hi/lo), fused src1/dst1 ============
// grid 256 (h = bx>>6, mt = bx&63), 512 thr (8 waves), tile M=128, N=128(head), K=256 (4 kt)
__global__ __launch_bounds__(512) void k_wh1(const float* __restrict__ x,
                                             const float* __restrict__ ah_,
                                             const ushortT* __restrict__ WbTh,
                                             const ushortT* __restrict__ WbTl,
                                             ushortT* __restrict__ WhT,
                                             float* __restrict__ src1,
                                             float* __restrict__ dst1) {
    __shared__ ushortT Ah[128 * 64], Al[128 * 64];    // 32 KB
    __shared__ ushortT Bh[128 * 64], Bl[128 * 64];    // 32 KB
    __shared__ float sred[8][32], dred[8][32];
    const int tid = threadIdx.x, lane = tid & 63, wave = tid >> 6;
    const int h = blockIdx.x >> 6, mt = blockIdx.x & 63;
    const int r0 = mt * 128, b = r0 >> 10, jr = r0 & 1023;
    const int m16 = lane & 15, quad = lane >> 4;
    const int mg = wave >> 1, fg = wave & 1;
    const int arow = tid >> 2, apart = tid & 3;
    f32x4 acc[2][4];
#pragma unroll
    for (int a = 0; a < 2; ++a)
#pragma unroll
        for (int c = 0; c < 4; ++c) acc[a][c] = (f32x4){0.f, 0.f, 0.f, 0.f};

    for (int kt = 0; kt < 4; ++kt) {
        __syncthreads();
        // B stage: rows=f 0..127, contiguous tiled source, XOR-swizzled slots
        const ushortT* planeH = WbTh + (size_t)((h * 4 + kt) * 128) * 64;
        const ushortT* planeL = WbTl + (size_t)((h * 4 + kt) * 128) * 64;
#pragma unroll
        for (int half = 0; half < 2; ++half) {
            const int f = wave * 16 + half * 8 + (lane >> 3);
            const int sc = (lane & 7) ^ (f & 7);
            gload16(planeH + (size_t)f * 64 + sc * 8, Bh + (wave * 16 + half * 8) * 64);
            gload16(planeL + (size_t)f * 64 + sc * 8, Bl + (wave * 16 + half * 8) * 64);
        }
        // A stage: x f32 -> hi/lo bf16, swizzled
        {
            const float4* xs = (const float4*)(x + (size_t)(r0 + arow) * DIN + kt * 64 + apart * 16);
            union { ushortT u[16]; uint4 q[2]; } th, tl;
#pragma unroll
            for (int e = 0; e < 4; ++e) {
                const float4 v = xs[e];
                split2(v.x, th.u[e * 4 + 0], tl.u[e * 4 + 0]);
                split2(v.y, th.u[e * 4 + 1], tl.u[e * 4 + 1]);
                split2(v.z, th.u[e * 4 + 2], tl.u[e * 4 + 2]);
                split2(v.w, th.u[e * 4 + 3], tl.u[e * 4 + 3]);
            }
            const int s0 = (2 * apart) ^ (arow & 7), s1 = (2 * apart + 1) ^ (arow & 7);
            *(uint4*)&Ah[arow * 64 + s0 * 8] = th.q[0];
            *(uint4*)&Ah[arow * 64 + s1 * 8] = th.q[1];
            *(uint4*)&Al[arow * 64 + s0 * 8] = tl.q[0];
            *(uint4*)&Al[arow * 64 + s1 * 8] = tl.q[1];
        }
        __syncthreads();
#pragma unroll
        for (int ks = 0; ks < 2; ++ks) {
            bf16x8 a_h[2], a_l[2], b_h[4], b_l[4];
#pragma unroll
            for (int ms = 0; ms < 2; ++ms) {
                const int row = (mg * 2 + ms) * 16 + m16;
                const int cl = (ks * 4 + quad) ^ (row & 7);
                a_h[ms] = *(const bf16x8*)&Ah[row * 64 + cl * 8];
                a_l[ms] = *(const bf16x8*)&Al[row * 64 + cl * 8];
            }
#pragma unroll
            for (int fs = 0; fs < 4; ++fs) {
                const int row = (fg * 4 + fs) * 16 + m16;
                const int cl = (ks * 4 + quad) ^ (row & 7);
                b_h[fs] = *(const bf16x8*)&Bh[row * 64 + cl * 8];
                b_l[fs] = *(const bf16x8*)&Bl[row * 64 + cl * 8];
            }
#pragma unroll
            for (int ms = 0; ms < 2; ++ms)
#pragma unroll
                for (int fs = 0; fs < 4; ++fs) {
                    acc[ms][fs] = __builtin_amdgcn_mfma_f32_16x16x32_bf16(a_h[ms], b_h[fs], acc[ms][fs], 0, 0, 0);
                    acc[ms][fs] = __builtin_amdgcn_mfma_f32_16x16x32_bf16(a_h[ms], b_l[fs], acc[ms][fs], 0, 0, 0);
                    acc[ms][fs] = __builtin_amdgcn_mfma_f32_16x16x32_bf16(a_l[ms], b_h[fs], acc[ms][fs], 0, 0, 0);
                }
        }
    }
    // epilogue: WhT bf16 + fused src1/dst1
    float sacc[2][4] = {{0,0,0,0},{0,0,0,0}}, dacc[2][4] = {{0,0,0,0},{0,0,0,0}};
#pragma unroll
    for (int ms = 0; ms < 2; ++ms)
#pragma unroll
        for (int fs = 0; fs < 4; ++fs) {
            const int fl = (fg * 4 + fs) * 16 + m16;
            const float a_s = ah_[h * 2 * DH + fl];
            const float a_d = ah_[h * 2 * DH + DH + fl];
            union { ushortT u[4]; uint2 q; } tw;
#pragma unroll
            for (int reg = 0; reg < 4; ++reg) {
                const float v = acc[ms][fs][reg];
                sacc[ms][reg] += v * a_s;
                dacc[ms][reg] += v * a_d;
                tw.u[reg] = f2bf(v);
            }
            *(uint2*)(WhT + ((size_t)((b * NH + h) * DH + fl)) * NN + jr + (mg * 2 + ms) * 16 + quad * 4) = tw.q;
        }
#pragma unroll
    for (int ms = 0; ms < 2; ++ms) {
#pragma unroll
        for (int reg = 0; reg < 4; ++reg) {
            float s = sacc[ms][reg], d = dacc[ms][reg];
#pragma unroll
            for (int o = 8; o > 0; o >>= 1) {
                s += __shfl_xor(s, o, 64);
                d += __shfl_xor(d, o, 64);
            }
            if (m16 == 0) {
                sred[wave][ms * 16 + quad * 4 + reg] = s;
                dred[wave][ms * 16 + quad * 4 + reg] = d;
            }
        }
    }
    __syncthreads();
    if (tid < 128) {
        const int mgr = tid >> 5, idx = tid & 31;
        src1[h * RTOT + r0 + tid] = sred[mgr * 2][idx] + sred[mgr * 2 + 1][idx];
        dst1[h * RTOT + r0 + tid] = dred[mgr * 2][idx] + dred[mgr * 2 + 1][idx];
    }
}

// ============ k_attn1: fused softmax + PV GEMM (layer 1) ============
// grid 256 (bh = bx&31 -> b*4+h, it = bx>>5), 512 thr, tile M=128, N=128, K=1024 (16 kt)
__global__ __launch_bounds__(512) void k_attn1(const unsigned* __restrict__ adjbit,
                                               const ushortT* __restrict__ WhT,
                                               const float* __restrict__ src1,
                                               const float* __restrict__ dst1,
                                               ushortT* __restrict__ xcatH,
                                               ushortT* __restrict__ xcatL) {
    __shared__ ushortT As[128 * 64], Bs[128 * 64];   // 32 KB
    __shared__ unsigned maskS[128 * 32];             // 16 KB
    __shared__ float dstv[NN];                       // 4 KB
    __shared__ float srcv[128], rowm[128], rowinv[128];
    const int tid = threadIdx.x, lane = tid & 63, wave = tid >> 6;
    const int bh = blockIdx.x & 31, it = blockIdx.x >> 5;
    const int b = bh >> 2, h = bh & 3;
    const int i0 = it * 128;
    const int m16 = lane & 15, quad = lane >> 4;
    const int mg = wave >> 1, fg = wave & 1;

    const unsigned* mbase = adjbit + (size_t)(b * NN + i0) * 32;
#pragma unroll
    for (int k2 = 0; k2 < 8; ++k2) maskS[tid + 512 * k2] = mbase[tid + 512 * k2];
    dstv[tid]       = dst1[h * RTOT + b * NN + tid];
    dstv[tid + 512] = dst1[h * RTOT + b * NN + tid + 512];
    if (tid < 128) srcv[tid] = src1[h * RTOT + b * NN + i0 + tid];
    __syncthreads();

    // phase 1: per-row max + sum (16 rows per wave, sequential)
    for (int rr = 0; rr < 16; ++rr) {
        const int row = wave * 16 + rr;
        const float si = srcv[row];
        float s[16]; float m = -INFINITY;
#pragma unroll
        for (int c = 0; c < 16; ++c) {
            float v = si + dstv[lane + c * 64];
            v = v >= 0.f ? v : ALPHA * v;
            s[c] = v;
            m = fmaxf(m, v);
        }
#pragma unroll
        for (int o = 32; o > 0; o >>= 1) m = fmaxf(m, __shfl_xor(m, o, 64));
        float sum = 0.f;
#pragma unroll
        for (int c = 0; c < 16; ++c) {
            const unsigned bit = (maskS[row * 32 + c * 2 + (lane >> 5)] >> (lane & 31)) & 1u;
            sum += bit ? __expf(s[c] - m) : 0.f;
        }
#pragma unroll
        for (int o = 32; o > 0; o >>= 1) sum += __shfl_xor(sum, o, 64);
        if (lane == 0) { rowm[row] = m; rowinv[row] = 1.f / sum; }
    }

    // K-loop: B staged via global_load_lds, A computed in-register
    const int arow = tid >> 2, apart = tid & 3;
    const ushortT* Bbase = WhT + (size_t)(bh * DH) * NN;
    f32x4 acc[2][4];
#pragma unroll
    for (int a = 0; a < 2; ++a)
#pragma unroll
        for (int c = 0; c < 4; ++c) acc[a][c] = (f32x4){0.f, 0.f, 0.f, 0.f};

    for (int kt = 0; kt < 16; ++kt) {
        __syncthreads();
#pragma unroll
        for (int half = 0; half < 2; ++half) {
            const int f = wave * 16 + half * 8 + (lane >> 3);
            gload16(Bbase + (size_t)f * NN + kt * 64 + (((lane & 7) ^ (f & 7)) * 8),
                    Bs + (wave * 16 + half * 8) * 64);
        }
        {
            const float mrow = rowm[arow], sA = srcv[arow];
            const unsigned w0 = maskS[arow * 32 + kt * 2 + (apart >> 1)];
            const int bb = (apart & 1) * 16;
            union { ushortT u[16]; uint4 q[2]; } tw;
#pragma unroll
            for (int e4 = 0; e4 < 4; ++e4) {
                const float4 dv = *(const float4*)&dstv[kt * 64 + apart * 16 + e4 * 4];
                const float vv[4] = {dv.x, dv.y, dv.z, dv.w};
#pragma unroll
                for (int e = 0; e < 4; ++e) {
                    float v = sA + vv[e];
                    v = v >= 0.f ? v : ALPHA * v;
                    const unsigned bit = (w0 >> (bb + e4 * 4 + e)) & 1u;
                    tw.u[e4 * 4 + e] = f2bf(bit ? __expf(v - mrow) : 0.f);
                }
            }
            const int s0 = (2 * apart) ^ (arow & 7), s1 = (2 * apart + 1) ^ (arow & 7);
            *(uint4*)&As[arow * 64 + s0 * 8] = tw.q[0];
            *(uint4*)&As[arow * 64 + s1 * 8] = tw.q[1];
        }
        __syncthreads();
#pragma unroll
        for (int ks = 0; ks < 2; ++ks) {
            bf16x8 afr[2], bfr[4];
#pragma unroll
            for (int ms = 0; ms < 2; ++ms) {
                const int row = (mg * 2 + ms) * 16 + m16;
                const int cl = (ks * 4 + quad) ^ (row & 7);
                afr[ms] = *(const bf16x8*)&As[row * 64 + cl * 8];
            }
#pragma unroll
            for (int fs = 0; fs < 4; ++fs) {
                const int row = (fg * 4 + fs) * 16 + m16;
                const int cl = (ks * 4 + quad) ^ (row & 7);
                bfr[fs] = *(const bf16x8*)&Bs[row * 64 + cl * 8];
            }
#pragma unroll
            for (int ms = 0; ms < 2; ++ms)
#pragma unroll
                for (int fs = 0; fs < 4; ++fs)
                    acc[ms][fs] = __builtin_amdgcn_mfma_f32_16x16x32_bf16(afr[ms], bfr[fs], acc[ms][fs], 0, 0, 0);
        }
    }
    // epilogue: normalize, hi/lo bf16 xcat
#pragma unroll
    for (int ms = 0; ms < 2; ++ms) {
        float rv[4];
#pragma unroll
        for (int reg = 0; reg < 4; ++reg)
            rv[reg] = rowinv[(mg * 2 + ms) * 16 + quad * 4 + reg];
#pragma unroll
        for (int fs = 0; fs < 4; ++fs) {
            const int f = h * DH + (fg * 4 + fs) * 16 + m16;
#pragma unroll
            for (int reg = 0; reg < 4; ++reg) {
                const int i = i0 + (mg * 2 + ms) * 16 + quad * 4 + reg;
                const float v = acc[ms][fs][reg] * rv[reg];
                const size_t idx = (size_t)(b * NN + i) * FCAT + f;
                ushortT hi, lo; split2(v, hi, lo);
                xcatH[idx] = hi;
                xcatL[idx] = lo;
            }
        }
    }
}

// ============ k_wh2: Wh2 = xcat @ W_out (hi/lo MFMA) + fused src2/dst2 ============
__global__ __launch_bounds__(256) void k_wh2(const ushortT* __restrict__ xcatH,
                                             const ushortT* __restrict__ xcatL,
                                             const ushortT* __restrict__ WoTh,
                                             const ushortT* __restrict__ WoTl,
                                             const float* __restrict__ aout,
                                             ushortT* __restrict__ Wh2T,
                                             float* __restrict__ src2,
                                             float* __restrict__ dst2) {
    __shared__ float sred[4][16], dred[4][16];
    const int tid = threadIdx.x;
    const int r0  = blockIdx.x * 16;
    const int b   = r0 >> 10, jr = r0 & 1023;
    const int lane = tid & 63, wave = tid >> 6;
    const int quad = lane >> 4, n = lane & 15;
    const int f0 = wave * 16;
    const ushortT* ahp = xcatH + (size_t)(r0 + n) * FCAT + quad * 8;
    const ushortT* alp = xcatL + (size_t)(r0 + n) * FCAT + quad * 8;
    const ushortT* bhp = WoTh + (size_t)(f0 + n) * FCAT + quad * 8;
    const ushortT* blp = WoTl + (size_t)(f0 + n) * FCAT + quad * 8;
    f32x4 acc = {0.f, 0.f, 0.f, 0.f};
#pragma unroll
    for (int s = 0; s < 16; ++s) {
        const int off = 32 * s;
        const bf16x8 ah = *(const bf16x8*)(ahp + off);
        const bf16x8 al = *(const bf16x8*)(alp + off);
        const bf16x8 bh = *(const bf16x8*)(bhp + off);
        const bf16x8 bl = *(const bf16x8*)(blp + off);
        acc = __builtin_amdgcn_mfma_f32_16x16x32_bf16(ah, bh, acc, 0, 0, 0);
        acc = __builtin_amdgcn_mfma_f32_16x16x32_bf16(ah, bl, acc, 0, 0, 0);
        acc = __builtin_amdgcn_mfma_f32_16x16x32_bf16(al, bh, acc, 0, 0, 0);
    }
    const int f = f0 + n;
    const float a_s = aout[f], a_d = aout[DOUT + f];
    float sv[4], dv[4];
    union { ushortT u[4]; uint2 q; } tw;
#pragma unroll
    for (int reg = 0; reg < 4; ++reg) {
        const float v = acc[reg];
        sv[reg] = v * a_s; dv[reg] = v * a_d;
        tw.u[reg] = f2bf(v);
    }
    *(uint2*)(Wh2T + ((size_t)(b * DOUT + f)) * NN + jr + quad * 4) = tw.q;
#pragma unroll
    for (int reg = 0; reg < 4; ++reg) {
#pragma unroll
        for (int o = 8; o > 0; o >>= 1) {
            sv[reg] += __shfl_xor(sv[reg], o, 64);
            dv[reg] += __shfl_xor(dv[reg], o, 64);
        }
        if (n == 0) { sred[wave][quad * 4 + reg] = sv[reg]; dred[wave][quad * 4 + reg] = dv[reg]; }
    }
    __syncthreads();
    if (tid < 16) {
        src2[r0 + tid] = sred[0][tid] + sred[1][tid] + sred[2][tid] + sred[3][tid];
        dst2[r0 + tid] = dred[0][tid] + dred[1][tid] + dred[2][tid] + dred[3][tid];
    }
}

// ============ k_attn2: fused softmax + PV + ELU + FC + ReLU (layer 2) ============
// grid 256 (b = bx&7, it = bx>>3), 256 thr, tile M=32, N=64, K=1024 (16 kt)
__global__ __launch_bounds__(256) void k_attn2(const unsigned* __restrict__ adjbit,
                                               const ushortT* __restrict__ Wh2T,
                                               const float* __restrict__ src2,
                                               const float* __restrict__ dst2,
                                               const float* __restrict__ Wf,
                                               const float* __restrict__ bfv,
                                               float* __restrict__ out) {
    __shared__ ushortT As[32 * 64];                 // 4 KB
    __shared__ ushortT Bs[64 * 64];                 // 8 KB
    __shared__ unsigned maskS[32 * 32];             // 4 KB
    __shared__ float dstv[NN];                      // 4 KB
    __shared__ ushortT Wfh[64 * 64], Wfl[64 * 64];  // 16 KB
    __shared__ float t2s[32 * 68];                  // 8.5 KB
    __shared__ float srcv[32], rowm[32], rowinv[32];
    const int tid = threadIdx.x, lane = tid & 63, wave = tid >> 6;
    const int b = blockIdx.x & 7, it = blockIdx.x >> 3;
    const int i0 = it * 32;
    const int m16 = lane & 15, quad = lane >> 4;

    const unsigned* mbase = adjbit + (size_t)(b * NN + i0) * 32;
#pragma unroll
    for (int k2 = 0; k2 < 4; ++k2) maskS[tid + 256 * k2] = mbase[tid + 256 * k2];
#pragma unroll
    for (int k2 = 0; k2 < 4; ++k2) dstv[tid + 256 * k2] = dst2[b * NN + tid + 256 * k2];
    if (tid < 32) srcv[tid] = src2[b * NN + i0 + tid];
    {   // stage Wf as hi/lo, layout [c][k] swizzled
        const int c = tid & 63, kc = (tid >> 6) * 16;
        union { ushortT u[16]; uint4 q[2]; } th, tl;
#pragma unroll
        for (int e = 0; e < 16; ++e)
            split2(Wf[(size_t)(kc + e) * DOUT + c], th.u[e], tl.u[e]);
        const int s0 = ((tid >> 6) * 2) ^ (c & 7), s1 = ((tid >> 6) * 2 + 1) ^ (c & 7);
        *(uint4*)&Wfh[c * 64 + s0 * 8] = th.q[0];
        *(uint4*)&Wfh[c * 64 + s1 * 8] = th.q[1];
        *(uint4*)&Wfl[c * 64 + s0 * 8] = tl.q[0];
        *(uint4*)&Wfl[c * 64 + s1 * 8] = tl.q[1];
    }
    __syncthreads();

    // phase 1: 8 rows per wave
    for (int rr = 0; rr < 8; ++rr) {
        const int row = wave * 8 + rr;
        const float si = srcv[row];
        float s[16]; float m = -INFINITY;
#pragma unroll
        for (int c = 0; c < 16; ++c) {
            float v = si + dstv[lane + c * 64];
            v = v >= 0.f ? v : ALPHA * v;
            s[c] = v;
            m = fmaxf(m, v);
        }
#pragma unroll
        for (int o = 32; o > 0; o >>= 1) m = fmaxf(m, __shfl_xor(m, o, 64));
        float sum = 0.f;
#pragma unroll
        for (int c = 0; c < 16; ++c) {
            const unsigned bit = (maskS[row * 32 + c * 2 + (lane >> 5)] >> (lane & 31)) & 1u;
            sum += bit ? __expf(s[c] - m) : 0.f;
        }
#pragma unroll
        for (int o = 32; o > 0; o >>= 1) sum += __shfl_xor(sum, o, 64);
        if (lane == 0) { rowm[row] = m; rowinv[row] = 1.f / sum; }
    }

    const int mfrag = wave >> 1, fh = wave & 1;
    const int arow = tid >> 3, apart = tid & 7;
    const ushortT* Bbase = Wh2T + (size_t)(b * DOUT) * NN;
    f32x4 acc[2] = {(f32x4){0.f,0.f,0.f,0.f}, (f32x4){0.f,0.f,0.f,0.f}};

    for (int kt = 0; kt < 16; ++kt) {
        __syncthreads();
#pragma unroll
        for (int half = 0; half < 2; ++half) {
            const int f = wave * 16 + half * 8 + (lane >> 3);
            gload16(Bbase + (size_t)f * NN + kt * 64 + (((lane & 7) ^ (f & 7)) * 8),
                    Bs + (wave * 16 + half * 8) * 64);
        }
        {
            const float mrow = rowm[arow], sA = srcv[arow];
            const unsigned w0 = maskS[arow * 32 + kt * 2 + (apart >> 2)];
            const int bb = (apart & 3) * 8;
            union { ushortT u[8]; uint4 q; } tw;
#pragma unroll
            for (int e4 = 0; e4 < 2; ++e4) {
                const float4 dv = *(const float4*)&dstv[kt * 64 + apart * 8 + e4 * 4];
                const float vv[4] = {dv.x, dv.y, dv.z, dv.w};
#pragma unroll
                for (int e = 0; e < 4; ++e) {
                    float v = sA + vv[e];
                    v = v >= 0.f ? v : ALPHA * v;
                    const unsigned bit = (w0 >> (bb + e4 * 4 + e)) & 1u;
                    tw.u[e4 * 4 + e] = f2bf(bit ? __expf(v - mrow) : 0.f);
                }
            }
            *(uint4*)&As[arow * 64 + (apart ^ (arow & 7)) * 8] = tw.q;
        }
        __syncthreads();
#pragma unroll
        for (int ks = 0; ks < 2; ++ks) {
            const int rowa = mfrag * 16 + m16;
            const int cla = (ks * 4 + quad) ^ (rowa & 7);
            const bf16x8 afr = *(const bf16x8*)&As[rowa * 64 + cla * 8];
#pragma unroll
            for (int ff = 0; ff < 2; ++ff) {
                const int rowb = (fh * 2 + ff) * 16 + m16;
                const int clb = (ks * 4 + quad) ^ (rowb & 7);
                const bf16x8 bfr = *(const bf16x8*)&Bs[rowb * 64 + clb * 8];
                acc[ff] = __builtin_amdgcn_mfma_f32_16x16x32_bf16(afr, bfr, acc[ff], 0, 0, 0);
            }
        }
    }
    // ELU -> t2 tile in LDS
#pragma unroll
    for (int ff = 0; ff < 2; ++ff) {
#pragma unroll
        for (int reg = 0; reg < 4; ++reg) {
            const int row = mfrag * 16 + quad * 4 + reg;
            float v = acc[ff][reg] * rowinv[row];
            v = v > 0.f ? v : (__expf(v) - 1.f);
            t2s[row * 68 + (fh * 2 + ff) * 16 + m16] = v;
        }
    }
    __syncthreads();
    // FC: out = relu(t2 @ Wf + bf), 3-term hi/lo MFMA
    const int mf = wave >> 1, nh = wave & 1;
    f32x4 oacc[2];
#pragma unroll
    for (int g = 0; g < 2; ++g) {
        const float bias = bfv[(nh * 2 + g) * 16 + m16];
        oacc[g] = (f32x4){bias, bias, bias, bias};
    }
#pragma unroll
    for (int ks = 0; ks < 2; ++ks) {
        const int rowa = mf * 16 + m16;
        const float4 fA = *(const float4*)&t2s[rowa * 68 + ks * 32 + quad * 8];
        const float4 fB = *(const float4*)&t2s[rowa * 68 + ks * 32 + quad * 8 + 4];
        union { ushortT u[8]; bf16x8 v; } a_h, a_l;
        const float av[8] = {fA.x, fA.y, fA.z, fA.w, fB.x, fB.y, fB.z, fB.w};
#pragma unroll
        for (int e = 0; e < 8; ++e) split2(av[e], a_h.u[e], a_l.u[e]);
#pragma unroll
        for (int g = 0; g < 2; ++g) {
            const int rowc = (nh * 2 + g) * 16 + m16;
            const int cl = (ks * 4 + quad) ^ (rowc & 7);
            const bf16x8 b_h = *(const bf16x8*)&Wfh[rowc * 64 + cl * 8];
            const bf16x8 b_l = *(const bf16x8*)&Wfl[rowc * 64 + cl * 8];
            oacc[g] = __builtin_amdgcn_mfma_f32_16x16x32_bf16(a_h.v, b_h, oacc[g], 0, 0, 0);
            oacc[g] = __builtin_amdgcn_mfma_f32_16x16x32_bf16(a_h.v, b_l, oacc[g], 0, 0, 0);
            oacc[g] = __builtin_amdgcn_mfma_f32_16x16x32_bf16(a_l.v, b_h, oacc[g], 0, 0, 0);
        }
    }
#pragma unroll
    for (int g = 0; g < 2; ++g) {
        const int c = (nh * 2 + g) * 16 + m16;
#pragma unroll
        for (int reg = 0; reg < 4; ++reg) {
            const int i = i0 + mf * 16 + quad * 4 + reg;
            out[(size_t)(b * NN + i) * DOUT + c] = fmaxf(oacc[g][reg], 0.f);
        }
    }
}

extern "C" void kernel_launch(void* const* d_in, const int* in_sizes, int n_in,
                              void* d_out, int out_size, void* d_ws, size_t ws_size,
                              hipStream_t stream) {
    const float* x   = (const float*)d_in[0];
    const int*   adj = (const int*)d_in[1];
    const float* Wh  = (const float*)d_in[2];
    const float* ah  = (const float*)d_in[3];
    const float* Wo  = (const float*)d_in[4];
    const float* ao  = (const float*)d_in[5];
    const float* Wf  = (const float*)d_in[6];
    const float* bf  = (const float*)d_in[7];
    float* out = (float*)d_out;

    float* ws    = (float*)d_ws;
    float* src1  = ws;                                 // 4*8192
    float* dst1  = src1 + NH * RTOT;                   // 4*8192
    float* src2  = dst1 + NH * RTOT;                   // 8192
    float* dst2  = src2 + RTOT;                        // 8192
    ushortT* WhT   = (ushortT*)(dst2 + RTOT);                // 8192*512 bf16
    ushortT* Wh2T  = WhT + (size_t)RTOT * FCAT;              // 8192*64
    ushortT* xcatH = Wh2T + (size_t)RTOT * DOUT;             // 8192*512
    ushortT* xcatL = xcatH + (size_t)RTOT * FCAT;            // 8192*512
    ushortT* WbTh  = xcatL + (size_t)RTOT * FCAT;            // 131072
    ushortT* WbTl  = WbTh + NH * DH * DIN;
    ushortT* WoTh  = WbTl + NH * DH * DIN;                   // 32768
    ushortT* WoTl  = WoTh + DOUT * FCAT;
    unsigned* adjbit = (unsigned*)(WoTl + DOUT * FCAT);      // 262144 words

    hipLaunchKernelGGL(k_prep,  dim3(1024 + (NH * DH * DIN + DOUT * FCAT) / 256), dim3(256), 0, stream,
                       adj, Wh, Wo, adjbit, WbTh, WbTl, WoTh, WoTl);
    hipLaunchKernelGGL(k_wh1,   dim3(256), dim3(512), 0, stream,
                       x, ah, WbTh, WbTl, WhT, src1, dst1);
    hipLaunchKernelGGL(k_attn1, dim3(256), dim3(512), 0, stream,
                       adjbit, WhT, src1, dst1, xcatH, xcatL);
    hipLaunchKernelGGL(k_wh2,   dim3(RTOT / 16), dim3(256), 0, stream,
                       xcatH, xcatL, WoTh, WoTl, ao, Wh2T, src2, dst2);
    hipLaunchKernelGGL(k_attn2, dim3(256), dim3(256), 0, stream,
                       adjbit, Wh2T, src2, dst2, Wf, bf, out);
}

// Round 7
// 171.731 us; speedup vs baseline: 2.8721x; 1.1148x over previous
//
#include <hip/hip_runtime.h>
#include <hip/hip_bf16.h>

// Shapes (fixed by reference): B=8, N=1024, Din=256, H=4, Dh=128, Do=64
#define BSZ 8
#define NN 1024
#define DIN 256
#define NH 4
#define DH 128
#define DOUT 64
#define RTOT (BSZ*NN)          // 8192 rows total
#define FCAT (NH*DH)           // 512
#define ALPHA 0.2f

typedef unsigned short ushortT;
typedef __attribute__((ext_vector_type(8))) short bf16x8;
typedef __attribute__((ext_vector_type(4))) float f32x4;

static __device__ __forceinline__ ushortT f2bf(float f) {
    __hip_bfloat16 h = __float2bfloat16(f);
    return *reinterpret_cast<ushortT*>(&h);
}
static __device__ __forceinline__ float bfu2f(ushortT u) {
    return __uint_as_float(((unsigned)u) << 16);
}
static __device__ __forceinline__ void split2(float v, ushortT& hi, ushortT& lo) {
    hi = f2bf(v);
    lo = f2bf(v - bfu2f(hi));
}
// async global->LDS, 16B per lane; LDS dest = base(wave-uniform) + lane*16
static __device__ __forceinline__ void gload16(const ushortT* g, ushortT* l) {
    __builtin_amdgcn_global_load_lds(
        (const __attribute__((address_space(1))) unsigned int*)(const void*)g,
        (__attribute__((address_space(3))) unsigned int*)(void*)l, 16, 0, 0);
}

// ============ prep: adj bitmask + weight transforms (bf16 hi/lo, k-contig) ============
__global__ __launch_bounds__(256) void k_prep(const int* __restrict__ adj,
                                              const float* __restrict__ W,
                                              const float* __restrict__ Wout,
                                              unsigned* __restrict__ adjbit,
                                              ushortT* __restrict__ WbTh, ushortT* __restrict__ WbTl,
                                              ushortT* __restrict__ WoTh, ushortT* __restrict__ WoTl) {
    const int bx = blockIdx.x, t = threadIdx.x;
    if (bx < 1024) {                    // pack: 262144 words
        const int g = bx * 256 + t;
        const int row = g >> 5, w = g & 31;
        const int4* p = (const int4*)(adj + (size_t)row * NN + w * 32);
        unsigned m = 0;
#pragma unroll
        for (int q = 0; q < 8; ++q) {
            const int4 v = p[q];
            m |= (v.x > 0 ? 1u : 0u) << (q * 4 + 0);
            m |= (v.y > 0 ? 1u : 0u) << (q * 4 + 1);
            m |= (v.z > 0 ? 1u : 0u) << (q * 4 + 2);
            m |= (v.w > 0 ? 1u : 0u) << (q * 4 + 3);
        }
        adjbit[g] = m;
        return;
    }
    const int g2 = (bx - 1024) * 256 + t;
    if (g2 < NH * DH * DIN) {           // 131072
        const int h = g2 >> 15, f = (g2 >> 8) & 127, k = g2 & 255;
        const int kt = k >> 6, k64 = k & 63;
        const float v = W[(size_t)h * DIN * DH + (size_t)k * DH + f];
        ushortT hi, lo; split2(v, hi, lo);
        const int idx = ((h * 4 + kt) * 128 + f) * 64 + k64;
        WbTh[idx] = hi; WbTl[idx] = lo;
    } else {
        const int g3 = g2 - NH * DH * DIN;   // < 32768
        const int f = g3 >> 9, k = g3 & 511;
        const float v = Wout[(size_t)k * DOUT + f];
        ushortT hi, lo; split2(v, hi, lo);
        WoTh[g3] = hi; WoTl[g3] = lo;
    }
}

// ============ k_wh1: Wh1 = x @ W_heads, tiled MFMA GEMM (hi/lo), fused src1/dst1 ============
__global__ __launch_bounds__(512) void k_wh1(const float* __restrict__ x,
                                             const float* __restrict__ ah_,
                                             const ushortT* __restrict__ WbTh,
                                             const ushortT* __restrict__ WbTl,
                                             ushortT* __restrict__ WhT,
                                             float* __restrict__ src1,
                                             float* __restrict__ dst1) {
    __shared__ ushortT Ah[128 * 64], Al[128 * 64];    // 32 KB
    __shared__ ushortT Bh[128 * 64], Bl[128 * 64];    // 32 KB
    __shared__ float sred[8][32], dred[8][32];
    const int tid = threadIdx.x, lane = tid & 63, wave = tid >> 6;
    const int h = blockIdx.x >> 6, mt = blockIdx.x & 63;
    const int r0 = mt * 128, b = r0 >> 10, jr = r0 & 1023;
    const int m16 = lane & 15, quad = lane >> 4;
    const int mg = wave >> 1, fg = wave & 1;
    const int arow = tid >> 2, apart = tid & 3;
    f32x4 acc[2][4];
#pragma unroll
    for (int a = 0; a < 2; ++a)
#pragma unroll
        for (int c = 0; c < 4; ++c) acc[a][c] = (f32x4){0.f, 0.f, 0.f, 0.f};

    for (int kt = 0; kt < 4; ++kt) {
        __syncthreads();
        const ushortT* planeH = WbTh + (size_t)((h * 4 + kt) * 128) * 64;
        const ushortT* planeL = WbTl + (size_t)((h * 4 + kt) * 128) * 64;
#pragma unroll
        for (int half = 0; half < 2; ++half) {
            const int f = wave * 16 + half * 8 + (lane >> 3);
            const int sc = (lane & 7) ^ (f & 7);
            gload16(planeH + (size_t)f * 64 + sc * 8, Bh + (wave * 16 + half * 8) * 64);
            gload16(planeL + (size_t)f * 64 + sc * 8, Bl + (wave * 16 + half * 8) * 64);
        }
        {
            const float4* xs = (const float4*)(x + (size_t)(r0 + arow) * DIN + kt * 64 + apart * 16);
            union { ushortT u[16]; uint4 q[2]; } th, tl;
#pragma unroll
            for (int e = 0; e < 4; ++e) {
                const float4 v = xs[e];
                split2(v.x, th.u[e * 4 + 0], tl.u[e * 4 + 0]);
                split2(v.y, th.u[e * 4 + 1], tl.u[e * 4 + 1]);
                split2(v.z, th.u[e * 4 + 2], tl.u[e * 4 + 2]);
                split2(v.w, th.u[e * 4 + 3], tl.u[e * 4 + 3]);
            }
            const int s0 = (2 * apart) ^ (arow & 7), s1 = (2 * apart + 1) ^ (arow & 7);
            *(uint4*)&Ah[arow * 64 + s0 * 8] = th.q[0];
            *(uint4*)&Ah[arow * 64 + s1 * 8] = th.q[1];
            *(uint4*)&Al[arow * 64 + s0 * 8] = tl.q[0];
            *(uint4*)&Al[arow * 64 + s1 * 8] = tl.q[1];
        }
        __syncthreads();
#pragma unroll
        for (int ks = 0; ks < 2; ++ks) {
            bf16x8 a_h[2], a_l[2], b_h[4], b_l[4];
#pragma unroll
            for (int ms = 0; ms < 2; ++ms) {
                const int row = (mg * 2 + ms) * 16 + m16;
                const int cl = (ks * 4 + quad) ^ (row & 7);
                a_h[ms] = *(const bf16x8*)&Ah[row * 64 + cl * 8];
                a_l[ms] = *(const bf16x8*)&Al[row * 64 + cl * 8];
            }
#pragma unroll
            for (int fs = 0; fs < 4; ++fs) {
                const int row = (fg * 4 + fs) * 16 + m16;
                const int cl = (ks * 4 + quad) ^ (row & 7);
                b_h[fs] = *(const bf16x8*)&Bh[row * 64 + cl * 8];
                b_l[fs] = *(const bf16x8*)&Bl[row * 64 + cl * 8];
            }
#pragma unroll
            for (int ms = 0; ms < 2; ++ms)
#pragma unroll
                for (int fs = 0; fs < 4; ++fs) {
                    acc[ms][fs] = __builtin_amdgcn_mfma_f32_16x16x32_bf16(a_h[ms], b_h[fs], acc[ms][fs], 0, 0, 0);
                    acc[ms][fs] = __builtin_amdgcn_mfma_f32_16x16x32_bf16(a_h[ms], b_l[fs], acc[ms][fs], 0, 0, 0);
                    acc[ms][fs] = __builtin_amdgcn_mfma_f32_16x16x32_bf16(a_l[ms], b_h[fs], acc[ms][fs], 0, 0, 0);
                }
        }
    }
    float sacc[2][4] = {{0,0,0,0},{0,0,0,0}}, dacc[2][4] = {{0,0,0,0},{0,0,0,0}};
#pragma unroll
    for (int ms = 0; ms < 2; ++ms)
#pragma unroll
        for (int fs = 0; fs < 4; ++fs) {
            const int fl = (fg * 4 + fs) * 16 + m16;
            const float a_s = ah_[h * 2 * DH + fl];
            const float a_d = ah_[h * 2 * DH + DH + fl];
            union { ushortT u[4]; uint2 q; } tw;
#pragma unroll
            for (int reg = 0; reg < 4; ++reg) {
                const float v = acc[ms][fs][reg];
                sacc[ms][reg] += v * a_s;
                dacc[ms][reg] += v * a_d;
                tw.u[reg] = f2bf(v);
            }
            *(uint2*)(WhT + ((size_t)((b * NH + h) * DH + fl)) * NN + jr + (mg * 2 + ms) * 16 + quad * 4) = tw.q;
        }
#pragma unroll
    for (int ms = 0; ms < 2; ++ms) {
#pragma unroll
        for (int reg = 0; reg < 4; ++reg) {
            float s = sacc[ms][reg], d = dacc[ms][reg];
#pragma unroll
            for (int o = 8; o > 0; o >>= 1) {
                s += __shfl_xor(s, o, 64);
                d += __shfl_xor(d, o, 64);
            }
            if (m16 == 0) {
                sred[wave][ms * 16 + quad * 4 + reg] = s;
                dred[wave][ms * 16 + quad * 4 + reg] = d;
            }
        }
    }
    __syncthreads();
    if (tid < 128) {
        const int mgr = tid >> 5, idx = tid & 31;
        src1[h * RTOT + r0 + tid] = sred[mgr * 2][idx] + sred[mgr * 2 + 1][idx];
        dst1[h * RTOT + r0 + tid] = dred[mgr * 2][idx] + dred[mgr * 2 + 1][idx];
    }
}

// ============ k_attn1: fused single-pass softmax + PV GEMM (layer 1) ============
// grid 512 (bh = bx&31 -> b*4+h, it = bx>>5), 512 thr, tile M=64, F=128, K=1024 (16 kt)
// max via monotone-leaky trick (dmax reduction); row sums accumulated in K-loop.
__global__ __launch_bounds__(512) void k_attn1(const unsigned* __restrict__ adjbit,
                                               const ushortT* __restrict__ WhT,
                                               const float* __restrict__ src1,
                                               const float* __restrict__ dst1,
                                               ushortT* __restrict__ xcatH,
                                               ushortT* __restrict__ xcatL) {
    __shared__ ushortT As[64 * 64];                  // 8 KB
    __shared__ ushortT Bs[128 * 64];                 // 16 KB
    __shared__ unsigned maskS[64 * 32];              // 8 KB
    __shared__ float dstv[NN];                       // 4 KB
    __shared__ float srcv[64], rowinv[64], red8[8];
    const int tid = threadIdx.x, lane = tid & 63, wave = tid >> 6;
    const int bh = blockIdx.x & 31, it = blockIdx.x >> 5;
    const int b = bh >> 2, h = bh & 3;
    const int i0 = it * 64;
    const int m16 = lane & 15, quad = lane >> 4;
    const int mg = wave >> 1, fg = wave & 1;

    const unsigned* mbase = adjbit + (size_t)(b * NN + i0) * 32;
#pragma unroll
    for (int k2 = 0; k2 < 4; ++k2) maskS[tid + 512 * k2] = mbase[tid + 512 * k2];
    const float d0 = dst1[h * RTOT + b * NN + tid];
    const float d1 = dst1[h * RTOT + b * NN + tid + 512];
    dstv[tid] = d0; dstv[tid + 512] = d1;
    if (tid < 64) srcv[tid] = src1[h * RTOT + b * NN + i0 + tid];
    float lm = fmaxf(d0, d1);
#pragma unroll
    for (int o = 32; o > 0; o >>= 1) lm = fmaxf(lm, __shfl_xor(lm, o, 64));
    if (lane == 0) red8[wave] = lm;
    __syncthreads();
    const float dmax = fmaxf(fmaxf(fmaxf(red8[0], red8[1]), fmaxf(red8[2], red8[3])),
                             fmaxf(fmaxf(red8[4], red8[5]), fmaxf(red8[6], red8[7])));

    const int arow = tid >> 3, apart = tid & 7;      // 64 rows x 8 parts
    const float si = srcv[arow];
    float mrow = si + dmax;
    mrow = mrow >= 0.f ? mrow : ALPHA * mrow;        // per-row max (monotone leaky)
    float fsum = 0.f;

    const ushortT* Bbase = WhT + (size_t)(bh * DH) * NN;
    f32x4 acc[4];
#pragma unroll
    for (int c = 0; c < 4; ++c) acc[c] = (f32x4){0.f, 0.f, 0.f, 0.f};

    for (int kt = 0; kt < 16; ++kt) {
        __syncthreads();
#pragma unroll
        for (int half = 0; half < 2; ++half) {
            const int f = wave * 16 + half * 8 + (lane >> 3);
            gload16(Bbase + (size_t)f * NN + kt * 64 + (((lane & 7) ^ (f & 7)) * 8),
                    Bs + (wave * 16 + half * 8) * 64);
        }
        {
            const unsigned w0 = maskS[arow * 32 + kt * 2 + (apart >> 2)];
            const int bb = (apart & 3) * 8;
            union { ushortT u[8]; uint4 q; } tw;
#pragma unroll
            for (int e4 = 0; e4 < 2; ++e4) {
                const float4 dv = *(const float4*)&dstv[kt * 64 + apart * 8 + e4 * 4];
                const float vv[4] = {dv.x, dv.y, dv.z, dv.w};
#pragma unroll
                for (int e = 0; e < 4; ++e) {
                    float v = si + vv[e];
                    v = v >= 0.f ? v : ALPHA * v;
                    const unsigned bit = (w0 >> (bb + e4 * 4 + e)) & 1u;
                    const float p = bit ? __expf(v - mrow) : 0.f;
                    fsum += p;
                    tw.u[e4 * 4 + e] = f2bf(p);
                }
            }
            *(uint4*)&As[arow * 64 + (apart ^ (arow & 7)) * 8] = tw.q;
        }
        __syncthreads();
#pragma unroll
        for (int ks = 0; ks < 2; ++ks) {
            const int rowa = mg * 16 + m16;
            const int cla = (ks * 4 + quad) ^ (rowa & 7);
            const bf16x8 afr = *(const bf16x8*)&As[rowa * 64 + cla * 8];
#pragma unroll
            for (int fs = 0; fs < 4; ++fs) {
                const int rowb = fg * 64 + fs * 16 + m16;
                const int clb = (ks * 4 + quad) ^ (rowb & 7);
                const bf16x8 bfr = *(const bf16x8*)&Bs[rowb * 64 + clb * 8];
                acc[fs] = __builtin_amdgcn_mfma_f32_16x16x32_bf16(afr, bfr, acc[fs], 0, 0, 0);
            }
        }
    }
    // row sums: reduce over the 8 threads owning each row
#pragma unroll
    for (int o = 1; o < 8; o <<= 1) fsum += __shfl_xor(fsum, o, 64);
    if ((lane & 7) == 0) rowinv[arow] = 1.f / fsum;
    __syncthreads();
    // epilogue: normalize, hi/lo bf16 xcat
    float rv[4];
#pragma unroll
    for (int reg = 0; reg < 4; ++reg) rv[reg] = rowinv[mg * 16 + quad * 4 + reg];
#pragma unroll
    for (int fs = 0; fs < 4; ++fs) {
        const int f = h * DH + fg * 64 + fs * 16 + m16;
#pragma unroll
        for (int reg = 0; reg < 4; ++reg) {
            const int i = i0 + mg * 16 + quad * 4 + reg;
            const float v = acc[fs][reg] * rv[reg];
            const size_t idx = (size_t)(b * NN + i) * FCAT + f;
            ushortT hi, lo; split2(v, hi, lo);
            xcatH[idx] = hi;
            xcatL[idx] = lo;
        }
    }
}

// ============ k_wh2: Wh2 = xcat @ W_out (hi/lo MFMA) + fused src2/dst2 ============
__global__ __launch_bounds__(256) void k_wh2(const ushortT* __restrict__ xcatH,
                                             const ushortT* __restrict__ xcatL,
                                             const ushortT* __restrict__ WoTh,
                                             const ushortT* __restrict__ WoTl,
                                             const float* __restrict__ aout,
                                             ushortT* __restrict__ Wh2T,
                                             float* __restrict__ src2,
                                             float* __restrict__ dst2) {
    __shared__ float sred[4][16], dred[4][16];
    const int tid = threadIdx.x;
    const int r0  = blockIdx.x * 16;
    const int b   = r0 >> 10, jr = r0 & 1023;
    const int lane = tid & 63, wave = tid >> 6;
    const int quad = lane >> 4, n = lane & 15;
    const int f0 = wave * 16;
    const ushortT* ahp = xcatH + (size_t)(r0 + n) * FCAT + quad * 8;
    const ushortT* alp = xcatL + (size_t)(r0 + n) * FCAT + quad * 8;
    const ushortT* bhp = WoTh + (size_t)(f0 + n) * FCAT + quad * 8;
    const ushortT* blp = WoTl + (size_t)(f0 + n) * FCAT + quad * 8;
    f32x4 acc = {0.f, 0.f, 0.f, 0.f};
#pragma unroll
    for (int s = 0; s < 16; ++s) {
        const int off = 32 * s;
        const bf16x8 ah = *(const bf16x8*)(ahp + off);
        const bf16x8 al = *(const bf16x8*)(alp + off);
        const bf16x8 bh = *(const bf16x8*)(bhp + off);
        const bf16x8 bl = *(const bf16x8*)(blp + off);
        acc = __builtin_amdgcn_mfma_f32_16x16x32_bf16(ah, bh, acc, 0, 0, 0);
        acc = __builtin_amdgcn_mfma_f32_16x16x32_bf16(ah, bl, acc, 0, 0, 0);
        acc = __builtin_amdgcn_mfma_f32_16x16x32_bf16(al, bh, acc, 0, 0, 0);
    }
    const int f = f0 + n;
    const float a_s = aout[f], a_d = aout[DOUT + f];
    float sv[4], dv[4];
    union { ushortT u[4]; uint2 q; } tw;
#pragma unroll
    for (int reg = 0; reg < 4; ++reg) {
        const float v = acc[reg];
        sv[reg] = v * a_s; dv[reg] = v * a_d;
        tw.u[reg] = f2bf(v);
    }
    *(uint2*)(Wh2T + ((size_t)(b * DOUT + f)) * NN + jr + quad * 4) = tw.q;
#pragma unroll
    for (int reg = 0; reg < 4; ++reg) {
#pragma unroll
        for (int o = 8; o > 0; o >>= 1) {
            sv[reg] += __shfl_xor(sv[reg], o, 64);
            dv[reg] += __shfl_xor(dv[reg], o, 64);
        }
        if (n == 0) { sred[wave][quad * 4 + reg] = sv[reg]; dred[wave][quad * 4 + reg] = dv[reg]; }
    }
    __syncthreads();
    if (tid < 16) {
        src2[r0 + tid] = sred[0][tid] + sred[1][tid] + sred[2][tid] + sred[3][tid];
        dst2[r0 + tid] = dred[0][tid] + dred[1][tid] + dred[2][tid] + dred[3][tid];
    }
}

// ============ k_attn2: single-pass softmax + PV + ELU + FC + ReLU (layer 2) ============
// grid 256 (b = bx&7, it = bx>>3), 256 thr, tile M=32, F=64, K=1024 (16 kt)
__global__ __launch_bounds__(256) void k_attn2(const unsigned* __restrict__ adjbit,
                                               const ushortT* __restrict__ Wh2T,
                                               const float* __restrict__ src2,
                                               const float* __restrict__ dst2,
                                               const float* __restrict__ Wf,
                                               const float* __restrict__ bfv,
                                               float* __restrict__ out) {
    __shared__ ushortT As[32 * 64];                 // 4 KB
    __shared__ ushortT Bs[64 * 64];                 // 8 KB
    __shared__ unsigned maskS[32 * 32];             // 4 KB
    __shared__ float dstv[NN];                      // 4 KB
    __shared__ ushortT Wfh[64 * 64], Wfl[64 * 64];  // 16 KB
    __shared__ float t2s[32 * 68];                  // 8.5 KB
    __shared__ float srcv[32], rowinv[32], red4[4];
    const int tid = threadIdx.x, lane = tid & 63, wave = tid >> 6;
    const int b = blockIdx.x & 7, it = blockIdx.x >> 3;
    const int i0 = it * 32;
    const int m16 = lane & 15, quad = lane >> 4;

    const unsigned* mbase = adjbit + (size_t)(b * NN + i0) * 32;
#pragma unroll
    for (int k2 = 0; k2 < 4; ++k2) maskS[tid + 256 * k2] = mbase[tid + 256 * k2];
    float lm = -INFINITY;
#pragma unroll
    for (int k2 = 0; k2 < 4; ++k2) {
        const float d = dst2[b * NN + tid + 256 * k2];
        dstv[tid + 256 * k2] = d;
        lm = fmaxf(lm, d);
    }
    if (tid < 32) srcv[tid] = src2[b * NN + i0 + tid];
    {   // stage Wf as hi/lo, layout [c][k] swizzled
        const int c = tid & 63, kc = (tid >> 6) * 16;
        union { ushortT u[16]; uint4 q[2]; } th, tl;
#pragma unroll
        for (int e = 0; e < 16; ++e)
            split2(Wf[(size_t)(kc + e) * DOUT + c], th.u[e], tl.u[e]);
        const int s0 = ((tid >> 6) * 2) ^ (c & 7), s1 = ((tid >> 6) * 2 + 1) ^ (c & 7);
        *(uint4*)&Wfh[c * 64 + s0 * 8] = th.q[0];
        *(uint4*)&Wfh[c * 64 + s1 * 8] = th.q[1];
        *(uint4*)&Wfl[c * 64 + s0 * 8] = tl.q[0];
        *(uint4*)&Wfl[c * 64 + s1 * 8] = tl.q[1];
    }
#pragma unroll
    for (int o = 32; o > 0; o >>= 1) lm = fmaxf(lm, __shfl_xor(lm, o, 64));
    if (lane == 0) red4[wave] = lm;
    __syncthreads();
    const float dmax = fmaxf(fmaxf(red4[0], red4[1]), fmaxf(red4[2], red4[3]));

    const int arow = tid >> 3, apart = tid & 7;      // 32 rows x 8 parts
    const float si = srcv[arow];
    float mrow = si + dmax;
    mrow = mrow >= 0.f ? mrow : ALPHA * mrow;
    float fsum = 0.f;

    const int mfrag = wave >> 1, fh = wave & 1;
    const ushortT* Bbase = Wh2T + (size_t)(b * DOUT) * NN;
    f32x4 acc[2] = {(f32x4){0.f,0.f,0.f,0.f}, (f32x4){0.f,0.f,0.f,0.f}};

    for (int kt = 0; kt < 16; ++kt) {
        __syncthreads();
#pragma unroll
        for (int half = 0; half < 2; ++half) {
            const int f = wave * 16 + half * 8 + (lane >> 3);
            gload16(Bbase + (size_t)f * NN + kt * 64 + (((lane & 7) ^ (f & 7)) * 8),
                    Bs + (wave * 16 + half * 8) * 64);
        }
        {
            const unsigned w0 = maskS[arow * 32 + kt * 2 + (apart >> 2)];
            const int bb = (apart & 3) * 8;
            union { ushortT u[8]; uint4 q; } tw;
#pragma unroll
            for (int e4 = 0; e4 < 2; ++e4) {
                const float4 dv = *(const float4*)&dstv[kt * 64 + apart * 8 + e4 * 4];
                const float vv[4] = {dv.x, dv.y, dv.z, dv.w};
#pragma unroll
                for (int e = 0; e < 4; ++e) {
                    float v = si + vv[e];
                    v = v >= 0.f ? v : ALPHA * v;
                    const unsigned bit = (w0 >> (bb + e4 * 4 + e)) & 1u;
                    const float p = bit ? __expf(v - mrow) : 0.f;
                    fsum += p;
                    tw.u[e4 * 4 + e] = f2bf(p);
                }
            }
            *(uint4*)&As[arow * 64 + (apart ^ (arow & 7)) * 8] = tw.q;
        }
        __syncthreads();
#pragma unroll
        for (int ks = 0; ks < 2; ++ks) {
            const int rowa = mfrag * 16 + m16;
            const int cla = (ks * 4 + quad) ^ (rowa & 7);
            const bf16x8 afr = *(const bf16x8*)&As[rowa * 64 + cla * 8];
#pragma unroll
            for (int ff = 0; ff < 2; ++ff) {
                const int rowb = (fh * 2 + ff) * 16 + m16;
                const int clb = (ks * 4 + quad) ^ (rowb & 7);
                const bf16x8 bfr = *(const bf16x8*)&Bs[rowb * 64 + clb * 8];
                acc[ff] = __builtin_amdgcn_mfma_f32_16x16x32_bf16(afr, bfr, acc[ff], 0, 0, 0);
            }
        }
    }
#pragma unroll
    for (int o = 1; o < 8; o <<= 1) fsum += __shfl_xor(fsum, o, 64);
    if ((lane & 7) == 0) rowinv[arow] = 1.f / fsum;
    __syncthreads();
    // ELU -> t2 tile in LDS
#pragma unroll
    for (int ff = 0; ff < 2; ++ff) {
#pragma unroll
        for (int reg = 0; reg < 4; ++reg) {
            const int row = mfrag * 16 + quad * 4 + reg;
            float v = acc[ff][reg] * rowinv[row];
            v = v > 0.f ? v : (__expf(v) - 1.f);
            t2s[row * 68 + (fh * 2 + ff) * 16 + m16] = v;
        }
    }
    __syncthreads();
    // FC: out = relu(t2 @ Wf + bf), 3-term hi/lo MFMA
    const int mf = wave >> 1, nh = wave & 1;
    f32x4 oacc[2];
#pragma unroll
    for (int g = 0; g < 2; ++g) {
        const float bias = bfv[(nh * 2 + g) * 16 + m16];
        oacc[g] = (f32x4){bias, bias, bias, bias};
    }
#pragma unroll
    for (int ks = 0; ks < 2; ++ks) {
        const int rowa = mf * 16 + m16;
        const float4 fA = *(const float4*)&t2s[rowa * 68 + ks * 32 + quad * 8];
        const float4 fB = *(const float4*)&t2s[rowa * 68 + ks * 32 + quad * 8 + 4];
        union { ushortT u[8]; bf16x8 v; } a_h, a_l;
        const float av[8] = {fA.x, fA.y, fA.z, fA.w, fB.x, fB.y, fB.z, fB.w};
#pragma unroll
        for (int e = 0; e < 8; ++e) split2(av[e], a_h.u[e], a_l.u[e]);
#pragma unroll
        for (int g = 0; g < 2; ++g) {
            const int rowc = (nh * 2 + g) * 16 + m16;
            const int cl = (ks * 4 + quad) ^ (rowc & 7);
            const bf16x8 b_h = *(const bf16x8*)&Wfh[rowc * 64 + cl * 8];
            const bf16x8 b_l = *(const bf16x8*)&Wfl[rowc * 64 + cl * 8];
            oacc[g] = __builtin_amdgcn_mfma_f32_16x16x32_bf16(a_h.v, b_h, oacc[g], 0, 0, 0);
            oacc[g] = __builtin_amdgcn_mfma_f32_16x16x32_bf16(a_h.v, b_l, oacc[g], 0, 0, 0);
            oacc[g] = __builtin_amdgcn_mfma_f32_16x16x32_bf16(a_l.v, b_h, oacc[g], 0, 0, 0);
        }
    }
#pragma unroll
    for (int g = 0; g < 2; ++g) {
        const int c = (nh * 2 + g) * 16 + m16;
#pragma unroll
        for (int reg = 0; reg < 4; ++reg) {
            const int i = i0 + mf * 16 + quad * 4 + reg;
            out[(size_t)(b * NN + i) * DOUT + c] = fmaxf(oacc[g][reg], 0.f);
        }
    }
}

extern "C" void kernel_launch(void* const* d_in, const int* in_sizes, int n_in,
                              void* d_out, int out_size, void* d_ws, size_t ws_size,
                              hipStream_t stream) {
    const float* x   = (const float*)d_in[0];
    const int*   adj = (const int*)d_in[1];
    const float* Wh  = (const float*)d_in[2];
    const float* ah  = (const float*)d_in[3];
    const float* Wo  = (const float*)d_in[4];
    const float* ao  = (const float*)d_in[5];
    const float* Wf  = (const float*)d_in[6];
    const float* bf  = (const float*)d_in[7];
    float* out = (float*)d_out;

    float* ws    = (float*)d_ws;
    float* src1  = ws;                                 // 4*8192
    float* dst1  = src1 + NH * RTOT;                   // 4*8192
    float* src2  = dst1 + NH * RTOT;                   // 8192
    float* dst2  = src2 + RTOT;                        // 8192
    ushortT* WhT   = (ushortT*)(dst2 + RTOT);                // 8192*512 bf16
    ushortT* Wh2T  = WhT + (size_t)RTOT * FCAT;              // 8192*64
    ushortT* xcatH = Wh2T + (size_t)RTOT * DOUT;             // 8192*512
    ushortT* xcatL = xcatH + (size_t)RTOT * FCAT;            // 8192*512
    ushortT* WbTh  = xcatL + (size_t)RTOT * FCAT;            // 131072
    ushortT* WbTl  = WbTh + NH * DH * DIN;
    ushortT* WoTh  = WbTl + NH * DH * DIN;                   // 32768
    ushortT* WoTl  = WoTh + DOUT * FCAT;
    unsigned* adjbit = (unsigned*)(WoTl + DOUT * FCAT);      // 262144 words

    hipLaunchKernelGGL(k_prep,  dim3(1024 + (NH * DH * DIN + DOUT * FCAT) / 256), dim3(256), 0, stream,
                       adj, Wh, Wo, adjbit, WbTh, WbTl, WoTh, WoTl);
    hipLaunchKernelGGL(k_wh1,   dim3(256), dim3(512), 0, stream,
                       x, ah, WbTh, WbTl, WhT, src1, dst1);
    hipLaunchKernelGGL(k_attn1, dim3(512), dim3(512), 0, stream,
                       adjbit, WhT, src1, dst1, xcatH, xcatL);
    hipLaunchKernelGGL(k_wh2,   dim3(RTOT / 16), dim3(256), 0, stream,
                       xcatH, xcatL, WoTh, WoTl, ao, Wh2T, src2, dst2);
    hipLaunchKernelGGL(k_attn2, dim3(256), dim3(256), 0, stream,
                       adjbit, Wh2T, src2, dst2, Wf, bf, out);
}

// Round 8
// 164.878 us; speedup vs baseline: 2.9914x; 1.0416x over previous
//
#include <hip/hip_runtime.h>
#include <hip/hip_bf16.h>

// Shapes (fixed by reference): B=8, N=1024, Din=256, H=4, Dh=128, Do=64
#define BSZ 8
#define NN 1024
#define DIN 256
#define NH 4
#define DH 128
#define DOUT 64
#define RTOT (BSZ*NN)          // 8192 rows total
#define FCAT (NH*DH)           // 512
#define ALPHA 0.2f

typedef unsigned short ushortT;
typedef __attribute__((ext_vector_type(8))) short bf16x8;
typedef __attribute__((ext_vector_type(4))) float f32x4;

static __device__ __forceinline__ ushortT f2bf(float f) {
    __hip_bfloat16 h = __float2bfloat16(f);
    return *reinterpret_cast<ushortT*>(&h);
}
static __device__ __forceinline__ float bfu2f(ushortT u) {
    return __uint_as_float(((unsigned)u) << 16);
}
static __device__ __forceinline__ void split2(float v, ushortT& hi, ushortT& lo) {
    hi = f2bf(v);
    lo = f2bf(v - bfu2f(hi));
}
// async global->LDS, 16B per lane; LDS dest = base(wave-uniform) + lane*16
static __device__ __forceinline__ void gload16(const ushortT* g, ushortT* l) {
    __builtin_amdgcn_global_load_lds(
        (const __attribute__((address_space(1))) unsigned int*)(const void*)g,
        (__attribute__((address_space(3))) unsigned int*)(void*)l, 16, 0, 0);
}

// ============ k_prepw: weight transforms only (bf16 hi/lo, k-contig) ============
__global__ __launch_bounds__(256) void k_prepw(const float* __restrict__ W,
                                               const float* __restrict__ Wout,
                                               ushortT* __restrict__ WbTh, ushortT* __restrict__ WbTl,
                                               ushortT* __restrict__ WoTh, ushortT* __restrict__ WoTl) {
    const int g2 = blockIdx.x * 256 + threadIdx.x;
    if (g2 < NH * DH * DIN) {           // 131072
        const int h = g2 >> 15, f = (g2 >> 8) & 127, k = g2 & 255;
        const int kt = k >> 6, k64 = k & 63;
        const float v = W[(size_t)h * DIN * DH + (size_t)k * DH + f];
        ushortT hi, lo; split2(v, hi, lo);
        const int idx = ((h * 4 + kt) * 128 + f) * 64 + k64;
        WbTh[idx] = hi; WbTl[idx] = lo;
    } else {
        const int g3 = g2 - NH * DH * DIN;   // < 32768
        const int f = g3 >> 9, k = g3 & 511;
        const float v = Wout[(size_t)k * DOUT + f];
        ushortT hi, lo; split2(v, hi, lo);
        WoTh[g3] = hi; WoTl[g3] = lo;
    }
}

// ============ k_main: blocks 0..255 = wh1 MFMA GEMM; blocks 256..767 = adj bit-pack ============
// wh1: grid-part 256 (h = bx>>6, mt = bx&63), 512 thr, tile M=128, F=128(head), K=256
__global__ __launch_bounds__(512) void k_main(const float* __restrict__ x,
                                              const float* __restrict__ ah_,
                                              const ushortT* __restrict__ WbTh,
                                              const ushortT* __restrict__ WbTl,
                                              const int* __restrict__ adj,
                                              unsigned* __restrict__ adjbit,
                                              ushortT* __restrict__ WhT,
                                              float* __restrict__ src1,
                                              float* __restrict__ dst1) {
    __shared__ ushortT Ah[128 * 64], Al[128 * 64];    // 32 KB
    __shared__ ushortT Bh[128 * 64], Bl[128 * 64];    // 32 KB
    __shared__ float sred[8][32], dred[8][32];
    const int tid = threadIdx.x;
    if (blockIdx.x >= 256) {
        // -------- adj pack: 512 blocks x 512 thr, one 32-bit word each --------
        const int g = (blockIdx.x - 256) * 512 + tid;     // 262144 words
        const int row = g >> 5, w = g & 31;
        const int4* p = (const int4*)(adj + (size_t)row * NN + w * 32);
        unsigned m = 0;
#pragma unroll
        for (int q = 0; q < 8; ++q) {
            const int4 v = p[q];
            m |= (v.x > 0 ? 1u : 0u) << (q * 4 + 0);
            m |= (v.y > 0 ? 1u : 0u) << (q * 4 + 1);
            m |= (v.z > 0 ? 1u : 0u) << (q * 4 + 2);
            m |= (v.w > 0 ? 1u : 0u) << (q * 4 + 3);
        }
        adjbit[g] = m;
        return;
    }
    // -------- wh1 --------
    const int lane = tid & 63, wave = tid >> 6;
    const int h = blockIdx.x >> 6, mt = blockIdx.x & 63;
    const int r0 = mt * 128, b = r0 >> 10, jr = r0 & 1023;
    const int m16 = lane & 15, quad = lane >> 4;
    const int mg = wave >> 1, fg = wave & 1;
    const int arow = tid >> 2, apart = tid & 3;
    f32x4 acc[2][4];
#pragma unroll
    for (int a = 0; a < 2; ++a)
#pragma unroll
        for (int c = 0; c < 4; ++c) acc[a][c] = (f32x4){0.f, 0.f, 0.f, 0.f};

    for (int kt = 0; kt < 4; ++kt) {
        __syncthreads();
        const ushortT* planeH = WbTh + (size_t)((h * 4 + kt) * 128) * 64;
        const ushortT* planeL = WbTl + (size_t)((h * 4 + kt) * 128) * 64;
#pragma unroll
        for (int half = 0; half < 2; ++half) {
            const int f = wave * 16 + half * 8 + (lane >> 3);
            const int sc = (lane & 7) ^ (f & 7);
            gload16(planeH + (size_t)f * 64 + sc * 8, Bh + (wave * 16 + half * 8) * 64);
            gload16(planeL + (size_t)f * 64 + sc * 8, Bl + (wave * 16 + half * 8) * 64);
        }
        {
            const float4* xs = (const float4*)(x + (size_t)(r0 + arow) * DIN + kt * 64 + apart * 16);
            union { ushortT u[16]; uint4 q[2]; } th, tl;
#pragma unroll
            for (int e = 0; e < 4; ++e) {
                const float4 v = xs[e];
                split2(v.x, th.u[e * 4 + 0], tl.u[e * 4 + 0]);
                split2(v.y, th.u[e * 4 + 1], tl.u[e * 4 + 1]);
                split2(v.z, th.u[e * 4 + 2], tl.u[e * 4 + 2]);
                split2(v.w, th.u[e * 4 + 3], tl.u[e * 4 + 3]);
            }
            const int s0 = (2 * apart) ^ (arow & 7), s1 = (2 * apart + 1) ^ (arow & 7);
            *(uint4*)&Ah[arow * 64 + s0 * 8] = th.q[0];
            *(uint4*)&Ah[arow * 64 + s1 * 8] = th.q[1];
            *(uint4*)&Al[arow * 64 + s0 * 8] = tl.q[0];
            *(uint4*)&Al[arow * 64 + s1 * 8] = tl.q[1];
        }
        __syncthreads();
#pragma unroll
        for (int ks = 0; ks < 2; ++ks) {
            bf16x8 a_h[2], a_l[2], b_h[4], b_l[4];
#pragma unroll
            for (int ms = 0; ms < 2; ++ms) {
                const int row = (mg * 2 + ms) * 16 + m16;
                const int cl = (ks * 4 + quad) ^ (row & 7);
                a_h[ms] = *(const bf16x8*)&Ah[row * 64 + cl * 8];
                a_l[ms] = *(const bf16x8*)&Al[row * 64 + cl * 8];
            }
#pragma unroll
            for (int fs = 0; fs < 4; ++fs) {
                const int row = (fg * 4 + fs) * 16 + m16;
                const int cl = (ks * 4 + quad) ^ (row & 7);
                b_h[fs] = *(const bf16x8*)&Bh[row * 64 + cl * 8];
                b_l[fs] = *(const bf16x8*)&Bl[row * 64 + cl * 8];
            }
#pragma unroll
            for (int ms = 0; ms < 2; ++ms)
#pragma unroll
                for (int fs = 0; fs < 4; ++fs) {
                    acc[ms][fs] = __builtin_amdgcn_mfma_f32_16x16x32_bf16(a_h[ms], b_h[fs], acc[ms][fs], 0, 0, 0);
                    acc[ms][fs] = __builtin_amdgcn_mfma_f32_16x16x32_bf16(a_h[ms], b_l[fs], acc[ms][fs], 0, 0, 0);
                    acc[ms][fs] = __builtin_amdgcn_mfma_f32_16x16x32_bf16(a_l[ms], b_h[fs], acc[ms][fs], 0, 0, 0);
                }
        }
    }
    float sacc[2][4] = {{0,0,0,0},{0,0,0,0}}, dacc[2][4] = {{0,0,0,0},{0,0,0,0}};
#pragma unroll
    for (int ms = 0; ms < 2; ++ms)
#pragma unroll
        for (int fs = 0; fs < 4; ++fs) {
            const int fl = (fg * 4 + fs) * 16 + m16;
            const float a_s = ah_[h * 2 * DH + fl];
            const float a_d = ah_[h * 2 * DH + DH + fl];
            union { ushortT u[4]; uint2 q; } tw;
#pragma unroll
            for (int reg = 0; reg < 4; ++reg) {
                const float v = acc[ms][fs][reg];
                sacc[ms][reg] += v * a_s;
                dacc[ms][reg] += v * a_d;
                tw.u[reg] = f2bf(v);
            }
            *(uint2*)(WhT + ((size_t)((b * NH + h) * DH + fl)) * NN + jr + (mg * 2 + ms) * 16 + quad * 4) = tw.q;
        }
#pragma unroll
    for (int ms = 0; ms < 2; ++ms) {
#pragma unroll
        for (int reg = 0; reg < 4; ++reg) {
            float s = sacc[ms][reg], d = dacc[ms][reg];
#pragma unroll
            for (int o = 8; o > 0; o >>= 1) {
                s += __shfl_xor(s, o, 64);
                d += __shfl_xor(d, o, 64);
            }
            if (m16 == 0) {
                sred[wave][ms * 16 + quad * 4 + reg] = s;
                dred[wave][ms * 16 + quad * 4 + reg] = d;
            }
        }
    }
    __syncthreads();
    if (tid < 128) {
        const int mgr = tid >> 5, idx = tid & 31;
        src1[h * RTOT + r0 + tid] = sred[mgr * 2][idx] + sred[mgr * 2 + 1][idx];
        dst1[h * RTOT + r0 + tid] = dred[mgr * 2][idx] + dred[mgr * 2 + 1][idx];
    }
}

// ============ k_attn1: fused single-pass softmax + PV GEMM (layer 1) ============
// grid 512 (bh = bx&31 -> b*4+h, it = bx>>5), 512 thr, tile M=64, F=128, K=1024 (16 kt)
__global__ __launch_bounds__(512) void k_attn1(const unsigned* __restrict__ adjbit,
                                               const ushortT* __restrict__ WhT,
                                               const float* __restrict__ src1,
                                               const float* __restrict__ dst1,
                                               ushortT* __restrict__ xcatH,
                                               ushortT* __restrict__ xcatL) {
    __shared__ ushortT As[64 * 64];                  // 8 KB
    __shared__ ushortT Bs[128 * 64];                 // 16 KB
    __shared__ unsigned maskS[64 * 32];              // 8 KB
    __shared__ float dstv[NN];                       // 4 KB
    __shared__ float srcv[64], rowinv[64], red8[8];
    const int tid = threadIdx.x, lane = tid & 63, wave = tid >> 6;
    const int bh = blockIdx.x & 31, it = blockIdx.x >> 5;
    const int b = bh >> 2, h = bh & 3;
    const int i0 = it * 64;
    const int m16 = lane & 15, quad = lane >> 4;
    const int mg = wave >> 1, fg = wave & 1;

    const unsigned* mbase = adjbit + (size_t)(b * NN + i0) * 32;
#pragma unroll
    for (int k2 = 0; k2 < 4; ++k2) maskS[tid + 512 * k2] = mbase[tid + 512 * k2];
    const float d0 = dst1[h * RTOT + b * NN + tid];
    const float d1 = dst1[h * RTOT + b * NN + tid + 512];
    dstv[tid] = d0; dstv[tid + 512] = d1;
    if (tid < 64) srcv[tid] = src1[h * RTOT + b * NN + i0 + tid];
    float lm = fmaxf(d0, d1);
#pragma unroll
    for (int o = 32; o > 0; o >>= 1) lm = fmaxf(lm, __shfl_xor(lm, o, 64));
    if (lane == 0) red8[wave] = lm;
    __syncthreads();
    const float dmax = fmaxf(fmaxf(fmaxf(red8[0], red8[1]), fmaxf(red8[2], red8[3])),
                             fmaxf(fmaxf(red8[4], red8[5]), fmaxf(red8[6], red8[7])));

    const int arow = tid >> 3, apart = tid & 7;      // 64 rows x 8 parts
    const float si = srcv[arow];
    float mrow = si + dmax;
    mrow = mrow >= 0.f ? mrow : ALPHA * mrow;        // per-row max (monotone leaky)
    float fsum = 0.f;

    const ushortT* Bbase = WhT + (size_t)(bh * DH) * NN;
    f32x4 acc[4];
#pragma unroll
    for (int c = 0; c < 4; ++c) acc[c] = (f32x4){0.f, 0.f, 0.f, 0.f};

    for (int kt = 0; kt < 16; ++kt) {
        __syncthreads();
#pragma unroll
        for (int half = 0; half < 2; ++half) {
            const int f = wave * 16 + half * 8 + (lane >> 3);
            gload16(Bbase + (size_t)f * NN + kt * 64 + (((lane & 7) ^ (f & 7)) * 8),
                    Bs + (wave * 16 + half * 8) * 64);
        }
        {
            const unsigned w0 = maskS[arow * 32 + kt * 2 + (apart >> 2)];
            const int bb = (apart & 3) * 8;
            union { ushortT u[8]; uint4 q; } tw;
#pragma unroll
            for (int e4 = 0; e4 < 2; ++e4) {
                const float4 dv = *(const float4*)&dstv[kt * 64 + apart * 8 + e4 * 4];
                const float vv[4] = {dv.x, dv.y, dv.z, dv.w};
#pragma unroll
                for (int e = 0; e < 4; ++e) {
                    float v = si + vv[e];
                    v = v >= 0.f ? v : ALPHA * v;
                    const unsigned bit = (w0 >> (bb + e4 * 4 + e)) & 1u;
                    const float p = bit ? __expf(v - mrow) : 0.f;
                    fsum += p;
                    tw.u[e4 * 4 + e] = f2bf(p);
                }
            }
            *(uint4*)&As[arow * 64 + (apart ^ (arow & 7)) * 8] = tw.q;
        }
        __syncthreads();
#pragma unroll
        for (int ks = 0; ks < 2; ++ks) {
            const int rowa = mg * 16 + m16;
            const int cla = (ks * 4 + quad) ^ (rowa & 7);
            const bf16x8 afr = *(const bf16x8*)&As[rowa * 64 + cla * 8];
#pragma unroll
            for (int fs = 0; fs < 4; ++fs) {
                const int rowb = fg * 64 + fs * 16 + m16;
                const int clb = (ks * 4 + quad) ^ (rowb & 7);
                const bf16x8 bfr = *(const bf16x8*)&Bs[rowb * 64 + clb * 8];
                acc[fs] = __builtin_amdgcn_mfma_f32_16x16x32_bf16(afr, bfr, acc[fs], 0, 0, 0);
            }
        }
    }
#pragma unroll
    for (int o = 1; o < 8; o <<= 1) fsum += __shfl_xor(fsum, o, 64);
    if ((lane & 7) == 0) rowinv[arow] = 1.f / fsum;
    __syncthreads();
    float rv[4];
#pragma unroll
    for (int reg = 0; reg < 4; ++reg) rv[reg] = rowinv[mg * 16 + quad * 4 + reg];
#pragma unroll
    for (int fs = 0; fs < 4; ++fs) {
        const int f = h * DH + fg * 64 + fs * 16 + m16;
#pragma unroll
        for (int reg = 0; reg < 4; ++reg) {
            const int i = i0 + mg * 16 + quad * 4 + reg;
            const float v = acc[fs][reg] * rv[reg];
            const size_t idx = (size_t)(b * NN + i) * FCAT + f;
            ushortT hi, lo; split2(v, hi, lo);
            xcatH[idx] = hi;
            xcatL[idx] = lo;
        }
    }
}

// ============ k_wh2: Wh2 = xcat @ W_out (hi/lo MFMA) + fused src2/dst2 ============
__global__ __launch_bounds__(256) void k_wh2(const ushortT* __restrict__ xcatH,
                                             const ushortT* __restrict__ xcatL,
                                             const ushortT* __restrict__ WoTh,
                                             const ushortT* __restrict__ WoTl,
                                             const float* __restrict__ aout,
                                             ushortT* __restrict__ Wh2T,
                                             float* __restrict__ src2,
                                             float* __restrict__ dst2) {
    __shared__ float sred[4][16], dred[4][16];
    const int tid = threadIdx.x;
    const int r0  = blockIdx.x * 16;
    const int b   = r0 >> 10, jr = r0 & 1023;
    const int lane = tid & 63, wave = tid >> 6;
    const int quad = lane >> 4, n = lane & 15;
    const int f0 = wave * 16;
    const ushortT* ahp = xcatH + (size_t)(r0 + n) * FCAT + quad * 8;
    const ushortT* alp = xcatL + (size_t)(r0 + n) * FCAT + quad * 8;
    const ushortT* bhp = WoTh + (size_t)(f0 + n) * FCAT + quad * 8;
    const ushortT* blp = WoTl + (size_t)(f0 + n) * FCAT + quad * 8;
    f32x4 acc = {0.f, 0.f, 0.f, 0.f};
#pragma unroll
    for (int s = 0; s < 16; ++s) {
        const int off = 32 * s;
        const bf16x8 ah = *(const bf16x8*)(ahp + off);
        const bf16x8 al = *(const bf16x8*)(alp + off);
        const bf16x8 bh = *(const bf16x8*)(bhp + off);
        const bf16x8 bl = *(const bf16x8*)(blp + off);
        acc = __builtin_amdgcn_mfma_f32_16x16x32_bf16(ah, bh, acc, 0, 0, 0);
        acc = __builtin_amdgcn_mfma_f32_16x16x32_bf16(ah, bl, acc, 0, 0, 0);
        acc = __builtin_amdgcn_mfma_f32_16x16x32_bf16(al, bh, acc, 0, 0, 0);
    }
    const int f = f0 + n;
    const float a_s = aout[f], a_d = aout[DOUT + f];
    float sv[4], dv[4];
    union { ushortT u[4]; uint2 q; } tw;
#pragma unroll
    for (int reg = 0; reg < 4; ++reg) {
        const float v = acc[reg];
        sv[reg] = v * a_s; dv[reg] = v * a_d;
        tw.u[reg] = f2bf(v);
    }
    *(uint2*)(Wh2T + ((size_t)(b * DOUT + f)) * NN + jr + quad * 4) = tw.q;
#pragma unroll
    for (int reg = 0; reg < 4; ++reg) {
#pragma unroll
        for (int o = 8; o > 0; o >>= 1) {
            sv[reg] += __shfl_xor(sv[reg], o, 64);
            dv[reg] += __shfl_xor(dv[reg], o, 64);
        }
        if (n == 0) { sred[wave][quad * 4 + reg] = sv[reg]; dred[wave][quad * 4 + reg] = dv[reg]; }
    }
    __syncthreads();
    if (tid < 16) {
        src2[r0 + tid] = sred[0][tid] + sred[1][tid] + sred[2][tid] + sred[3][tid];
        dst2[r0 + tid] = dred[0][tid] + dred[1][tid] + dred[2][tid] + dred[3][tid];
    }
}

// ============ k_attn2: single-pass softmax + PV + ELU + FC + ReLU (layer 2) ============
// grid 256 (b = bx&7, it = bx>>3), 256 thr, tile M=32, F=64, K=1024 (16 kt)
__global__ __launch_bounds__(256) void k_attn2(const unsigned* __restrict__ adjbit,
                                               const ushortT* __restrict__ Wh2T,
                                               const float* __restrict__ src2,
                                               const float* __restrict__ dst2,
                                               const float* __restrict__ Wf,
                                               const float* __restrict__ bfv,
                                               float* __restrict__ out) {
    __shared__ ushortT As[32 * 64];                 // 4 KB
    __shared__ ushortT Bs[64 * 64];                 // 8 KB
    __shared__ unsigned maskS[32 * 32];             // 4 KB
    __shared__ float dstv[NN];                      // 4 KB
    __shared__ ushortT Wfh[64 * 64], Wfl[64 * 64];  // 16 KB
    __shared__ float t2s[32 * 68];                  // 8.5 KB
    __shared__ float srcv[32], rowinv[32], red4[4];
    const int tid = threadIdx.x, lane = tid & 63, wave = tid >> 6;
    const int b = blockIdx.x & 7, it = blockIdx.x >> 3;
    const int i0 = it * 32;
    const int m16 = lane & 15, quad = lane >> 4;

    const unsigned* mbase = adjbit + (size_t)(b * NN + i0) * 32;
#pragma unroll
    for (int k2 = 0; k2 < 4; ++k2) maskS[tid + 256 * k2] = mbase[tid + 256 * k2];
    float lm = -INFINITY;
#pragma unroll
    for (int k2 = 0; k2 < 4; ++k2) {
        const float d = dst2[b * NN + tid + 256 * k2];
        dstv[tid + 256 * k2] = d;
        lm = fmaxf(lm, d);
    }
    if (tid < 32) srcv[tid] = src2[b * NN + i0 + tid];
    {   // stage Wf as hi/lo, layout [c][k] swizzled
        const int c = tid & 63, kc = (tid >> 6) * 16;
        union { ushortT u[16]; uint4 q[2]; } th, tl;
#pragma unroll
        for (int e = 0; e < 16; ++e)
            split2(Wf[(size_t)(kc + e) * DOUT + c], th.u[e], tl.u[e]);
        const int s0 = ((tid >> 6) * 2) ^ (c & 7), s1 = ((tid >> 6) * 2 + 1) ^ (c & 7);
        *(uint4*)&Wfh[c * 64 + s0 * 8] = th.q[0];
        *(uint4*)&Wfh[c * 64 + s1 * 8] = th.q[1];
        *(uint4*)&Wfl[c * 64 + s0 * 8] = tl.q[0];
        *(uint4*)&Wfl[c * 64 + s1 * 8] = tl.q[1];
    }
#pragma unroll
    for (int o = 32; o > 0; o >>= 1) lm = fmaxf(lm, __shfl_xor(lm, o, 64));
    if (lane == 0) red4[wave] = lm;
    __syncthreads();
    const float dmax = fmaxf(fmaxf(red4[0], red4[1]), fmaxf(red4[2], red4[3]));

    const int arow = tid >> 3, apart = tid & 7;      // 32 rows x 8 parts
    const float si = srcv[arow];
    float mrow = si + dmax;
    mrow = mrow >= 0.f ? mrow : ALPHA * mrow;
    float fsum = 0.f;

    const int mfrag = wave >> 1, fh = wave & 1;
    const ushortT* Bbase = Wh2T + (size_t)(b * DOUT) * NN;
    f32x4 acc[2] = {(f32x4){0.f,0.f,0.f,0.f}, (f32x4){0.f,0.f,0.f,0.f}};

    for (int kt = 0; kt < 16; ++kt) {
        __syncthreads();
#pragma unroll
        for (int half = 0; half < 2; ++half) {
            const int f = wave * 16 + half * 8 + (lane >> 3);
            gload16(Bbase + (size_t)f * NN + kt * 64 + (((lane & 7) ^ (f & 7)) * 8),
                    Bs + (wave * 16 + half * 8) * 64);
        }
        {
            const unsigned w0 = maskS[arow * 32 + kt * 2 + (apart >> 2)];
            const int bb = (apart & 3) * 8;
            union { ushortT u[8]; uint4 q; } tw;
#pragma unroll
            for (int e4 = 0; e4 < 2; ++e4) {
                const float4 dv = *(const float4*)&dstv[kt * 64 + apart * 8 + e4 * 4];
                const float vv[4] = {dv.x, dv.y, dv.z, dv.w};
#pragma unroll
                for (int e = 0; e < 4; ++e) {
                    float v = si + vv[e];
                    v = v >= 0.f ? v : ALPHA * v;
                    const unsigned bit = (w0 >> (bb + e4 * 4 + e)) & 1u;
                    const float p = bit ? __expf(v - mrow) : 0.f;
                    fsum += p;
                    tw.u[e4 * 4 + e] = f2bf(p);
                }
            }
            *(uint4*)&As[arow * 64 + (apart ^ (arow & 7)) * 8] = tw.q;
        }
        __syncthreads();
#pragma unroll
        for (int ks = 0; ks < 2; ++ks) {
            const int rowa = mfrag * 16 + m16;
            const int cla = (ks * 4 + quad) ^ (rowa & 7);
            const bf16x8 afr = *(const bf16x8*)&As[rowa * 64 + cla * 8];
#pragma unroll
            for (int ff = 0; ff < 2; ++ff) {
                const int rowb = (fh * 2 + ff) * 16 + m16;
                const int clb = (ks * 4 + quad) ^ (rowb & 7);
                const bf16x8 bfr = *(const bf16x8*)&Bs[rowb * 64 + clb * 8];
                acc[ff] = __builtin_amdgcn_mfma_f32_16x16x32_bf16(afr, bfr, acc[ff], 0, 0, 0);
            }
        }
    }
#pragma unroll
    for (int o = 1; o < 8; o <<= 1) fsum += __shfl_xor(fsum, o, 64);
    if ((lane & 7) == 0) rowinv[arow] = 1.f / fsum;
    __syncthreads();
#pragma unroll
    for (int ff = 0; ff < 2; ++ff) {
#pragma unroll
        for (int reg = 0; reg < 4; ++reg) {
            const int row = mfrag * 16 + quad * 4 + reg;
            float v = acc[ff][reg] * rowinv[row];
            v = v > 0.f ? v : (__expf(v) - 1.f);
            t2s[row * 68 + (fh * 2 + ff) * 16 + m16] = v;
        }
    }
    __syncthreads();
    const int mf = wave >> 1, nh = wave & 1;
    f32x4 oacc[2];
#pragma unroll
    for (int g = 0; g < 2; ++g) {
        const float bias = bfv[(nh * 2 + g) * 16 + m16];
        oacc[g] = (f32x4){bias, bias, bias, bias};
    }
#pragma unroll
    for (int ks = 0; ks < 2; ++ks) {
        const int rowa = mf * 16 + m16;
        const float4 fA = *(const float4*)&t2s[rowa * 68 + ks * 32 + quad * 8];
        const float4 fB = *(const float4*)&t2s[rowa * 68 + ks * 32 + quad * 8 + 4];
        union { ushortT u[8]; bf16x8 v; } a_h, a_l;
        const float av[8] = {fA.x, fA.y, fA.z, fA.w, fB.x, fB.y, fB.z, fB.w};
#pragma unroll
        for (int e = 0; e < 8; ++e) split2(av[e], a_h.u[e], a_l.u[e]);
#pragma unroll
        for (int g = 0; g < 2; ++g) {
            const int rowc = (nh * 2 + g) * 16 + m16;
            const int cl = (ks * 4 + quad) ^ (rowc & 7);
            const bf16x8 b_h = *(const bf16x8*)&Wfh[rowc * 64 + cl * 8];
            const bf16x8 b_l = *(const bf16x8*)&Wfl[rowc * 64 + cl * 8];
            oacc[g] = __builtin_amdgcn_mfma_f32_16x16x32_bf16(a_h.v, b_h, oacc[g], 0, 0, 0);
            oacc[g] = __builtin_amdgcn_mfma_f32_16x16x32_bf16(a_h.v, b_l, oacc[g], 0, 0, 0);
            oacc[g] = __builtin_amdgcn_mfma_f32_16x16x32_bf16(a_l.v, b_h, oacc[g], 0, 0, 0);
        }
    }
#pragma unroll
    for (int g = 0; g < 2; ++g) {
        const int c = (nh * 2 + g) * 16 + m16;
#pragma unroll
        for (int reg = 0; reg < 4; ++reg) {
            const int i = i0 + mf * 16 + quad * 4 + reg;
            out[(size_t)(b * NN + i) * DOUT + c] = fmaxf(oacc[g][reg], 0.f);
        }
    }
}

extern "C" void kernel_launch(void* const* d_in, const int* in_sizes, int n_in,
                              void* d_out, int out_size, void* d_ws, size_t ws_size,
                              hipStream_t stream) {
    const float* x   = (const float*)d_in[0];
    const int*   adj = (const int*)d_in[1];
    const float* Wh  = (const float*)d_in[2];
    const float* ah  = (const float*)d_in[3];
    const float* Wo  = (const float*)d_in[4];
    const float* ao  = (const float*)d_in[5];
    const float* Wf  = (const float*)d_in[6];
    const float* bf  = (const float*)d_in[7];
    float* out = (float*)d_out;

    float* ws    = (float*)d_ws;
    float* src1  = ws;                                 // 4*8192
    float* dst1  = src1 + NH * RTOT;                   // 4*8192
    float* src2  = dst1 + NH * RTOT;                   // 8192
    float* dst2  = src2 + RTOT;                        // 8192
    ushortT* WhT   = (ushortT*)(dst2 + RTOT);                // 8192*512 bf16
    ushortT* Wh2T  = WhT + (size_t)RTOT * FCAT;              // 8192*64
    ushortT* xcatH = Wh2T + (size_t)RTOT * DOUT;             // 8192*512
    ushortT* xcatL = xcatH + (size_t)RTOT * FCAT;            // 8192*512
    ushortT* WbTh  = xcatL + (size_t)RTOT * FCAT;            // 131072
    ushortT* WbTl  = WbTh + NH * DH * DIN;
    ushortT* WoTh  = WbTl + NH * DH * DIN;                   // 32768
    ushortT* WoTl  = WoTh + DOUT * FCAT;
    unsigned* adjbit = (unsigned*)(WoTl + DOUT * FCAT);      // 262144 words

    hipLaunchKernelGGL(k_prepw, dim3((NH * DH * DIN + DOUT * FCAT) / 256), dim3(256), 0, stream,
                       Wh, Wo, WbTh, WbTl, WoTh, WoTl);
    hipLaunchKernelGGL(k_main,  dim3(768), dim3(512), 0, stream,
                       x, ah, WbTh, WbTl, adj, adjbit, WhT, src1, dst1);
    hipLaunchKernelGGL(k_attn1, dim3(512), dim3(512), 0, stream,
                       adjbit, WhT, src1, dst1, xcatH, xcatL);
    hipLaunchKernelGGL(k_wh2,   dim3(RTOT / 16), dim3(256), 0, stream,
                       xcatH, xcatL, WoTh, WoTl, ao, Wh2T, src2, dst2);
    hipLaunchKernelGGL(k_attn2, dim3(256), dim3(256), 0, stream,
                       adjbit, Wh2T, src2, dst2, Wf, bf, out);
}

// Round 9
// 157.381 us; speedup vs baseline: 3.1340x; 1.0476x over previous
//
#include <hip/hip_runtime.h>
#include <hip/hip_bf16.h>

// Shapes (fixed by reference): B=8, N=1024, Din=256, H=4, Dh=128, Do=64
#define BSZ 8
#define NN 1024
#define DIN 256
#define NH 4
#define DH 128
#define DOUT 64
#define RTOT (BSZ*NN)          // 8192 rows total
#define FCAT (NH*DH)           // 512
#define ALPHA 0.2f

typedef unsigned short ushortT;
typedef __attribute__((ext_vector_type(8))) short bf16x8;
typedef __attribute__((ext_vector_type(4))) float f32x4;

static __device__ __forceinline__ ushortT f2bf(float f) {
    __hip_bfloat16 h = __float2bfloat16(f);
    return *reinterpret_cast<ushortT*>(&h);
}
static __device__ __forceinline__ float bfu2f(ushortT u) {
    return __uint_as_float(((unsigned)u) << 16);
}
static __device__ __forceinline__ void split2(float v, ushortT& hi, ushortT& lo) {
    hi = f2bf(v);
    lo = f2bf(v - bfu2f(hi));
}
// async global->LDS, 16B per lane; LDS dest = base(wave-uniform) + lane*16
static __device__ __forceinline__ void gload16(const ushortT* g, ushortT* l) {
    __builtin_amdgcn_global_load_lds(
        (const __attribute__((address_space(1))) unsigned int*)(const void*)g,
        (__attribute__((address_space(3))) unsigned int*)(void*)l, 16, 0, 0);
}

// ============ k_prepw: weight transforms only (bf16 hi/lo, k-contig) ============
__global__ __launch_bounds__(256) void k_prepw(const float* __restrict__ W,
                                               const float* __restrict__ Wout,
                                               ushortT* __restrict__ WbTh, ushortT* __restrict__ WbTl,
                                               ushortT* __restrict__ WoTh, ushortT* __restrict__ WoTl) {
    const int g2 = blockIdx.x * 256 + threadIdx.x;
    if (g2 < NH * DH * DIN) {           // 131072
        const int h = g2 >> 15, f = (g2 >> 8) & 127, k = g2 & 255;
        const int kt = k >> 6, k64 = k & 63;
        const float v = W[(size_t)h * DIN * DH + (size_t)k * DH + f];
        ushortT hi, lo; split2(v, hi, lo);
        const int idx = ((h * 4 + kt) * 128 + f) * 64 + k64;
        WbTh[idx] = hi; WbTl[idx] = lo;
    } else {
        const int g3 = g2 - NH * DH * DIN;   // < 32768
        const int f = g3 >> 9, k = g3 & 511;
        const float v = Wout[(size_t)k * DOUT + f];
        ushortT hi, lo; split2(v, hi, lo);
        WoTh[g3] = hi; WoTl[g3] = lo;
    }
}

// ============ k_main: blocks 0..255 = wh1 MFMA GEMM; blocks 256..767 = adj bit-pack ============
__global__ __launch_bounds__(512) void k_main(const float* __restrict__ x,
                                              const float* __restrict__ ah_,
                                              const ushortT* __restrict__ WbTh,
                                              const ushortT* __restrict__ WbTl,
                                              const int* __restrict__ adj,
                                              unsigned* __restrict__ adjbit,
                                              ushortT* __restrict__ WhT,
                                              float* __restrict__ src1,
                                              float* __restrict__ dst1) {
    __shared__ ushortT Ah[128 * 64], Al[128 * 64];    // 32 KB
    __shared__ ushortT Bh[128 * 64], Bl[128 * 64];    // 32 KB
    __shared__ float sred[8][32], dred[8][32];
    const int tid = threadIdx.x;
    if (blockIdx.x >= 256) {
        const int g = (blockIdx.x - 256) * 512 + tid;     // 262144 words
        const int row = g >> 5, w = g & 31;
        const int4* p = (const int4*)(adj + (size_t)row * NN + w * 32);
        unsigned m = 0;
#pragma unroll
        for (int q = 0; q < 8; ++q) {
            const int4 v = p[q];
            m |= (v.x > 0 ? 1u : 0u) << (q * 4 + 0);
            m |= (v.y > 0 ? 1u : 0u) << (q * 4 + 1);
            m |= (v.z > 0 ? 1u : 0u) << (q * 4 + 2);
            m |= (v.w > 0 ? 1u : 0u) << (q * 4 + 3);
        }
        adjbit[g] = m;
        return;
    }
    const int lane = tid & 63, wave = tid >> 6;
    const int h = blockIdx.x >> 6, mt = blockIdx.x & 63;
    const int r0 = mt * 128, b = r0 >> 10, jr = r0 & 1023;
    const int m16 = lane & 15, quad = lane >> 4;
    const int mg = wave >> 1, fg = wave & 1;
    const int arow = tid >> 2, apart = tid & 3;
    f32x4 acc[2][4];
#pragma unroll
    for (int a = 0; a < 2; ++a)
#pragma unroll
        for (int c = 0; c < 4; ++c) acc[a][c] = (f32x4){0.f, 0.f, 0.f, 0.f};

    for (int kt = 0; kt < 4; ++kt) {
        __syncthreads();
        const ushortT* planeH = WbTh + (size_t)((h * 4 + kt) * 128) * 64;
        const ushortT* planeL = WbTl + (size_t)((h * 4 + kt) * 128) * 64;
#pragma unroll
        for (int half = 0; half < 2; ++half) {
            const int f = wave * 16 + half * 8 + (lane >> 3);
            const int sc = (lane & 7) ^ (f & 7);
            gload16(planeH + (size_t)f * 64 + sc * 8, Bh + (wave * 16 + half * 8) * 64);
            gload16(planeL + (size_t)f * 64 + sc * 8, Bl + (wave * 16 + half * 8) * 64);
        }
        {
            const float4* xs = (const float4*)(x + (size_t)(r0 + arow) * DIN + kt * 64 + apart * 16);
            union { ushortT u[16]; uint4 q[2]; } th, tl;
#pragma unroll
            for (int e = 0; e < 4; ++e) {
                const float4 v = xs[e];
                split2(v.x, th.u[e * 4 + 0], tl.u[e * 4 + 0]);
                split2(v.y, th.u[e * 4 + 1], tl.u[e * 4 + 1]);
                split2(v.z, th.u[e * 4 + 2], tl.u[e * 4 + 2]);
                split2(v.w, th.u[e * 4 + 3], tl.u[e * 4 + 3]);
            }
            const int s0 = (2 * apart) ^ (arow & 7), s1 = (2 * apart + 1) ^ (arow & 7);
            *(uint4*)&Ah[arow * 64 + s0 * 8] = th.q[0];
            *(uint4*)&Ah[arow * 64 + s1 * 8] = th.q[1];
            *(uint4*)&Al[arow * 64 + s0 * 8] = tl.q[0];
            *(uint4*)&Al[arow * 64 + s1 * 8] = tl.q[1];
        }
        __syncthreads();
#pragma unroll
        for (int ks = 0; ks < 2; ++ks) {
            bf16x8 a_h[2], a_l[2], b_h[4], b_l[4];
#pragma unroll
            for (int ms = 0; ms < 2; ++ms) {
                const int row = (mg * 2 + ms) * 16 + m16;
                const int cl = (ks * 4 + quad) ^ (row & 7);
                a_h[ms] = *(const bf16x8*)&Ah[row * 64 + cl * 8];
                a_l[ms] = *(const bf16x8*)&Al[row * 64 + cl * 8];
            }
#pragma unroll
            for (int fs = 0; fs < 4; ++fs) {
                const int row = (fg * 4 + fs) * 16 + m16;
                const int cl = (ks * 4 + quad) ^ (row & 7);
                b_h[fs] = *(const bf16x8*)&Bh[row * 64 + cl * 8];
                b_l[fs] = *(const bf16x8*)&Bl[row * 64 + cl * 8];
            }
#pragma unroll
            for (int ms = 0; ms < 2; ++ms)
#pragma unroll
                for (int fs = 0; fs < 4; ++fs) {
                    acc[ms][fs] = __builtin_amdgcn_mfma_f32_16x16x32_bf16(a_h[ms], b_h[fs], acc[ms][fs], 0, 0, 0);
                    acc[ms][fs] = __builtin_amdgcn_mfma_f32_16x16x32_bf16(a_h[ms], b_l[fs], acc[ms][fs], 0, 0, 0);
                    acc[ms][fs] = __builtin_amdgcn_mfma_f32_16x16x32_bf16(a_l[ms], b_h[fs], acc[ms][fs], 0, 0, 0);
                }
        }
    }
    float sacc[2][4] = {{0,0,0,0},{0,0,0,0}}, dacc[2][4] = {{0,0,0,0},{0,0,0,0}};
#pragma unroll
    for (int ms = 0; ms < 2; ++ms)
#pragma unroll
        for (int fs = 0; fs < 4; ++fs) {
            const int fl = (fg * 4 + fs) * 16 + m16;
            const float a_s = ah_[h * 2 * DH + fl];
            const float a_d = ah_[h * 2 * DH + DH + fl];
            union { ushortT u[4]; uint2 q; } tw;
#pragma unroll
            for (int reg = 0; reg < 4; ++reg) {
                const float v = acc[ms][fs][reg];
                sacc[ms][reg] += v * a_s;
                dacc[ms][reg] += v * a_d;
                tw.u[reg] = f2bf(v);
            }
            *(uint2*)(WhT + ((size_t)((b * NH + h) * DH + fl)) * NN + jr + (mg * 2 + ms) * 16 + quad * 4) = tw.q;
        }
#pragma unroll
    for (int ms = 0; ms < 2; ++ms) {
#pragma unroll
        for (int reg = 0; reg < 4; ++reg) {
            float s = sacc[ms][reg], d = dacc[ms][reg];
#pragma unroll
            for (int o = 8; o > 0; o >>= 1) {
                s += __shfl_xor(s, o, 64);
                d += __shfl_xor(d, o, 64);
            }
            if (m16 == 0) {
                sred[wave][ms * 16 + quad * 4 + reg] = s;
                dred[wave][ms * 16 + quad * 4 + reg] = d;
            }
        }
    }
    __syncthreads();
    if (tid < 128) {
        const int mgr = tid >> 5, idx = tid & 31;
        src1[h * RTOT + r0 + tid] = sred[mgr * 2][idx] + sred[mgr * 2 + 1][idx];
        dst1[h * RTOT + r0 + tid] = dred[mgr * 2][idx] + dred[mgr * 2 + 1][idx];
    }
}

// ============ k_attn1: fused single-pass softmax + PV GEMM (layer 1) ============
// grid 512 (bh = bx&31 -> b*4+h, it = bx>>5), 512 thr, tile M=64, F=128, K=1024 (16 kt)
__global__ __launch_bounds__(512) void k_attn1(const unsigned* __restrict__ adjbit,
                                               const ushortT* __restrict__ WhT,
                                               const float* __restrict__ src1,
                                               const float* __restrict__ dst1,
                                               ushortT* __restrict__ xcat) {
    __shared__ ushortT As[64 * 64];                  // 8 KB
    __shared__ ushortT Bs[128 * 64];                 // 16 KB
    __shared__ unsigned maskS[64 * 32];              // 8 KB
    __shared__ float dstv[NN];                       // 4 KB
    __shared__ float srcv[64], rowinv[64], red8[8];
    const int tid = threadIdx.x, lane = tid & 63, wave = tid >> 6;
    const int bh = blockIdx.x & 31, it = blockIdx.x >> 5;
    const int b = bh >> 2, h = bh & 3;
    const int i0 = it * 64;
    const int m16 = lane & 15, quad = lane >> 4;
    const int mg = wave >> 1, fg = wave & 1;

    const unsigned* mbase = adjbit + (size_t)(b * NN + i0) * 32;
#pragma unroll
    for (int k2 = 0; k2 < 4; ++k2) maskS[tid + 512 * k2] = mbase[tid + 512 * k2];
    const float d0 = dst1[h * RTOT + b * NN + tid];
    const float d1 = dst1[h * RTOT + b * NN + tid + 512];
    dstv[tid] = d0; dstv[tid + 512] = d1;
    if (tid < 64) srcv[tid] = src1[h * RTOT + b * NN + i0 + tid];
    float lm = fmaxf(d0, d1);
#pragma unroll
    for (int o = 32; o > 0; o >>= 1) lm = fmaxf(lm, __shfl_xor(lm, o, 64));
    if (lane == 0) red8[wave] = lm;
    __syncthreads();
    const float dmax = fmaxf(fmaxf(fmaxf(red8[0], red8[1]), fmaxf(red8[2], red8[3])),
                             fmaxf(fmaxf(red8[4], red8[5]), fmaxf(red8[6], red8[7])));

    const int arow = tid >> 3, apart = tid & 7;      // 64 rows x 8 parts
    const float si = srcv[arow];
    float mrow = si + dmax;
    mrow = mrow >= 0.f ? mrow : ALPHA * mrow;        // per-row max (monotone leaky)
    float fsum = 0.f;

    const ushortT* Bbase = WhT + (size_t)(bh * DH) * NN;
    f32x4 acc[4];
#pragma unroll
    for (int c = 0; c < 4; ++c) acc[c] = (f32x4){0.f, 0.f, 0.f, 0.f};

    for (int kt = 0; kt < 16; ++kt) {
        __syncthreads();
#pragma unroll
        for (int half = 0; half < 2; ++half) {
            const int f = wave * 16 + half * 8 + (lane >> 3);
            gload16(Bbase + (size_t)f * NN + kt * 64 + (((lane & 7) ^ (f & 7)) * 8),
                    Bs + (wave * 16 + half * 8) * 64);
        }
        {
            const unsigned w0 = maskS[arow * 32 + kt * 2 + (apart >> 2)];
            const int bb = (apart & 3) * 8;
            union { ushortT u[8]; uint4 q; } tw;
#pragma unroll
            for (int e4 = 0; e4 < 2; ++e4) {
                const float4 dv = *(const float4*)&dstv[kt * 64 + apart * 8 + e4 * 4];
                const float vv[4] = {dv.x, dv.y, dv.z, dv.w};
#pragma unroll
                for (int e = 0; e < 4; ++e) {
                    float v = si + vv[e];
                    v = v >= 0.f ? v : ALPHA * v;
                    const unsigned bit = (w0 >> (bb + e4 * 4 + e)) & 1u;
                    const float p = bit ? __expf(v - mrow) : 0.f;
                    fsum += p;
                    tw.u[e4 * 4 + e] = f2bf(p);
                }
            }
            *(uint4*)&As[arow * 64 + (apart ^ (arow & 7)) * 8] = tw.q;
        }
        __syncthreads();
#pragma unroll
        for (int ks = 0; ks < 2; ++ks) {
            const int rowa = mg * 16 + m16;
            const int cla = (ks * 4 + quad) ^ (rowa & 7);
            const bf16x8 afr = *(const bf16x8*)&As[rowa * 64 + cla * 8];
#pragma unroll
            for (int fs = 0; fs < 4; ++fs) {
                const int rowb = fg * 64 + fs * 16 + m16;
                const int clb = (ks * 4 + quad) ^ (rowb & 7);
                const bf16x8 bfr = *(const bf16x8*)&Bs[rowb * 64 + clb * 8];
                acc[fs] = __builtin_amdgcn_mfma_f32_16x16x32_bf16(afr, bfr, acc[fs], 0, 0, 0);
            }
        }
    }
#pragma unroll
    for (int o = 1; o < 8; o <<= 1) fsum += __shfl_xor(fsum, o, 64);
    if ((lane & 7) == 0) rowinv[arow] = 1.f / fsum;
    __syncthreads();
    float rv[4];
#pragma unroll
    for (int reg = 0; reg < 4; ++reg) rv[reg] = rowinv[mg * 16 + quad * 4 + reg];
#pragma unroll
    for (int fs = 0; fs < 4; ++fs) {
        const int f = h * DH + fg * 64 + fs * 16 + m16;
#pragma unroll
        for (int reg = 0; reg < 4; ++reg) {
            const int i = i0 + mg * 16 + quad * 4 + reg;
            xcat[(size_t)(b * NN + i) * FCAT + f] = f2bf(acc[fs][reg] * rv[reg]);
        }
    }
}

// ============ k_wh2: Wh2 = xcat @ W_out, staged GEMM, fused Wh2T + src2/dst2 ============
// grid 256 (r0 = bx*32), 256 thr (4 waves), tile M=32, F=64, K=512 (8 kt)
__global__ __launch_bounds__(256) void k_wh2(const ushortT* __restrict__ xcat,
                                             const ushortT* __restrict__ WoTh,
                                             const ushortT* __restrict__ WoTl,
                                             const float* __restrict__ aout,
                                             ushortT* __restrict__ Wh2T,
                                             float* __restrict__ src2,
                                             float* __restrict__ dst2) {
    __shared__ ushortT As[32 * 64];                  // 4 KB
    __shared__ ushortT Bh[64 * 64], Bl[64 * 64];     // 16 KB
    __shared__ float sred[4][16], dred[4][16];
    const int tid = threadIdx.x, lane = tid & 63, wave = tid >> 6;
    const int r0 = blockIdx.x * 32;
    const int b = r0 >> 10, jr = r0 & 1023;
    const int m16 = lane & 15, quad = lane >> 4;
    const int mg = wave >> 1, fg = wave & 1;         // mg: row-frag 0..1, fg: f-half 0..1
    f32x4 acc[2] = {(f32x4){0.f,0.f,0.f,0.f}, (f32x4){0.f,0.f,0.f,0.f}};

    for (int kt = 0; kt < 8; ++kt) {
        __syncthreads();
        {   // A: 32 rows of xcat, wave covers 8 rows
            const int row = wave * 8 + (lane >> 3);
            const int sc = (lane & 7) ^ (row & 7);
            gload16(xcat + (size_t)(r0 + row) * FCAT + kt * 64 + sc * 8, As + wave * 8 * 64);
        }
#pragma unroll
        for (int half = 0; half < 2; ++half) {   // B: 64 f-rows, wave covers 16
            const int f = wave * 16 + half * 8 + (lane >> 3);
            const int sc = (lane & 7) ^ (f & 7);
            gload16(WoTh + (size_t)f * FCAT + kt * 64 + sc * 8, Bh + (wave * 16 + half * 8) * 64);
            gload16(WoTl + (size_t)f * FCAT + kt * 64 + sc * 8, Bl + (wave * 16 + half * 8) * 64);
        }
        __syncthreads();
#pragma unroll
        for (int ks = 0; ks < 2; ++ks) {
            const int rowa = mg * 16 + m16;
            const int cla = (ks * 4 + quad) ^ (rowa & 7);
            const bf16x8 afr = *(const bf16x8*)&As[rowa * 64 + cla * 8];
#pragma unroll
            for (int ff = 0; ff < 2; ++ff) {
                const int rowb = fg * 32 + ff * 16 + m16;
                const int clb = (ks * 4 + quad) ^ (rowb & 7);
                const bf16x8 b_h = *(const bf16x8*)&Bh[rowb * 64 + clb * 8];
                const bf16x8 b_l = *(const bf16x8*)&Bl[rowb * 64 + clb * 8];
                acc[ff] = __builtin_amdgcn_mfma_f32_16x16x32_bf16(afr, b_h, acc[ff], 0, 0, 0);
                acc[ff] = __builtin_amdgcn_mfma_f32_16x16x32_bf16(afr, b_l, acc[ff], 0, 0, 0);
            }
        }
    }
    // epilogue: Wh2T bf16 + fused src2/dst2 partials
    float sv[4] = {0, 0, 0, 0}, dv[4] = {0, 0, 0, 0};
#pragma unroll
    for (int ff = 0; ff < 2; ++ff) {
        const int f = fg * 32 + ff * 16 + m16;
        const float a_s = aout[f], a_d = aout[DOUT + f];
        union { ushortT u[4]; uint2 q; } tw;
#pragma unroll
        for (int reg = 0; reg < 4; ++reg) {
            const float v = acc[ff][reg];
            sv[reg] += v * a_s;
            dv[reg] += v * a_d;
            tw.u[reg] = f2bf(v);
        }
        *(uint2*)(Wh2T + ((size_t)(b * DOUT + f)) * NN + jr + mg * 16 + quad * 4) = tw.q;
    }
#pragma unroll
    for (int reg = 0; reg < 4; ++reg) {
#pragma unroll
        for (int o = 8; o > 0; o >>= 1) {
            sv[reg] += __shfl_xor(sv[reg], o, 64);
            dv[reg] += __shfl_xor(dv[reg], o, 64);
        }
        if (m16 == 0) { sred[wave][quad * 4 + reg] = sv[reg]; dred[wave][quad * 4 + reg] = dv[reg]; }
    }
    __syncthreads();
    if (tid < 32) {
        const int mgr = tid >> 4, idx = tid & 15;
        src2[r0 + tid] = sred[mgr * 2][idx] + sred[mgr * 2 + 1][idx];
        dst2[r0 + tid] = dred[mgr * 2][idx] + dred[mgr * 2 + 1][idx];
    }
}

// ============ k_attn2: single-pass softmax + PV + ELU + FC + ReLU (layer 2) ============
// grid 256 (b = bx&7, it = bx>>3), 256 thr, tile M=32, F=64, K=1024 (16 kt)
__global__ __launch_bounds__(256) void k_attn2(const unsigned* __restrict__ adjbit,
                                               const ushortT* __restrict__ Wh2T,
                                               const float* __restrict__ src2,
                                               const float* __restrict__ dst2,
                                               const float* __restrict__ Wf,
                                               const float* __restrict__ bfv,
                                               float* __restrict__ out) {
    __shared__ ushortT As[32 * 64];                 // 4 KB
    __shared__ ushortT Bs[64 * 64];                 // 8 KB
    __shared__ unsigned maskS[32 * 32];             // 4 KB
    __shared__ float dstv[NN];                      // 4 KB
    __shared__ ushortT Wfh[64 * 64], Wfl[64 * 64];  // 16 KB
    __shared__ float t2s[32 * 68];                  // 8.5 KB
    __shared__ float srcv[32], rowinv[32], red4[4];
    const int tid = threadIdx.x, lane = tid & 63, wave = tid >> 6;
    const int b = blockIdx.x & 7, it = blockIdx.x >> 3;
    const int i0 = it * 32;
    const int m16 = lane & 15, quad = lane >> 4;

    const unsigned* mbase = adjbit + (size_t)(b * NN + i0) * 32;
#pragma unroll
    for (int k2 = 0; k2 < 4; ++k2) maskS[tid + 256 * k2] = mbase[tid + 256 * k2];
    float lm = -INFINITY;
#pragma unroll
    for (int k2 = 0; k2 < 4; ++k2) {
        const float d = dst2[b * NN + tid + 256 * k2];
        dstv[tid + 256 * k2] = d;
        lm = fmaxf(lm, d);
    }
    if (tid < 32) srcv[tid] = src2[b * NN + i0 + tid];
    {   // stage Wf as hi/lo, layout [c][k] swizzled
        const int c = tid & 63, kc = (tid >> 6) * 16;
        union { ushortT u[16]; uint4 q[2]; } th, tl;
#pragma unroll
        for (int e = 0; e < 16; ++e)
            split2(Wf[(size_t)(kc + e) * DOUT + c], th.u[e], tl.u[e]);
        const int s0 = ((tid >> 6) * 2) ^ (c & 7), s1 = ((tid >> 6) * 2 + 1) ^ (c & 7);
        *(uint4*)&Wfh[c * 64 + s0 * 8] = th.q[0];
        *(uint4*)&Wfh[c * 64 + s1 * 8] = th.q[1];
        *(uint4*)&Wfl[c * 64 + s0 * 8] = tl.q[0];
        *(uint4*)&Wfl[c * 64 + s1 * 8] = tl.q[1];
    }
#pragma unroll
    for (int o = 32; o > 0; o >>= 1) lm = fmaxf(lm, __shfl_xor(lm, o, 64));
    if (lane == 0) red4[wave] = lm;
    __syncthreads();
    const float dmax = fmaxf(fmaxf(red4[0], red4[1]), fmaxf(red4[2], red4[3]));

    const int arow = tid >> 3, apart = tid & 7;      // 32 rows x 8 parts
    const float si = srcv[arow];
    float mrow = si + dmax;
    mrow = mrow >= 0.f ? mrow : ALPHA * mrow;
    float fsum = 0.f;

    const int mfrag = wave >> 1, fh = wave & 1;
    const ushortT* Bbase = Wh2T + (size_t)(b * DOUT) * NN;
    f32x4 acc[2] = {(f32x4){0.f,0.f,0.f,0.f}, (f32x4){0.f,0.f,0.f,0.f}};

    for (int kt = 0; kt < 16; ++kt) {
        __syncthreads();
#pragma unroll
        for (int half = 0; half < 2; ++half) {
            const int f = wave * 16 + half * 8 + (lane >> 3);
            gload16(Bbase + (size_t)f * NN + kt * 64 + (((lane & 7) ^ (f & 7)) * 8),
                    Bs + (wave * 16 + half * 8) * 64);
        }
        {
            const unsigned w0 = maskS[arow * 32 + kt * 2 + (apart >> 2)];
            const int bb = (apart & 3) * 8;
            union { ushortT u[8]; uint4 q; } tw;
#pragma unroll
            for (int e4 = 0; e4 < 2; ++e4) {
                const float4 dv = *(const float4*)&dstv[kt * 64 + apart * 8 + e4 * 4];
                const float vv[4] = {dv.x, dv.y, dv.z, dv.w};
#pragma unroll
                for (int e = 0; e < 4; ++e) {
                    float v = si + vv[e];
                    v = v >= 0.f ? v : ALPHA * v;
                    const unsigned bit = (w0 >> (bb + e4 * 4 + e)) & 1u;
                    const float p = bit ? __expf(v - mrow) : 0.f;
                    fsum += p;
                    tw.u[e4 * 4 + e] = f2bf(p);
                }
            }
            *(uint4*)&As[arow * 64 + (apart ^ (arow & 7)) * 8] = tw.q;
        }
        __syncthreads();
#pragma unroll
        for (int ks = 0; ks < 2; ++ks) {
            const int rowa = mfrag * 16 + m16;
            const int cla = (ks * 4 + quad) ^ (rowa & 7);
            const bf16x8 afr = *(const bf16x8*)&As[rowa * 64 + cla * 8];
#pragma unroll
            for (int ff = 0; ff < 2; ++ff) {
                const int rowb = (fh * 2 + ff) * 16 + m16;
                const int clb = (ks * 4 + quad) ^ (rowb & 7);
                const bf16x8 bfr = *(const bf16x8*)&Bs[rowb * 64 + clb * 8];
                acc[ff] = __builtin_amdgcn_mfma_f32_16x16x32_bf16(afr, bfr, acc[ff], 0, 0, 0);
            }
        }
    }
#pragma unroll
    for (int o = 1; o < 8; o <<= 1) fsum += __shfl_xor(fsum, o, 64);
    if ((lane & 7) == 0) rowinv[arow] = 1.f / fsum;
    __syncthreads();
#pragma unroll
    for (int ff = 0; ff < 2; ++ff) {
#pragma unroll
        for (int reg = 0; reg < 4; ++reg) {
            const int row = mfrag * 16 + quad * 4 + reg;
            float v = acc[ff][reg] * rowinv[row];
            v = v > 0.f ? v : (__expf(v) - 1.f);
            t2s[row * 68 + (fh * 2 + ff) * 16 + m16] = v;
        }
    }
    __syncthreads();
    const int mf = wave >> 1, nh = wave & 1;
    f32x4 oacc[2];
#pragma unroll
    for (int g = 0; g < 2; ++g) {
        const float bias = bfv[(nh * 2 + g) * 16 + m16];
        oacc[g] = (f32x4){bias, bias, bias, bias};
    }
#pragma unroll
    for (int ks = 0; ks < 2; ++ks) {
        const int rowa = mf * 16 + m16;
        const float4 fA = *(const float4*)&t2s[rowa * 68 + ks * 32 + quad * 8];
        const float4 fB = *(const float4*)&t2s[rowa * 68 + ks * 32 + quad * 8 + 4];
        union { ushortT u[8]; bf16x8 v; } a_h, a_l;
        const float av[8] = {fA.x, fA.y, fA.z, fA.w, fB.x, fB.y, fB.z, fB.w};
#pragma unroll
        for (int e = 0; e < 8; ++e) split2(av[e], a_h.u[e], a_l.u[e]);
#pragma unroll
        for (int g = 0; g < 2; ++g) {
            const int rowc = (nh * 2 + g) * 16 + m16;
            const int cl = (ks * 4 + quad) ^ (rowc & 7);
            const bf16x8 b_h = *(const bf16x8*)&Wfh[rowc * 64 + cl * 8];
            const bf16x8 b_l = *(const bf16x8*)&Wfl[rowc * 64 + cl * 8];
            oacc[g] = __builtin_amdgcn_mfma_f32_16x16x32_bf16(a_h.v, b_h, oacc[g], 0, 0, 0);
            oacc[g] = __builtin_amdgcn_mfma_f32_16x16x32_bf16(a_h.v, b_l, oacc[g], 0, 0, 0);
            oacc[g] = __builtin_amdgcn_mfma_f32_16x16x32_bf16(a_l.v, b_h, oacc[g], 0, 0, 0);
        }
    }
#pragma unroll
    for (int g = 0; g < 2; ++g) {
        const int c = (nh * 2 + g) * 16 + m16;
#pragma unroll
        for (int reg = 0; reg < 4; ++reg) {
            const int i = i0 + mf * 16 + quad * 4 + reg;
            out[(size_t)(b * NN + i) * DOUT + c] = fmaxf(oacc[g][reg], 0.f);
        }
    }
}

extern "C" void kernel_launch(void* const* d_in, const int* in_sizes, int n_in,
                              void* d_out, int out_size, void* d_ws, size_t ws_size,
                              hipStream_t stream) {
    const float* x   = (const float*)d_in[0];
    const int*   adj = (const int*)d_in[1];
    const float* Wh  = (const float*)d_in[2];
    const float* ah  = (const float*)d_in[3];
    const float* Wo  = (const float*)d_in[4];
    const float* ao  = (const float*)d_in[5];
    const float* Wf  = (const float*)d_in[6];
    const float* bf  = (const float*)d_in[7];
    float* out = (float*)d_out;

    float* ws    = (float*)d_ws;
    float* src1  = ws;                                 // 4*8192
    float* dst1  = src1 + NH * RTOT;                   // 4*8192
    float* src2  = dst1 + NH * RTOT;                   // 8192
    float* dst2  = src2 + RTOT;                        // 8192
    ushortT* WhT   = (ushortT*)(dst2 + RTOT);                // 8192*512 bf16
    ushortT* Wh2T  = WhT + (size_t)RTOT * FCAT;              // 8192*64
    ushortT* xcat  = Wh2T + (size_t)RTOT * DOUT;             // 8192*512
    ushortT* WbTh  = xcat + (size_t)RTOT * FCAT;             // 131072
    ushortT* WbTl  = WbTh + NH * DH * DIN;
    ushortT* WoTh  = WbTl + NH * DH * DIN;                   // 32768
    ushortT* WoTl  = WoTh + DOUT * FCAT;
    unsigned* adjbit = (unsigned*)(WoTl + DOUT * FCAT);      // 262144 words

    hipLaunchKernelGGL(k_prepw, dim3((NH * DH * DIN + DOUT * FCAT) / 256), dim3(256), 0, stream,
                       Wh, Wo, WbTh, WbTl, WoTh, WoTl);
    hipLaunchKernelGGL(k_main,  dim3(768), dim3(512), 0, stream,
                       x, ah, WbTh, WbTl, adj, adjbit, WhT, src1, dst1);
    hipLaunchKernelGGL(k_attn1, dim3(512), dim3(512), 0, stream,
                       adjbit, WhT, src1, dst1, xcat);
    hipLaunchKernelGGL(k_wh2,   dim3(256), dim3(256), 0, stream,
                       xcat, WoTh, WoTl, ao, Wh2T, src2, dst2);
    hipLaunchKernelGGL(k_attn2, dim3(256), dim3(256), 0, stream,
                       adjbit, Wh2T, src2, dst2, Wf, bf, out);
}